// Round 3
// baseline (1983.034 us; speedup 1.0000x reference)
//
#include <hip/hip_runtime.h>
#include <hip/hip_bf16.h>
#include <math.h>

#define B_    16
#define H_    56
#define W_    56
#define D_    384
#define HID_  1152
#define N_IN  3136
#define N_OUT 784
#define M_OUT (B_ * N_OUT)   // 12544
#define M_IN  (B_ * N_IN)    // 50176

#define XOUT_ELEMS ((size_t)M_OUT * D_)          // 4,816,896
#define A_ELEMS    ((size_t)B_ * N_OUT * N_IN)   // 39,337,984

__device__ __forceinline__ float wave_sum(float x) {
#pragma unroll
    for (int off = 32; off; off >>= 1) x += __shfl_xor(x, off, 64);
    return x;
}

// ---- conv weight relayout: wkn[(p*384+c)*384 + n] = conv_w[n*1536 + c*4 + p]
__global__ void prep_convw(const float* __restrict__ cw, float* __restrict__ wkn) {
    int idx = blockIdx.x * 256 + threadIdx.x;
    if (idx >= 1536 * 384) return;
    int k = idx / 384, n = idx % 384;
    int c = k % 384, p = k / 384;
    wkn[idx] = cw[n * 1536 + c * 4 + p];
}

__global__ void bias_mean(const float* __restrict__ rb, float* __restrict__ out) {
    if (threadIdx.x == 0) {
        float s = 0.f;
        for (int i = 0; i < 25; ++i) s += rb[i];
        *out = s / 25.0f;
    }
}

// ---- generic tiled f32 GEMM: C[M][N] = A[M][K] @ W[K][N] + bias (+ optional exact GELU)
// IM2COL: A is X_in, row m=(b,o) gathers the 2x2 conv patch; k = p*384 + c.
template <int IM2COL, int GELU>
__global__ __launch_bounds__(256) void gemm_kn(
    const float* __restrict__ A, const float* __restrict__ Wm,
    const float* __restrict__ bias, float* __restrict__ C,
    int M, int N, int K)
{
    __shared__ float As[16][64];
    __shared__ float Bs[16][64];
    int tid = threadIdx.x;
    int tx = tid & 15, ty = tid >> 4;
    int n0 = blockIdx.x * 64;
    int m0 = blockIdx.y * 64;
    float acc[4][4] = {};

    int arow = tid >> 2;          // 0..63
    int akq  = (tid & 3) * 4;     // 0,4,8,12
    int wkrow = tid >> 4;         // 0..15
    int wn    = (tid & 15) * 4;   // 0..60

    int m = m0 + arow;
    const float* Arowp = nullptr;
    int b_ = 0, pixbase = 0;
    if (IM2COL) {
        int bb = m / N_OUT; int o = m % N_OUT;
        int yo = o / 28, xo = o % 28;
        b_ = bb;
        pixbase = (2 * yo) * W_ + 2 * xo;
    } else {
        Arowp = A + (size_t)m * K;
    }

    for (int k0 = 0; k0 < K; k0 += 16) {
        float4 av;
        if (IM2COL) {
            int k = k0 + akq;
            int p = k / 384, c = k % 384;   // K-tile of 16 never crosses p (384%16==0)
            int pix = pixbase + (p >> 1) * W_ + (p & 1);
            av = *reinterpret_cast<const float4*>(A + ((size_t)(b_ * N_IN + pix)) * D_ + c);
        } else {
            av = *reinterpret_cast<const float4*>(Arowp + k0 + akq);
        }
        As[akq + 0][arow] = av.x;
        As[akq + 1][arow] = av.y;
        As[akq + 2][arow] = av.z;
        As[akq + 3][arow] = av.w;
        *reinterpret_cast<float4*>(&Bs[wkrow][wn]) =
            *reinterpret_cast<const float4*>(Wm + (size_t)(k0 + wkrow) * N + n0 + wn);
        __syncthreads();
#pragma unroll
        for (int kk = 0; kk < 16; ++kk) {
            float4 a = *reinterpret_cast<const float4*>(&As[kk][ty * 4]);
            float4 b = *reinterpret_cast<const float4*>(&Bs[kk][tx * 4]);
            float av_[4] = {a.x, a.y, a.z, a.w};
            float bv_[4] = {b.x, b.y, b.z, b.w};
#pragma unroll
            for (int i = 0; i < 4; ++i)
#pragma unroll
                for (int j = 0; j < 4; ++j)
                    acc[i][j] += av_[i] * bv_[j];
        }
        __syncthreads();
    }

#pragma unroll
    for (int i = 0; i < 4; ++i) {
        int row = m0 + ty * 4 + i;
        float* op = C + (size_t)row * N + n0 + tx * 4;
        float4 outv;
        float vals[4];
#pragma unroll
        for (int j = 0; j < 4; ++j) {
            float v = acc[i][j] + bias[n0 + tx * 4 + j];
            if (GELU) v = 0.5f * v * (1.0f + erff(v * 0.70710678118654752f));
            vals[j] = v;
        }
        outv.x = vals[0]; outv.y = vals[1]; outv.z = vals[2]; outv.w = vals[3];
        *reinterpret_cast<float4*>(op) = outv;
    }
}

// ---- row LayerNorm over D=384; one wave per row; ADD: dst += LN(src) else dst = LN(src)
template <int ADD>
__global__ __launch_bounds__(256) void ln_rows(
    const float* __restrict__ src, float* __restrict__ dst,
    const float* __restrict__ s, const float* __restrict__ bvec, int M)
{
    int wid = blockIdx.x * 4 + (threadIdx.x >> 6);
    int lane = threadIdx.x & 63;
    if (wid >= M) return;
    const float* r = src + (size_t)wid * D_;
    float v[6]; float sum = 0.f;
#pragma unroll
    for (int t = 0; t < 6; ++t) { v[t] = r[lane + 64 * t]; sum += v[t]; }
    sum = wave_sum(sum);
    float mean = sum * (1.0f / D_);
    float vs = 0.f;
#pragma unroll
    for (int t = 0; t < 6; ++t) { float d = v[t] - mean; vs += d * d; }
    vs = wave_sum(vs);
    float rstd = rsqrtf(vs * (1.0f / D_) + 1e-5f);
    float* w = dst + (size_t)wid * D_;
#pragma unroll
    for (int t = 0; t < 6; ++t) {
        int d = lane + 64 * t;
        float o = (v[t] - mean) * rstd * s[d] + bvec[d];
        if (ADD) w[d] += o; else w[d] = o;
    }
}

// ---- windowed attention scores -> P[(b,o)][12] (9 softmax probs, padded with 0)
__global__ __launch_bounds__(256) void attn_scores(
    const float* __restrict__ Q, const float* __restrict__ Kb,
    const float* __restrict__ biasp, float* __restrict__ P)
{
    int wid = blockIdx.x * 4 + (threadIdx.x >> 6);   // (b,o)
    int lane = threadIdx.x & 63;
    int b = wid / N_OUT, o = wid % N_OUT;
    int yo = o / 28, xo = o % 28;
    float q[6];
    const float* qr = Q + (size_t)wid * D_;
#pragma unroll
    for (int t = 0; t < 6; ++t) q[t] = qr[lane + 64 * t];
    float s[9]; bool valid[9];
#pragma unroll
    for (int j = 0; j < 9; ++j) {
        int dy = j / 3 - 1, dx = j % 3 - 1;
        int yi = 2 * yo + dy, xi = 2 * xo + dx;
        bool ok = (yi >= 0) && (yi < H_) && (xi >= 0) && (xi < W_);
        valid[j] = ok;
        float acc = 0.f;
        if (ok) {
            const float* kr = Kb + ((size_t)(b * N_IN + yi * W_ + xi)) * D_;
#pragma unroll
            for (int t = 0; t < 6; ++t) acc += q[t] * kr[lane + 64 * t];
        }
        s[j] = acc;
    }
#pragma unroll
    for (int j = 0; j < 9; ++j) s[j] = wave_sum(s[j]);
    float bias = *biasp;
    float mx = -1e30f;
#pragma unroll
    for (int j = 0; j < 9; ++j) if (valid[j]) mx = fmaxf(mx, s[j] + bias);
    float e[9]; float tot = 0.f;
#pragma unroll
    for (int j = 0; j < 9; ++j) { e[j] = valid[j] ? expf(s[j] + bias - mx) : 0.0f; tot += e[j]; }
    float inv = 1.0f / tot;
    if (lane < 12) P[(size_t)wid * 12 + lane] = (lane < 9) ? e[lane] * inv : 0.0f;
}

// ---- new_centers = P @ V (window gather), then X_out += LN(new_centers)
__global__ __launch_bounds__(256) void nc_ln_add(
    const float* __restrict__ P, const float* __restrict__ Vb,
    const float* __restrict__ s, const float* __restrict__ bvec,
    float* __restrict__ Xout)
{
    int wid = blockIdx.x * 4 + (threadIdx.x >> 6);
    int lane = threadIdx.x & 63;
    int b = wid / N_OUT, o = wid % N_OUT;
    int yo = o / 28, xo = o % 28;
    float acc[6] = {0, 0, 0, 0, 0, 0};
#pragma unroll
    for (int j = 0; j < 9; ++j) {
        int dy = j / 3 - 1, dx = j % 3 - 1;
        int yi = 2 * yo + dy, xi = 2 * xo + dx;
        if (yi >= 0 && yi < H_ && xi >= 0 && xi < W_) {
            float p = P[(size_t)wid * 12 + j];
            const float* vr = Vb + ((size_t)(b * N_IN + yi * W_ + xi)) * D_;
#pragma unroll
            for (int t = 0; t < 6; ++t) acc[t] += p * vr[lane + 64 * t];
        }
    }
    float sum = 0.f;
#pragma unroll
    for (int t = 0; t < 6; ++t) sum += acc[t];
    sum = wave_sum(sum);
    float mean = sum * (1.0f / D_);
    float vs = 0.f;
#pragma unroll
    for (int t = 0; t < 6; ++t) { float d = acc[t] - mean; vs += d * d; }
    vs = wave_sum(vs);
    float rstd = rsqrtf(vs * (1.0f / D_) + 1e-5f);
    float* w = Xout + (size_t)wid * D_;
#pragma unroll
    for (int t = 0; t < 6; ++t) {
        int d = lane + 64 * t;
        w[d] += (acc[t] - mean) * rstd * s[d] + bvec[d];
    }
}

// ---- per-(b, input pixel) column sum of A_ups (1,2, or 4 contributors)
__global__ void colsum_k(const float* __restrict__ P, float* __restrict__ cs) {
    int idx = blockIdx.x * 256 + threadIdx.x;
    if (idx >= B_ * N_IN) return;
    int b = idx / N_IN, i = idx % N_IN;
    int yi = i / W_, xi = i % W_;
    float sum = 0.f;
    int yc = yi >> 1, xc = xi >> 1;
    for (int yo = yc - 1; yo <= yc + 1; ++yo) {
        if (yo < 0 || yo >= 28) continue;
        int dy = yi - 2 * yo;
        if (dy < -1 || dy > 1) continue;
        for (int xo = xc - 1; xo <= xc + 1; ++xo) {
            if (xo < 0 || xo >= 28) continue;
            int dx = xi - 2 * xo;
            if (dx < -1 || dx > 1) continue;
            int j = (dy + 1) * 3 + (dx + 1);
            sum += P[((size_t)(b * N_OUT + yo * 28 + xo)) * 12 + j];
        }
    }
    cs[idx] = sum;
}

// ---- scatter sparse window probs into dense A_ups / A_down
__global__ void scatter_A(const float* __restrict__ P, const float* __restrict__ cs,
                          float* __restrict__ Aups, float* __restrict__ Adown) {
    int idx = blockIdx.x * 256 + threadIdx.x;
    if (idx >= M_OUT * 9) return;
    int wid = idx / 9, j = idx % 9;
    int b = wid / N_OUT, o = wid % N_OUT;
    int yo = o / 28, xo = o % 28;
    int dy = j / 3 - 1, dx = j % 3 - 1;
    int yi = 2 * yo + dy, xi = 2 * xo + dx;
    if (yi < 0 || yi >= H_ || xi < 0 || xi >= W_) return;
    int i = yi * W_ + xi;
    float p = P[(size_t)wid * 12 + j];
    size_t base = (size_t)wid * N_IN + i;
    Aups[base] = p;
    Adown[base] = p / (1e-10f + cs[b * N_IN + i]);
}

extern "C" void kernel_launch(void* const* d_in, const int* in_sizes, int n_in,
                              void* d_out, int out_size, void* d_ws, size_t ws_size,
                              hipStream_t stream)
{
    const float* X_in      = (const float*)d_in[0];
    const float* conv_w    = (const float*)d_in[1];
    const float* conv_b    = (const float*)d_in[2];
    const float* ln_init_s = (const float*)d_in[3];
    const float* ln_init_b = (const float*)d_in[4];
    const float* qw        = (const float*)d_in[5];
    const float* qb        = (const float*)d_in[6];
    const float* kw        = (const float*)d_in[7];
    const float* kb        = (const float*)d_in[8];
    const float* vw        = (const float*)d_in[9];
    const float* vb        = (const float*)d_in[10];
    const float* ln_out_s  = (const float*)d_in[11];
    const float* ln_out_b  = (const float*)d_in[12];
    const float* w1        = (const float*)d_in[13];
    const float* b1        = (const float*)d_in[14];
    const float* w2        = (const float*)d_in[15];
    const float* b2        = (const float*)d_in[16];
    const float* mlp_s     = (const float*)d_in[17];
    const float* mlp_b     = (const float*)d_in[18];
    const float* rel_bias  = (const float*)d_in[19];
    (void)in_sizes; (void)n_in; (void)out_size; (void)ws_size;

    float* out   = (float*)d_out;
    float* Xout  = out;                    // (M_OUT, D)
    float* Adown = out + XOUT_ELEMS;       // (B, N_OUT, N_IN)
    float* Aups  = Adown + A_ELEMS;

    // K/V live in the A regions until the final-iteration memset+scatter
    float* Vbuf = Adown;
    float* Kbuf = Aups;

    float* ws    = (float*)d_ws;
    float* wkn   = ws;                                   // 1536*384
    float* biasv = wkn + 1536 * 384;                     // 64
    float* h1    = biasv + 64;                           // M_OUT*HID
    float* qh2   = h1 + (size_t)M_OUT * HID_;            // M_OUT*D (Q, later h2)
    float* Pb    = qh2 + (size_t)M_OUT * D_;             // M_OUT*12
    float* cs    = Pb + (size_t)M_OUT * 12;              // B*N_IN

    hipLaunchKernelGGL(prep_convw, dim3((1536 * 384 + 255) / 256), dim3(256), 0, stream, conv_w, wkn);
    hipLaunchKernelGGL(bias_mean, dim3(1), dim3(64), 0, stream, rel_bias, biasv);

    // init_proj conv (as im2col GEMM) -> h1, then X_out = LN(h1)
    hipLaunchKernelGGL((gemm_kn<1, 0>), dim3(D_ / 64, M_OUT / 64), dim3(256), 0, stream,
                       X_in, wkn, conv_b, h1, M_OUT, D_, 4 * D_);
    hipLaunchKernelGGL((ln_rows<0>), dim3(M_OUT / 4), dim3(256), 0, stream,
                       h1, Xout, ln_init_s, ln_init_b, M_OUT);

    // K, V projections (parked in d_out A-regions)
    hipLaunchKernelGGL((gemm_kn<0, 0>), dim3(D_ / 64, M_IN / 64), dim3(256), 0, stream,
                       X_in, kw, kb, Kbuf, M_IN, D_, D_);
    hipLaunchKernelGGL((gemm_kn<0, 0>), dim3(D_ / 64, M_IN / 64), dim3(256), 0, stream,
                       X_in, vw, vb, Vbuf, M_IN, D_, D_);

    for (int it = 0; it < 3; ++it) {
        hipLaunchKernelGGL((gemm_kn<0, 0>), dim3(D_ / 64, M_OUT / 64), dim3(256), 0, stream,
                           Xout, qw, qb, qh2, M_OUT, D_, D_);
        hipLaunchKernelGGL(attn_scores, dim3(M_OUT / 4), dim3(256), 0, stream, qh2, Kbuf, biasv, Pb);
        hipLaunchKernelGGL(nc_ln_add, dim3(M_OUT / 4), dim3(256), 0, stream, Pb, Vbuf, ln_out_s, ln_out_b, Xout);
        if (it == 2) {
            // K,V dead from here; build the dense sparse outputs
            hipMemsetAsync(Adown, 0, sizeof(float) * 2 * A_ELEMS, stream);
            hipLaunchKernelGGL(colsum_k, dim3((B_ * N_IN + 255) / 256), dim3(256), 0, stream, Pb, cs);
            hipLaunchKernelGGL(scatter_A, dim3((M_OUT * 9 + 255) / 256), dim3(256), 0, stream, Pb, cs, Aups, Adown);
        }
        hipLaunchKernelGGL((gemm_kn<0, 1>), dim3(HID_ / 64, M_OUT / 64), dim3(256), 0, stream,
                           Xout, w1, b1, h1, M_OUT, HID_, D_);
        hipLaunchKernelGGL((gemm_kn<0, 0>), dim3(D_ / 64, M_OUT / 64), dim3(256), 0, stream,
                           h1, w2, b2, qh2, M_OUT, D_, HID_);
        hipLaunchKernelGGL((ln_rows<1>), dim3(M_OUT / 4), dim3(256), 0, stream,
                           qh2, Xout, mlp_s, mlp_b, M_OUT);
    }
}

// Round 5
// 957.166 us; speedup vs baseline: 2.0718x; 2.0718x over previous
//
#include <hip/hip_runtime.h>
#include <hip/hip_bf16.h>
#include <math.h>

#define B_    16
#define H_    56
#define W_    56
#define D_    384
#define HID_  1152
#define N_IN  3136
#define N_OUT 784
#define M_OUT (B_ * N_OUT)   // 12544
#define M_IN  (B_ * N_IN)    // 50176

#define XOUT_ELEMS ((size_t)M_OUT * D_)          // 4,816,896
#define A_ELEMS    ((size_t)B_ * N_OUT * N_IN)   // 39,337,984

typedef unsigned short u16;
using frag_ab = __attribute__((ext_vector_type(8))) short;  // 8 bf16 (4 VGPRs)
using frag_cd = __attribute__((ext_vector_type(4))) float;  // 4 fp32

__device__ __forceinline__ u16 f2b(float f) {
    __hip_bfloat16 h = __float2bfloat16(f);
    return *reinterpret_cast<u16*>(&h);
}
__device__ __forceinline__ float b2f(u16 u) {
    __hip_bfloat16 h = *reinterpret_cast<__hip_bfloat16*>(&u);
    return __bfloat162float(h);
}
__device__ __forceinline__ void split2(float f, u16& hi, u16& lo) {
    __hip_bfloat16 h = __float2bfloat16(f);
    hi = *reinterpret_cast<u16*>(&h);
    float r = f - __bfloat162float(h);
    __hip_bfloat16 l = __float2bfloat16(r);
    lo = *reinterpret_cast<u16*>(&l);
}

__device__ __forceinline__ float wave_sum(float x) {
#pragma unroll
    for (int off = 32; off; off >>= 1) x += __shfl_xor(x, off, 64);
    return x;
}

#define GLD16(g, l) __builtin_amdgcn_global_load_lds( \
    (const __attribute__((address_space(1))) void*)(g), \
    (__attribute__((address_space(3))) void*)(l), 16, 0, 0)

// ---- f32 -> (hi, lo) bf16 planes, float4 vectorized
__global__ void cvt_split(const float* __restrict__ in, u16* __restrict__ hi,
                          u16* __restrict__ lo, size_t n4) {
    size_t i = (size_t)blockIdx.x * 256 + threadIdx.x;
    size_t stride = (size_t)gridDim.x * 256;
    for (; i < n4; i += stride) {
        float4 v = reinterpret_cast<const float4*>(in)[i];
        ushort4 h, l;
        split2(v.x, h.x, l.x); split2(v.y, h.y, l.y);
        split2(v.z, h.z, l.z); split2(v.w, h.w, l.w);
        reinterpret_cast<ushort4*>(hi)[i] = h;
        reinterpret_cast<ushort4*>(lo)[i] = l;
    }
}

// ---- W[K][N] f32 -> Bt[N][K] hi/lo bf16 (LDS-tiled transpose)
__global__ void transpose_split(const float* __restrict__ Wm, u16* __restrict__ Bh,
                                u16* __restrict__ Bl, int K, int N) {
    __shared__ float t[32][33];
    int k0 = blockIdx.y * 32, n0 = blockIdx.x * 32;
    int r = threadIdx.x >> 5, c = threadIdx.x & 31;
#pragma unroll
    for (int i = 0; i < 4; ++i) t[r + 8 * i][c] = Wm[(size_t)(k0 + r + 8 * i) * N + n0 + c];
    __syncthreads();
#pragma unroll
    for (int i = 0; i < 4; ++i) {
        u16 hi, lo;
        split2(t[c][r + 8 * i], hi, lo);
        size_t idx = (size_t)(n0 + r + 8 * i) * K + k0 + c;
        Bh[idx] = hi; Bl[idx] = lo;
    }
}

// ---- conv weight: wknT[n][kk] hi/lo, kk = p*384 + c ; conv_w OIHW [n][c][p]
__global__ void prep_convw_split(const float* __restrict__ cw, u16* __restrict__ Bh,
                                 u16* __restrict__ Bl) {
    int idx = blockIdx.x * 256 + threadIdx.x;
    if (idx >= 384 * 1536) return;
    int n = idx / 1536, kk = idx % 1536;
    int p = kk / 384, c = kk % 384;
    u16 hi, lo;
    split2(cw[n * 1536 + c * 4 + p], hi, lo);
    Bh[idx] = hi; Bl[idx] = lo;
}

__global__ void bias_mean(const float* __restrict__ rb, float* __restrict__ out) {
    if (threadIdx.x == 0) {
        float s = 0.f;
        for (int i = 0; i < 25; ++i) s += rb[i];
        *out = s / 25.0f;
    }
}

// ---- split-bf16 MFMA GEMM: C = A @ Bt^T + bias, f32-accurate via 3 MFMA passes.
// 128x128 tile, BK=64, 4 waves (2x2), 16x16x32 MFMA, global_load_lds staging,
// XOR-swizzle: LDS(row, b) = G(row, b ^ ((row&7)<<4)), read undoes with swzf.
template <int IM2COL, int GELU, int OUTSPLIT>
__global__ __launch_bounds__(256, 2) void gemm_split(
    const u16* __restrict__ Ah, const u16* __restrict__ Al,
    const u16* __restrict__ Bth, const u16* __restrict__ Btl,
    const float* __restrict__ bias, float* __restrict__ Cf,
    u16* __restrict__ Chi, u16* __restrict__ Clo,
    int M, int N, int K)
{
    __shared__ u16 sAh[128 * 64];
    __shared__ u16 sAl[128 * 64];
    __shared__ u16 sBh[128 * 64];
    __shared__ u16 sBl[128 * 64];
    const int t = threadIdx.x;
    const int lane = t & 63;
    const int w = t >> 6;
    const int wr = w >> 1, wc = w & 1;
    const int lm = lane & 15, lk = lane >> 4;
    const int m0 = blockIdx.y * 128;
    const int n0 = blockIdx.x * 128;

    const int rt = t >> 3, st = t & 7;                    // staging row-sub, 16B slot
    const int skel = ((st * 16) ^ ((rt & 7) << 4)) >> 1;  // swizzle-inverse src k-elem

    int pb4[4];
    if (IM2COL) {
#pragma unroll
        for (int i = 0; i < 4; ++i) {
            int m = m0 + i * 32 + rt;
            int bb = m / N_OUT, o = m - bb * N_OUT;
            pb4[i] = bb * N_IN + (o / 28) * 112 + (o % 28) * 2;
        }
    }

    frag_cd acc[4][4];
#pragma unroll
    for (int i = 0; i < 4; ++i)
#pragma unroll
        for (int j = 0; j < 4; ++j) acc[i][j] = (frag_cd){0.f, 0.f, 0.f, 0.f};

    const int swzf = (lm & 7) << 4;

    for (int kt = 0; kt < K; kt += 64) {
#pragma unroll
        for (int i = 0; i < 4; ++i) {
            int r = i * 32 + rt;
            size_t aoff;
            if (IM2COL) {
                int k = kt + skel;
                int p = k / 384, c = k - p * 384;
                aoff = ((size_t)pb4[i] + (p >> 1) * 56 + (p & 1)) * 384 + c;
            } else {
                aoff = (size_t)(m0 + r) * K + kt + skel;
            }
            GLD16(Ah + aoff, &sAh[i * 2048 + t * 8]);
            GLD16(Al + aoff, &sAl[i * 2048 + t * 8]);
            size_t boff = (size_t)(n0 + r) * K + kt + skel;
            GLD16(Bth + boff, &sBh[i * 2048 + t * 8]);
            GLD16(Btl + boff, &sBl[i * 2048 + t * 8]);
        }
        __syncthreads();

#pragma unroll
        for (int h = 0; h < 2; ++h) {
            const int kb = (h * 64 + lk * 16) ^ swzf;
            frag_ab ah[4], al[4], bh[4], bl[4];
#pragma unroll
            for (int m = 0; m < 4; ++m) {
                int arow = wr * 64 + m * 16 + lm;
                int brow = wc * 64 + m * 16 + lm;
                ah[m] = *reinterpret_cast<const frag_ab*>(reinterpret_cast<const char*>(sAh) + arow * 128 + kb);
                al[m] = *reinterpret_cast<const frag_ab*>(reinterpret_cast<const char*>(sAl) + arow * 128 + kb);
                bh[m] = *reinterpret_cast<const frag_ab*>(reinterpret_cast<const char*>(sBh) + brow * 128 + kb);
                bl[m] = *reinterpret_cast<const frag_ab*>(reinterpret_cast<const char*>(sBl) + brow * 128 + kb);
            }
#pragma unroll
            for (int m = 0; m < 4; ++m)
#pragma unroll
                for (int n = 0; n < 4; ++n) {
                    acc[m][n] = __builtin_amdgcn_mfma_f32_16x16x32_bf16(ah[m], bh[n], acc[m][n], 0, 0, 0);
                    acc[m][n] = __builtin_amdgcn_mfma_f32_16x16x32_bf16(al[m], bh[n], acc[m][n], 0, 0, 0);
                    acc[m][n] = __builtin_amdgcn_mfma_f32_16x16x32_bf16(ah[m], bl[n], acc[m][n], 0, 0, 0);
                }
        }
        __syncthreads();
    }

    // epilogue: C/D layout col=lane&15, row=(lane>>4)*4+reg (m89-verified)
#pragma unroll
    for (int m = 0; m < 4; ++m) {
#pragma unroll
        for (int n = 0; n < 4; ++n) {
            int row0 = m0 + wr * 64 + m * 16 + lk * 4;
            int col  = n0 + wc * 64 + n * 16 + lm;
            float bv = bias[col];
#pragma unroll
            for (int r = 0; r < 4; ++r) {
                float v = acc[m][n][r] + bv;
                if (GELU) v = 0.5f * v * (1.0f + erff(v * 0.70710678118654752f));
                size_t idx = (size_t)(row0 + r) * N + col;
                if (OUTSPLIT) {
                    u16 hi, lo; split2(v, hi, lo);
                    Chi[idx] = hi; Clo[idx] = lo;
                } else {
                    Cf[idx] = v;
                }
            }
        }
    }
}

// ---- row LayerNorm over D=384; writes f32 dst + hi/lo bf16 planes; ADD: dst += LN
template <int ADD>
__global__ __launch_bounds__(256) void ln_rows(
    const float* __restrict__ src, float* __restrict__ dst,
    u16* __restrict__ dhi, u16* __restrict__ dlo,
    const float* __restrict__ s, const float* __restrict__ bvec)
{
    int wid = blockIdx.x * 4 + (threadIdx.x >> 6);
    int lane = threadIdx.x & 63;
    const float* r = src + (size_t)wid * D_;
    float v[6]; float sum = 0.f;
#pragma unroll
    for (int t = 0; t < 6; ++t) { v[t] = r[lane + 64 * t]; sum += v[t]; }
    sum = wave_sum(sum);
    float mean = sum * (1.0f / D_);
    float vs = 0.f;
#pragma unroll
    for (int t = 0; t < 6; ++t) { float d = v[t] - mean; vs += d * d; }
    vs = wave_sum(vs);
    float rstd = rsqrtf(vs * (1.0f / D_) + 1e-5f);
    float* wo = dst + (size_t)wid * D_;
    u16* wh = dhi + (size_t)wid * D_;
    u16* wl = dlo + (size_t)wid * D_;
#pragma unroll
    for (int t = 0; t < 6; ++t) {
        int d = lane + 64 * t;
        float o = (v[t] - mean) * rstd * s[d] + bvec[d];
        float nv = ADD ? (wo[d] + o) : o;
        wo[d] = nv;
        u16 hi, lo; split2(nv, hi, lo);
        wh[d] = hi; wl[d] = lo;
    }
}

// ---- windowed attention scores -> P[(b,o)][12]; Q,K f32
__global__ __launch_bounds__(256) void attn_scores(
    const float* __restrict__ Q, const float* __restrict__ Kb,
    const float* __restrict__ biasp, float* __restrict__ P)
{
    int wid = blockIdx.x * 4 + (threadIdx.x >> 6);   // (b,o)
    int lane = threadIdx.x & 63;
    int b = wid / N_OUT, o = wid % N_OUT;
    int yo = o / 28, xo = o % 28;
    float q[6];
    const float* qr = Q + (size_t)wid * D_;
#pragma unroll
    for (int t = 0; t < 6; ++t) q[t] = qr[lane + 64 * t];
    float s[9]; bool valid[9];
#pragma unroll
    for (int j = 0; j < 9; ++j) {
        int dy = j / 3 - 1, dx = j % 3 - 1;
        int yi = 2 * yo + dy, xi = 2 * xo + dx;
        bool ok = (yi >= 0) && (yi < H_) && (xi >= 0) && (xi < W_);
        valid[j] = ok;
        float acc = 0.f;
        if (ok) {
            const float* kr = Kb + ((size_t)(b * N_IN + yi * W_ + xi)) * D_;
#pragma unroll
            for (int t = 0; t < 6; ++t) acc += q[t] * kr[lane + 64 * t];
        }
        s[j] = acc;
    }
#pragma unroll
    for (int j = 0; j < 9; ++j) s[j] = wave_sum(s[j]);
    float bias = *biasp;
    float mx = -1e30f;
#pragma unroll
    for (int j = 0; j < 9; ++j) if (valid[j]) mx = fmaxf(mx, s[j] + bias);
    float e[9]; float tot = 0.f;
#pragma unroll
    for (int j = 0; j < 9; ++j) { e[j] = valid[j] ? expf(s[j] + bias - mx) : 0.0f; tot += e[j]; }
    float inv = 1.0f / tot;
    if (lane < 12) P[(size_t)wid * 12 + lane] = (lane < 9) ? e[lane] * inv : 0.0f;
}

// ---- new_centers = P @ V (f32 V), X_out += LN(new_centers); refresh hi/lo planes
__global__ __launch_bounds__(256) void nc_ln_add(
    const float* __restrict__ P, const float* __restrict__ Vb,
    const float* __restrict__ s, const float* __restrict__ bvec,
    float* __restrict__ Xout, u16* __restrict__ Xhi, u16* __restrict__ Xlo)
{
    int wid = blockIdx.x * 4 + (threadIdx.x >> 6);
    int lane = threadIdx.x & 63;
    int b = wid / N_OUT, o = wid % N_OUT;
    int yo = o / 28, xo = o % 28;
    float acc[6] = {0, 0, 0, 0, 0, 0};
#pragma unroll
    for (int j = 0; j < 9; ++j) {
        int dy = j / 3 - 1, dx = j % 3 - 1;
        int yi = 2 * yo + dy, xi = 2 * xo + dx;
        if (yi >= 0 && yi < H_ && xi >= 0 && xi < W_) {
            float p = P[(size_t)wid * 12 + j];
            const float* vr = Vb + ((size_t)(b * N_IN + yi * W_ + xi)) * D_;
#pragma unroll
            for (int t = 0; t < 6; ++t) acc[t] += p * vr[lane + 64 * t];
        }
    }
    float sum = 0.f;
#pragma unroll
    for (int t = 0; t < 6; ++t) sum += acc[t];
    sum = wave_sum(sum);
    float mean = sum * (1.0f / D_);
    float vs = 0.f;
#pragma unroll
    for (int t = 0; t < 6; ++t) { float d = acc[t] - mean; vs += d * d; }
    vs = wave_sum(vs);
    float rstd = rsqrtf(vs * (1.0f / D_) + 1e-5f);
    float* wo = Xout + (size_t)wid * D_;
    u16* wh = Xhi + (size_t)wid * D_;
    u16* wl = Xlo + (size_t)wid * D_;
#pragma unroll
    for (int t = 0; t < 6; ++t) {
        int d = lane + 64 * t;
        float nv = wo[d] + (acc[t] - mean) * rstd * s[d] + bvec[d];
        wo[d] = nv;
        u16 hi, lo; split2(nv, hi, lo);
        wh[d] = hi; wl[d] = lo;
    }
}

// ---- per-(b, input pixel) column sum of A_ups
__global__ void colsum_k(const float* __restrict__ P, float* __restrict__ cs) {
    int idx = blockIdx.x * 256 + threadIdx.x;
    if (idx >= B_ * N_IN) return;
    int b = idx / N_IN, i = idx % N_IN;
    int yi = i / W_, xi = i % W_;
    float sum = 0.f;
    int yc = yi >> 1, xc = xi >> 1;
    for (int yo = yc - 1; yo <= yc + 1; ++yo) {
        if (yo < 0 || yo >= 28) continue;
        int dy = yi - 2 * yo;
        if (dy < -1 || dy > 1) continue;
        for (int xo = xc - 1; xo <= xc + 1; ++xo) {
            if (xo < 0 || xo >= 28) continue;
            int dx = xi - 2 * xo;
            if (dx < -1 || dx > 1) continue;
            int j = (dy + 1) * 3 + (dx + 1);
            sum += P[((size_t)(b * N_OUT + yo * 28 + xo)) * 12 + j];
        }
    }
    cs[idx] = sum;
}

// ---- scatter sparse window probs into dense A_ups / A_down
__global__ void scatter_A(const float* __restrict__ P, const float* __restrict__ cs,
                          float* __restrict__ Aups, float* __restrict__ Adown) {
    int idx = blockIdx.x * 256 + threadIdx.x;
    if (idx >= M_OUT * 9) return;
    int wid = idx / 9, j = idx % 9;
    int b = wid / N_OUT, o = wid % N_OUT;
    int yo = o / 28, xo = o % 28;
    int dy = j / 3 - 1, dx = j % 3 - 1;
    int yi = 2 * yo + dy, xi = 2 * xo + dx;
    if (yi < 0 || yi >= H_ || xi < 0 || xi >= W_) return;
    int i = yi * W_ + xi;
    float p = P[(size_t)wid * 12 + j];
    size_t base = (size_t)wid * N_IN + i;
    Aups[base] = p;
    Adown[base] = p / (1e-10f + cs[b * N_IN + i]);
}

extern "C" void kernel_launch(void* const* d_in, const int* in_sizes, int n_in,
                              void* d_out, int out_size, void* d_ws, size_t ws_size,
                              hipStream_t stream)
{
    const float* X_in      = (const float*)d_in[0];
    const float* conv_w    = (const float*)d_in[1];
    const float* conv_b    = (const float*)d_in[2];
    const float* ln_init_s = (const float*)d_in[3];
    const float* ln_init_b = (const float*)d_in[4];
    const float* qw        = (const float*)d_in[5];
    const float* qb        = (const float*)d_in[6];
    const float* kw        = (const float*)d_in[7];
    const float* kb        = (const float*)d_in[8];
    const float* vw        = (const float*)d_in[9];
    const float* vb        = (const float*)d_in[10];
    const float* ln_out_s  = (const float*)d_in[11];
    const float* ln_out_b  = (const float*)d_in[12];
    const float* w1        = (const float*)d_in[13];
    const float* b1        = (const float*)d_in[14];
    const float* w2        = (const float*)d_in[15];
    const float* b2        = (const float*)d_in[16];
    const float* mlp_s     = (const float*)d_in[17];
    const float* mlp_b     = (const float*)d_in[18];
    const float* rel_bias  = (const float*)d_in[19];
    (void)in_sizes; (void)n_in; (void)out_size; (void)ws_size;

    float* out   = (float*)d_out;
    float* Xout  = out;                    // (M_OUT, D) f32 — final output 0
    float* Adown = out + XOUT_ELEMS;       // (B, N_OUT, N_IN)
    float* Aups  = Adown + A_ELEMS;

    // dead A-region overlays (all dead before the final memset+scatter):
    float* Abase = Adown;                            // 2*A_ELEMS floats total
    float* Vf    = Abase;                            // M_IN*D f32 (77MB)
    float* Kf    = Abase + (size_t)M_IN * D_;        // 77MB
    u16* XinHi = (u16*)(Abase + 38535168);           // M_IN*D u16
    u16* XinLo = (u16*)(Abase + 48168960);
    u16* h1Hi  = (u16*)(Abase + 57802752);           // M_OUT*HID u16
    u16* h1Lo  = (u16*)(Abase + 65028096);

    float* ws    = (float*)d_ws;
    float* tmpD  = ws;                               // M_OUT*D f32 (conv out / Q / h2)
    float* Pb    = tmpD + XOUT_ELEMS;                // M_OUT*12
    float* cs    = Pb + (size_t)M_OUT * 12;          // B_*N_IN
    float* biasv = cs + B_ * N_IN;                   // 4
    u16* XoutHi = (u16*)(biasv + 4);                 // M_OUT*D
    u16* XoutLo = XoutHi + XOUT_ELEMS;
    u16* qwTh   = XoutLo + XOUT_ELEMS;               // 384*384 each
    u16* qwTl   = qwTh + 147456;
    u16* kwTh   = qwTl + 147456;
    u16* kwTl   = kwTh + 147456;
    u16* vwTh   = kwTl + 147456;
    u16* vwTl   = vwTh + 147456;
    u16* w1Th   = vwTl + 147456;                     // 1152*384
    u16* w1Tl   = w1Th + 442368;
    u16* w2Th   = w1Tl + 442368;                     // 384*1152
    u16* w2Tl   = w2Th + 442368;
    u16* cvTh   = w2Tl + 442368;                     // 384*1536
    u16* cvTl   = cvTh + 589824;

    // ---- prep: split conversions + weight transposes
    hipLaunchKernelGGL(cvt_split, dim3(2048), dim3(256), 0, stream,
                       X_in, XinHi, XinLo, (size_t)M_IN * D_ / 4);
    hipLaunchKernelGGL(transpose_split, dim3(12, 12), dim3(256), 0, stream, qw, qwTh, qwTl, 384, 384);
    hipLaunchKernelGGL(transpose_split, dim3(12, 12), dim3(256), 0, stream, kw, kwTh, kwTl, 384, 384);
    hipLaunchKernelGGL(transpose_split, dim3(12, 12), dim3(256), 0, stream, vw, vwTh, vwTl, 384, 384);
    hipLaunchKernelGGL(transpose_split, dim3(36, 12), dim3(256), 0, stream, w1, w1Th, w1Tl, 384, 1152);
    hipLaunchKernelGGL(transpose_split, dim3(12, 36), dim3(256), 0, stream, w2, w2Th, w2Tl, 1152, 384);
    hipLaunchKernelGGL(prep_convw_split, dim3((384 * 1536 + 255) / 256), dim3(256), 0, stream,
                       conv_w, cvTh, cvTl);
    hipLaunchKernelGGL(bias_mean, dim3(1), dim3(64), 0, stream, rel_bias, biasv);

    // ---- init_proj conv (im2col split GEMM) -> tmpD, X_out = LN(tmpD)
    hipLaunchKernelGGL((gemm_split<1, 0, 0>), dim3(3, 98), dim3(256), 0, stream,
                       XinHi, XinLo, cvTh, cvTl, conv_b, tmpD, (u16*)0, (u16*)0, M_OUT, D_, 4 * D_);
    hipLaunchKernelGGL((ln_rows<0>), dim3(M_OUT / 4), dim3(256), 0, stream,
                       tmpD, Xout, XoutHi, XoutLo, ln_init_s, ln_init_b);

    // ---- K, V projections (f32 out, parked in dead A-region)
    hipLaunchKernelGGL((gemm_split<0, 0, 0>), dim3(3, 392), dim3(256), 0, stream,
                       XinHi, XinLo, kwTh, kwTl, kb, Kf, (u16*)0, (u16*)0, M_IN, D_, D_);
    hipLaunchKernelGGL((gemm_split<0, 0, 0>), dim3(3, 392), dim3(256), 0, stream,
                       XinHi, XinLo, vwTh, vwTl, vb, Vf, (u16*)0, (u16*)0, M_IN, D_, D_);

    for (int it = 0; it < 3; ++it) {
        hipLaunchKernelGGL((gemm_split<0, 0, 0>), dim3(3, 98), dim3(256), 0, stream,
                           XoutHi, XoutLo, qwTh, qwTl, qb, tmpD, (u16*)0, (u16*)0, M_OUT, D_, D_);
        hipLaunchKernelGGL(attn_scores, dim3(M_OUT / 4), dim3(256), 0, stream, tmpD, Kf, biasv, Pb);
        hipLaunchKernelGGL(nc_ln_add, dim3(M_OUT / 4), dim3(256), 0, stream,
                           Pb, Vf, ln_out_s, ln_out_b, Xout, XoutHi, XoutLo);
        hipLaunchKernelGGL((gemm_split<0, 1, 1>), dim3(9, 98), dim3(256), 0, stream,
                           XoutHi, XoutLo, w1Th, w1Tl, b1, (float*)0, h1Hi, h1Lo, M_OUT, HID_, D_);
        hipLaunchKernelGGL((gemm_split<0, 0, 0>), dim3(3, 98), dim3(256), 0, stream,
                           h1Hi, h1Lo, w2Th, w2Tl, b2, tmpD, (u16*)0, (u16*)0, M_OUT, D_, HID_);
        hipLaunchKernelGGL((ln_rows<1>), dim3(M_OUT / 4), dim3(256), 0, stream,
                           tmpD, Xout, XoutHi, XoutLo, mlp_s, mlp_b);
    }

    // ---- all A-region temporaries dead now; build dense A_ups/A_down from it==2's Pb
    hipMemsetAsync(Adown, 0, sizeof(float) * 2 * A_ELEMS, stream);
    hipLaunchKernelGGL(colsum_k, dim3((B_ * N_IN + 255) / 256), dim3(256), 0, stream, Pb, cs);
    hipLaunchKernelGGL(scatter_A, dim3((M_OUT * 9 + 255) / 256), dim3(256), 0, stream, Pb, cs, Aups, Adown);
}

// Round 6
// 957.142 us; speedup vs baseline: 2.0718x; 1.0000x over previous
//
#include <hip/hip_runtime.h>
#include <hip/hip_bf16.h>
#include <math.h>

#define B_    16
#define H_    56
#define W_    56
#define D_    384
#define HID_  1152
#define N_IN  3136
#define N_OUT 784
#define M_OUT (B_ * N_OUT)   // 12544
#define M_IN  (B_ * N_IN)    // 50176

#define XOUT_ELEMS ((size_t)M_OUT * D_)          // 4,816,896
#define A_ELEMS    ((size_t)B_ * N_OUT * N_IN)   // 39,337,984

typedef unsigned short u16;
using frag_ab = __attribute__((ext_vector_type(8))) short;  // 8 bf16 (4 VGPRs)
using frag_cd = __attribute__((ext_vector_type(4))) float;  // 4 fp32

__device__ __forceinline__ u16 f2b(float f) {
    __hip_bfloat16 h = __float2bfloat16(f);
    return *reinterpret_cast<u16*>(&h);
}
__device__ __forceinline__ void split2(float f, u16& hi, u16& lo) {
    __hip_bfloat16 h = __float2bfloat16(f);
    hi = *reinterpret_cast<u16*>(&h);
    float r = f - __bfloat162float(h);
    __hip_bfloat16 l = __float2bfloat16(r);
    lo = *reinterpret_cast<u16*>(&l);
}

__device__ __forceinline__ float wave_sum(float x) {
#pragma unroll
    for (int off = 32; off; off >>= 1) x += __shfl_xor(x, off, 64);
    return x;
}

#define GLD16(g, l) __builtin_amdgcn_global_load_lds( \
    (const __attribute__((address_space(1))) void*)(g), \
    (__attribute__((address_space(3))) void*)(l), 16, 0, 0)

// ---- f32 -> (hi, lo) bf16 planes, float4 vectorized
__global__ void cvt_split(const float* __restrict__ in, u16* __restrict__ hi,
                          u16* __restrict__ lo, size_t n4) {
    size_t i = (size_t)blockIdx.x * 256 + threadIdx.x;
    size_t stride = (size_t)gridDim.x * 256;
    for (; i < n4; i += stride) {
        float4 v = reinterpret_cast<const float4*>(in)[i];
        ushort4 h, l;
        split2(v.x, h.x, l.x); split2(v.y, h.y, l.y);
        split2(v.z, h.z, l.z); split2(v.w, h.w, l.w);
        reinterpret_cast<ushort4*>(hi)[i] = h;
        reinterpret_cast<ushort4*>(lo)[i] = l;
    }
}

// ---- W[K][N] f32 -> Bt[N][K] hi/lo bf16 (LDS-tiled transpose)
__global__ void transpose_split(const float* __restrict__ Wm, u16* __restrict__ Bh,
                                u16* __restrict__ Bl, int K, int N) {
    __shared__ float t[32][33];
    int k0 = blockIdx.y * 32, n0 = blockIdx.x * 32;
    int r = threadIdx.x >> 5, c = threadIdx.x & 31;
#pragma unroll
    for (int i = 0; i < 4; ++i) t[r + 8 * i][c] = Wm[(size_t)(k0 + r + 8 * i) * N + n0 + c];
    __syncthreads();
#pragma unroll
    for (int i = 0; i < 4; ++i) {
        u16 hi, lo;
        split2(t[c][r + 8 * i], hi, lo);
        size_t idx = (size_t)(n0 + r + 8 * i) * K + k0 + c;
        Bh[idx] = hi; Bl[idx] = lo;
    }
}

// ---- conv weight: wknT[n][kk] hi/lo, kk = p*384 + c ; conv_w OIHW [n][c][p]
__global__ void prep_convw_split(const float* __restrict__ cw, u16* __restrict__ Bh,
                                 u16* __restrict__ Bl) {
    int idx = blockIdx.x * 256 + threadIdx.x;
    if (idx >= 384 * 1536) return;
    int n = idx / 1536, kk = idx % 1536;
    int p = kk / 384, c = kk % 384;
    u16 hi, lo;
    split2(cw[n * 1536 + c * 4 + p], hi, lo);
    Bh[idx] = hi; Bl[idx] = lo;
}

__global__ void bias_mean(const float* __restrict__ rb, float* __restrict__ out) {
    if (threadIdx.x == 0) {
        float s = 0.f;
        for (int i = 0; i < 25; ++i) s += rb[i];
        *out = s / 25.0f;
    }
}

// ---- split-bf16 MFMA GEMM: C = A @ Bt^T + bias, f32-accurate via 3 MFMA passes.
// 128x128 tile, BK=64, 4 waves (2x2), 16x16x32 MFMA, global_load_lds staging,
// XOR-swizzle: LDS(row, b) = G(row, b ^ ((row&7)<<4)), read undoes with swzf.
template <int IM2COL, int GELU, int OUTSPLIT>
__global__ __launch_bounds__(256, 2) void gemm_split(
    const u16* __restrict__ Ah, const u16* __restrict__ Al,
    const u16* __restrict__ Bth, const u16* __restrict__ Btl,
    const float* __restrict__ bias, float* __restrict__ Cf,
    u16* __restrict__ Chi, u16* __restrict__ Clo,
    int M, int N, int K)
{
    __shared__ u16 sAh[128 * 64];
    __shared__ u16 sAl[128 * 64];
    __shared__ u16 sBh[128 * 64];
    __shared__ u16 sBl[128 * 64];
    const int t = threadIdx.x;
    const int lane = t & 63;
    const int w = t >> 6;
    const int wr = w >> 1, wc = w & 1;
    const int lm = lane & 15, lk = lane >> 4;
    const int m0 = blockIdx.y * 128;
    const int n0 = blockIdx.x * 128;

    const int rt = t >> 3, st = t & 7;                    // staging row-sub, 16B slot
    const int skel = ((st * 16) ^ ((rt & 7) << 4)) >> 1;  // swizzle-inverse src k-elem

    int pb4[4];
    if (IM2COL) {
#pragma unroll
        for (int i = 0; i < 4; ++i) {
            int m = m0 + i * 32 + rt;
            int bb = m / N_OUT, o = m - bb * N_OUT;
            pb4[i] = bb * N_IN + (o / 28) * 112 + (o % 28) * 2;
        }
    }

    frag_cd acc[4][4];
#pragma unroll
    for (int i = 0; i < 4; ++i)
#pragma unroll
        for (int j = 0; j < 4; ++j) acc[i][j] = (frag_cd){0.f, 0.f, 0.f, 0.f};

    const int swzf = (lm & 7) << 4;

    for (int kt = 0; kt < K; kt += 64) {
#pragma unroll
        for (int i = 0; i < 4; ++i) {
            int r = i * 32 + rt;
            size_t aoff;
            if (IM2COL) {
                int k = kt + skel;
                int p = k / 384, c = k - p * 384;
                aoff = ((size_t)pb4[i] + (p >> 1) * 56 + (p & 1)) * 384 + c;
            } else {
                aoff = (size_t)(m0 + r) * K + kt + skel;
            }
            GLD16(Ah + aoff, &sAh[i * 2048 + t * 8]);
            GLD16(Al + aoff, &sAl[i * 2048 + t * 8]);
            size_t boff = (size_t)(n0 + r) * K + kt + skel;
            GLD16(Bth + boff, &sBh[i * 2048 + t * 8]);
            GLD16(Btl + boff, &sBl[i * 2048 + t * 8]);
        }
        __syncthreads();

#pragma unroll
        for (int h = 0; h < 2; ++h) {
            const int kb = (h * 64 + lk * 16) ^ swzf;
            frag_ab ah[4], al[4], bh[4], bl[4];
#pragma unroll
            for (int m = 0; m < 4; ++m) {
                int arow = wr * 64 + m * 16 + lm;
                int brow = wc * 64 + m * 16 + lm;
                ah[m] = *reinterpret_cast<const frag_ab*>(reinterpret_cast<const char*>(sAh) + arow * 128 + kb);
                al[m] = *reinterpret_cast<const frag_ab*>(reinterpret_cast<const char*>(sAl) + arow * 128 + kb);
                bh[m] = *reinterpret_cast<const frag_ab*>(reinterpret_cast<const char*>(sBh) + brow * 128 + kb);
                bl[m] = *reinterpret_cast<const frag_ab*>(reinterpret_cast<const char*>(sBl) + brow * 128 + kb);
            }
#pragma unroll
            for (int m = 0; m < 4; ++m)
#pragma unroll
                for (int n = 0; n < 4; ++n) {
                    acc[m][n] = __builtin_amdgcn_mfma_f32_16x16x32_bf16(ah[m], bh[n], acc[m][n], 0, 0, 0);
                    acc[m][n] = __builtin_amdgcn_mfma_f32_16x16x32_bf16(al[m], bh[n], acc[m][n], 0, 0, 0);
                    acc[m][n] = __builtin_amdgcn_mfma_f32_16x16x32_bf16(ah[m], bl[n], acc[m][n], 0, 0, 0);
                }
        }
        __syncthreads();
    }

    // epilogue: C/D layout col=lane&15, row=(lane>>4)*4+reg (m89-verified)
#pragma unroll
    for (int m = 0; m < 4; ++m) {
#pragma unroll
        for (int n = 0; n < 4; ++n) {
            int row0 = m0 + wr * 64 + m * 16 + lk * 4;
            int col  = n0 + wc * 64 + n * 16 + lm;
            float bv = bias[col];
#pragma unroll
            for (int r = 0; r < 4; ++r) {
                float v = acc[m][n][r] + bv;
                if (GELU) v = 0.5f * v * (1.0f + erff(v * 0.70710678118654752f));
                size_t idx = (size_t)(row0 + r) * N + col;
                if (OUTSPLIT) {
                    u16 hi, lo; split2(v, hi, lo);
                    Chi[idx] = hi; Clo[idx] = lo;
                } else {
                    Cf[idx] = v;
                }
            }
        }
    }
}

// ---- row LayerNorm over D=384; writes f32 dst + hi/lo bf16 planes; ADD: dst += LN
template <int ADD>
__global__ __launch_bounds__(256) void ln_rows(
    const float* __restrict__ src, float* __restrict__ dst,
    u16* __restrict__ dhi, u16* __restrict__ dlo,
    const float* __restrict__ s, const float* __restrict__ bvec)
{
    int wid = blockIdx.x * 4 + (threadIdx.x >> 6);
    int lane = threadIdx.x & 63;
    const float* r = src + (size_t)wid * D_;
    float v[6]; float sum = 0.f;
#pragma unroll
    for (int t = 0; t < 6; ++t) { v[t] = r[lane + 64 * t]; sum += v[t]; }
    sum = wave_sum(sum);
    float mean = sum * (1.0f / D_);
    float vs = 0.f;
#pragma unroll
    for (int t = 0; t < 6; ++t) { float d = v[t] - mean; vs += d * d; }
    vs = wave_sum(vs);
    float rstd = rsqrtf(vs * (1.0f / D_) + 1e-5f);
    float* wo = dst + (size_t)wid * D_;
    u16* wh = dhi + (size_t)wid * D_;
    u16* wl = dlo + (size_t)wid * D_;
#pragma unroll
    for (int t = 0; t < 6; ++t) {
        int d = lane + 64 * t;
        float o = (v[t] - mean) * rstd * s[d] + bvec[d];
        float nv = ADD ? (wo[d] + o) : o;
        wo[d] = nv;
        u16 hi, lo; split2(nv, hi, lo);
        wh[d] = hi; wl[d] = lo;
    }
}

// ---- fused: windowed scores + softmax -> P, then new_centers = P@V,
//      X_out += LN(new_centers), refresh hi/lo planes. One wave per (b,o).
__global__ __launch_bounds__(256) void attn_nc(
    const float* __restrict__ Q, const float* __restrict__ Kb,
    const float* __restrict__ Vb, const float* __restrict__ biasp,
    float* __restrict__ P, const float* __restrict__ lns,
    const float* __restrict__ lnb, float* __restrict__ Xout,
    u16* __restrict__ Xhi, u16* __restrict__ Xlo)
{
    int wid = blockIdx.x * 4 + (threadIdx.x >> 6);   // (b,o)
    int lane = threadIdx.x & 63;
    int b = wid / N_OUT, o = wid % N_OUT;
    int yo = o / 28, xo = o % 28;
    float q[6];
    const float* qr = Q + (size_t)wid * D_;
#pragma unroll
    for (int t = 0; t < 6; ++t) q[t] = qr[lane + 64 * t];

    float s[9]; bool valid[9];
#pragma unroll
    for (int j = 0; j < 9; ++j) {
        int dy = j / 3 - 1, dx = j % 3 - 1;
        int yi = 2 * yo + dy, xi = 2 * xo + dx;
        bool ok = (yi >= 0) && (yi < H_) && (xi >= 0) && (xi < W_);
        valid[j] = ok;
        float acc = 0.f;
        if (ok) {
            const float* kr = Kb + ((size_t)(b * N_IN + yi * W_ + xi)) * D_;
#pragma unroll
            for (int t = 0; t < 6; ++t) acc += q[t] * kr[lane + 64 * t];
        }
        s[j] = acc;
    }
#pragma unroll
    for (int j = 0; j < 9; ++j) s[j] = wave_sum(s[j]);
    float bias = *biasp;
    float mx = -1e30f;
#pragma unroll
    for (int j = 0; j < 9; ++j) if (valid[j]) mx = fmaxf(mx, s[j] + bias);
    float e[9]; float tot = 0.f;
#pragma unroll
    for (int j = 0; j < 9; ++j) { e[j] = valid[j] ? expf(s[j] + bias - mx) : 0.0f; tot += e[j]; }
    float inv = 1.0f / tot;
#pragma unroll
    for (int j = 0; j < 9; ++j) e[j] *= inv;
    if (lane < 12) P[(size_t)wid * 12 + lane] = (lane < 9) ? e[lane] : 0.0f;

    // ---- P @ V over the window
    float acc[6] = {0, 0, 0, 0, 0, 0};
#pragma unroll
    for (int j = 0; j < 9; ++j) {
        if (valid[j]) {
            int dy = j / 3 - 1, dx = j % 3 - 1;
            int yi = 2 * yo + dy, xi = 2 * xo + dx;
            const float* vr = Vb + ((size_t)(b * N_IN + yi * W_ + xi)) * D_;
#pragma unroll
            for (int t = 0; t < 6; ++t) acc[t] += e[j] * vr[lane + 64 * t];
        }
    }
    float sum = 0.f;
#pragma unroll
    for (int t = 0; t < 6; ++t) sum += acc[t];
    sum = wave_sum(sum);
    float mean = sum * (1.0f / D_);
    float vs = 0.f;
#pragma unroll
    for (int t = 0; t < 6; ++t) { float d = acc[t] - mean; vs += d * d; }
    vs = wave_sum(vs);
    float rstd = rsqrtf(vs * (1.0f / D_) + 1e-5f);
    float* wo = Xout + (size_t)wid * D_;
    u16* wh = Xhi + (size_t)wid * D_;
    u16* wl = Xlo + (size_t)wid * D_;
#pragma unroll
    for (int t = 0; t < 6; ++t) {
        int d = lane + 64 * t;
        float nv = wo[d] + (acc[t] - mean) * rstd * lns[d] + lnb[d];
        wo[d] = nv;
        u16 hi, lo; split2(nv, hi, lo);
        wh[d] = hi; wl[d] = lo;
    }
}

// ---- per-(b, input pixel) column sum of A_ups
__global__ void colsum_k(const float* __restrict__ P, float* __restrict__ cs) {
    int idx = blockIdx.x * 256 + threadIdx.x;
    if (idx >= B_ * N_IN) return;
    int b = idx / N_IN, i = idx % N_IN;
    int yi = i / W_, xi = i % W_;
    float sum = 0.f;
    int yc = yi >> 1, xc = xi >> 1;
    for (int yo = yc - 1; yo <= yc + 1; ++yo) {
        if (yo < 0 || yo >= 28) continue;
        int dy = yi - 2 * yo;
        if (dy < -1 || dy > 1) continue;
        for (int xo = xc - 1; xo <= xc + 1; ++xo) {
            if (xo < 0 || xo >= 28) continue;
            int dx = xi - 2 * xo;
            if (dx < -1 || dx > 1) continue;
            int j = (dy + 1) * 3 + (dx + 1);
            sum += P[((size_t)(b * N_OUT + yo * 28 + xo)) * 12 + j];
        }
    }
    cs[idx] = sum;
}

// ---- dense A_ups/A_down writer: one block per (b,o) row; zero row then fix window
__global__ __launch_bounds__(256) void write_A(
    const float* __restrict__ P, const float* __restrict__ cs,
    float* __restrict__ Aups, float* __restrict__ Adown)
{
    int wid = blockIdx.x;                 // (b,o)
    int b = wid / N_OUT, o = wid % N_OUT;
    int yo = o / 28, xo = o % 28;
    float4 z = {0.f, 0.f, 0.f, 0.f};
    float4* up = reinterpret_cast<float4*>(Aups + (size_t)wid * N_IN);
    float4* dn = reinterpret_cast<float4*>(Adown + (size_t)wid * N_IN);
    for (int i = threadIdx.x; i < N_IN / 4; i += 256) { up[i] = z; dn[i] = z; }
    __syncthreads();
    int j = threadIdx.x;
    if (j < 9) {
        int dy = j / 3 - 1, dx = j % 3 - 1;
        int yi = 2 * yo + dy, xi = 2 * xo + dx;
        if (yi >= 0 && yi < H_ && xi >= 0 && xi < W_) {
            int i = yi * W_ + xi;
            float p = P[(size_t)wid * 12 + j];
            Aups[(size_t)wid * N_IN + i] = p;
            Adown[(size_t)wid * N_IN + i] = p / (1e-10f + cs[b * N_IN + i]);
        }
    }
}

extern "C" void kernel_launch(void* const* d_in, const int* in_sizes, int n_in,
                              void* d_out, int out_size, void* d_ws, size_t ws_size,
                              hipStream_t stream)
{
    const float* X_in      = (const float*)d_in[0];
    const float* conv_w    = (const float*)d_in[1];
    const float* conv_b    = (const float*)d_in[2];
    const float* ln_init_s = (const float*)d_in[3];
    const float* ln_init_b = (const float*)d_in[4];
    const float* qw        = (const float*)d_in[5];
    const float* qb        = (const float*)d_in[6];
    const float* kw        = (const float*)d_in[7];
    const float* kb        = (const float*)d_in[8];
    const float* vw        = (const float*)d_in[9];
    const float* vb        = (const float*)d_in[10];
    const float* ln_out_s  = (const float*)d_in[11];
    const float* ln_out_b  = (const float*)d_in[12];
    const float* w1        = (const float*)d_in[13];
    const float* b1        = (const float*)d_in[14];
    const float* w2        = (const float*)d_in[15];
    const float* b2        = (const float*)d_in[16];
    const float* mlp_s     = (const float*)d_in[17];
    const float* mlp_b     = (const float*)d_in[18];
    const float* rel_bias  = (const float*)d_in[19];
    (void)in_sizes; (void)n_in; (void)out_size; (void)ws_size;

    float* out   = (float*)d_out;
    float* Xout  = out;                    // (M_OUT, D) f32 — final output 0
    float* Adown = out + XOUT_ELEMS;       // (B, N_OUT, N_IN)
    float* Aups  = Adown + A_ELEMS;

    // dead A-region overlays (all dead before the final write_A):
    float* Abase = Adown;                            // 2*A_ELEMS floats total
    float* Vf    = Abase;                            // M_IN*D f32 (77MB)
    float* Kf    = Abase + (size_t)M_IN * D_;        // 77MB
    u16* XinHi = (u16*)(Abase + 38535168);           // M_IN*D u16
    u16* XinLo = (u16*)(Abase + 48168960);
    u16* h1Hi  = (u16*)(Abase + 57802752);           // M_OUT*HID u16
    u16* h1Lo  = (u16*)(Abase + 65028096);

    float* ws    = (float*)d_ws;
    float* tmpD  = ws;                               // M_OUT*D f32 (conv out / Q / h2)
    float* Pb    = tmpD + XOUT_ELEMS;                // M_OUT*12
    float* cs    = Pb + (size_t)M_OUT * 12;          // B_*N_IN
    float* biasv = cs + B_ * N_IN;                   // 4
    u16* XoutHi = (u16*)(biasv + 4);                 // M_OUT*D
    u16* XoutLo = XoutHi + XOUT_ELEMS;
    u16* qwTh   = XoutLo + XOUT_ELEMS;               // 384*384 each
    u16* qwTl   = qwTh + 147456;
    u16* kwTh   = qwTl + 147456;
    u16* kwTl   = kwTh + 147456;
    u16* vwTh   = kwTl + 147456;
    u16* vwTl   = vwTh + 147456;
    u16* w1Th   = vwTl + 147456;                     // 1152*384
    u16* w1Tl   = w1Th + 442368;
    u16* w2Th   = w1Tl + 442368;                     // 384*1152
    u16* w2Tl   = w2Th + 442368;
    u16* cvTh   = w2Tl + 442368;                     // 384*1536
    u16* cvTl   = cvTh + 589824;

    // ---- prep: split conversions + weight transposes
    hipLaunchKernelGGL(cvt_split, dim3(2048), dim3(256), 0, stream,
                       X_in, XinHi, XinLo, (size_t)M_IN * D_ / 4);
    hipLaunchKernelGGL(transpose_split, dim3(12, 12), dim3(256), 0, stream, qw, qwTh, qwTl, 384, 384);
    hipLaunchKernelGGL(transpose_split, dim3(12, 12), dim3(256), 0, stream, kw, kwTh, kwTl, 384, 384);
    hipLaunchKernelGGL(transpose_split, dim3(12, 12), dim3(256), 0, stream, vw, vwTh, vwTl, 384, 384);
    hipLaunchKernelGGL(transpose_split, dim3(36, 12), dim3(256), 0, stream, w1, w1Th, w1Tl, 384, 1152);
    hipLaunchKernelGGL(transpose_split, dim3(12, 36), dim3(256), 0, stream, w2, w2Th, w2Tl, 1152, 384);
    hipLaunchKernelGGL(prep_convw_split, dim3((384 * 1536 + 255) / 256), dim3(256), 0, stream,
                       conv_w, cvTh, cvTl);
    hipLaunchKernelGGL(bias_mean, dim3(1), dim3(64), 0, stream, rel_bias, biasv);

    // ---- init_proj conv (im2col split GEMM) -> tmpD, X_out = LN(tmpD)
    hipLaunchKernelGGL((gemm_split<1, 0, 0>), dim3(3, 98), dim3(256), 0, stream,
                       XinHi, XinLo, cvTh, cvTl, conv_b, tmpD, (u16*)0, (u16*)0, M_OUT, D_, 4 * D_);
    hipLaunchKernelGGL((ln_rows<0>), dim3(M_OUT / 4), dim3(256), 0, stream,
                       tmpD, Xout, XoutHi, XoutLo, ln_init_s, ln_init_b);

    // ---- K, V projections (f32 out, parked in dead A-region)
    hipLaunchKernelGGL((gemm_split<0, 0, 0>), dim3(3, 392), dim3(256), 0, stream,
                       XinHi, XinLo, kwTh, kwTl, kb, Kf, (u16*)0, (u16*)0, M_IN, D_, D_);
    hipLaunchKernelGGL((gemm_split<0, 0, 0>), dim3(3, 392), dim3(256), 0, stream,
                       XinHi, XinLo, vwTh, vwTl, vb, Vf, (u16*)0, (u16*)0, M_IN, D_, D_);

    for (int it = 0; it < 3; ++it) {
        hipLaunchKernelGGL((gemm_split<0, 0, 0>), dim3(3, 98), dim3(256), 0, stream,
                           XoutHi, XoutLo, qwTh, qwTl, qb, tmpD, (u16*)0, (u16*)0, M_OUT, D_, D_);
        hipLaunchKernelGGL(attn_nc, dim3(M_OUT / 4), dim3(256), 0, stream,
                           tmpD, Kf, Vf, biasv, Pb, ln_out_s, ln_out_b, Xout, XoutHi, XoutLo);
        hipLaunchKernelGGL((gemm_split<0, 1, 1>), dim3(9, 98), dim3(256), 0, stream,
                           XoutHi, XoutLo, w1Th, w1Tl, b1, (float*)0, h1Hi, h1Lo, M_OUT, HID_, D_);
        hipLaunchKernelGGL((gemm_split<0, 0, 0>), dim3(3, 98), dim3(256), 0, stream,
                           h1Hi, h1Lo, w2Th, w2Tl, b2, tmpD, (u16*)0, (u16*)0, M_OUT, D_, HID_);
        hipLaunchKernelGGL((ln_rows<1>), dim3(M_OUT / 4), dim3(256), 0, stream,
                           tmpD, Xout, XoutHi, XoutLo, mlp_s, mlp_b);
    }

    // ---- all A-region temporaries dead now; build dense A_ups/A_down from it==2's Pb
    hipLaunchKernelGGL(colsum_k, dim3((B_ * N_IN + 255) / 256), dim3(256), 0, stream, Pb, cs);
    hipLaunchKernelGGL(write_A, dim3(M_OUT), dim3(256), 0, stream, Pb, cs, Aups, Adown);
}

// Round 7
// 866.665 us; speedup vs baseline: 2.2881x; 1.1044x over previous
//
#include <hip/hip_runtime.h>
#include <hip/hip_bf16.h>
#include <math.h>

#define B_    16
#define H_    56
#define W_    56
#define D_    384
#define HID_  1152
#define N_IN  3136
#define N_OUT 784
#define M_OUT (B_ * N_OUT)   // 12544
#define M_IN  (B_ * N_IN)    // 50176
#define KVSTR 768

#define XOUT_ELEMS ((size_t)M_OUT * D_)          // 4,816,896
#define A_ELEMS    ((size_t)B_ * N_OUT * N_IN)   // 39,337,984

typedef unsigned short u16;
using frag_ab = __attribute__((ext_vector_type(8))) short;  // 8 bf16 (4 VGPRs)
using frag_cd = __attribute__((ext_vector_type(4))) float;  // 4 fp32

__device__ __forceinline__ void split2(float f, u16& hi, u16& lo) {
    __hip_bfloat16 h = __float2bfloat16(f);
    hi = *reinterpret_cast<u16*>(&h);
    float r = f - __bfloat162float(h);
    __hip_bfloat16 l = __float2bfloat16(r);
    lo = *reinterpret_cast<u16*>(&l);
}

__device__ __forceinline__ float wave_sum(float x) {
#pragma unroll
    for (int off = 32; off; off >>= 1) x += __shfl_xor(x, off, 64);
    return x;
}

#define GLD16(g, l) __builtin_amdgcn_global_load_lds( \
    (const __attribute__((address_space(1))) void*)(g), \
    (__attribute__((address_space(3))) void*)(l), 16, 0, 0)

// ---- f32 -> (hi, lo) bf16 planes, float4 vectorized
__global__ void cvt_split(const float* __restrict__ in, u16* __restrict__ hi,
                          u16* __restrict__ lo, size_t n4) {
    size_t i = (size_t)blockIdx.x * 256 + threadIdx.x;
    size_t stride = (size_t)gridDim.x * 256;
    for (; i < n4; i += stride) {
        float4 v = reinterpret_cast<const float4*>(in)[i];
        ushort4 h, l;
        split2(v.x, h.x, l.x); split2(v.y, h.y, l.y);
        split2(v.z, h.z, l.z); split2(v.w, h.w, l.w);
        reinterpret_cast<ushort4*>(hi)[i] = h;
        reinterpret_cast<ushort4*>(lo)[i] = l;
    }
}

// ---- W[K][N] f32 -> Bt[N][K] hi/lo bf16 (LDS-tiled transpose)
__global__ void transpose_split(const float* __restrict__ Wm, u16* __restrict__ Bh,
                                u16* __restrict__ Bl, int K, int N) {
    __shared__ float t[32][33];
    int k0 = blockIdx.y * 32, n0 = blockIdx.x * 32;
    int r = threadIdx.x >> 5, c = threadIdx.x & 31;
#pragma unroll
    for (int i = 0; i < 4; ++i) t[r + 8 * i][c] = Wm[(size_t)(k0 + r + 8 * i) * N + n0 + c];
    __syncthreads();
#pragma unroll
    for (int i = 0; i < 4; ++i) {
        u16 hi, lo;
        split2(t[c][r + 8 * i], hi, lo);
        size_t idx = (size_t)(n0 + r + 8 * i) * K + k0 + c;
        Bh[idx] = hi; Bl[idx] = lo;
    }
}

// ---- conv weight: wknT[n][kk] hi/lo, kk = p*384 + c ; conv_w OIHW [n][c][p]
__global__ void prep_convw_split(const float* __restrict__ cw, u16* __restrict__ Bh,
                                 u16* __restrict__ Bl) {
    int idx = blockIdx.x * 256 + threadIdx.x;
    if (idx >= 384 * 1536) return;
    int n = idx / 1536, kk = idx % 1536;
    int p = kk / 384, c = kk % 384;
    u16 hi, lo;
    split2(cw[n * 1536 + c * 4 + p], hi, lo);
    Bh[idx] = hi; Bl[idx] = lo;
}

__global__ void bias_mean(const float* __restrict__ rb, float* __restrict__ out) {
    if (threadIdx.x == 0) {
        float s = 0.f;
        for (int i = 0; i < 25; ++i) s += rb[i];
        *out = s / 25.0f;
    }
}

// ---- concat kb|vb -> kvb[768]
__global__ void concat_bias(const float* __restrict__ a, const float* __restrict__ b,
                            float* __restrict__ o) {
    int i = threadIdx.x + blockIdx.x * 256;
    if (i < 384) o[i] = a[i];
    else if (i < 768) o[i] = b[i - 384];
}

// ---- split-bf16 MFMA GEMM: C = A @ Bt^T + bias, f32-accurate via 3 MFMA passes.
// 128x128 tile, BK=64, 4 waves (2x2), 16x16x32 MFMA, global_load_lds staging,
// XOR-swizzle: LDS(row, b) = G(row, b ^ ((row&7)<<4)), read undoes with swzf.
// XCD remap: linear wgid d -> chunk of 8 M-panels x gridDim.x; d and d+8 land on
// the same XCD with the same M-panel (A-tile L2 reuse across N-blocks).
template <int IM2COL, int GELU, int OUTSPLIT>
__global__ __launch_bounds__(256, 2) void gemm_split(
    const u16* __restrict__ Ah, const u16* __restrict__ Al,
    const u16* __restrict__ Bth, const u16* __restrict__ Btl,
    const float* __restrict__ bias, float* __restrict__ Cf,
    u16* __restrict__ Chi, u16* __restrict__ Clo,
    int M, int N, int K)
{
    __shared__ u16 sAh[128 * 64];
    __shared__ u16 sAl[128 * 64];
    __shared__ u16 sBh[128 * 64];
    __shared__ u16 sBl[128 * 64];
    const int t = threadIdx.x;
    const int lane = t & 63;
    const int w = t >> 6;
    const int wr = w >> 1, wc = w & 1;
    const int lm = lane & 15, lk = lane >> 4;

    // ---- XCD-aware (y,x) remap
    const int gx = gridDim.x, ny = gridDim.y;
    int d = blockIdx.y * gx + blockIdx.x;
    const int covered = (ny >> 3) * 8 * gx;
    int m_y, n_x;
    if (d < covered) {
        int c = d / (8 * gx), l = d % (8 * gx);
        m_y = c * 8 + (l & 7);
        n_x = l >> 3;
    } else {
        int l = d - covered;
        m_y = (ny & ~7) + l / gx;
        n_x = l % gx;
    }
    const int m0 = m_y * 128;
    const int n0 = n_x * 128;

    const int rt = t >> 3, st = t & 7;                    // staging row-sub, 16B slot
    const int skel = ((st * 16) ^ ((rt & 7) << 4)) >> 1;  // swizzle-inverse src k-elem

    int pb4[4];
    if (IM2COL) {
#pragma unroll
        for (int i = 0; i < 4; ++i) {
            int m = m0 + i * 32 + rt;
            int bb = m / N_OUT, o = m - bb * N_OUT;
            pb4[i] = bb * N_IN + (o / 28) * 112 + (o % 28) * 2;
        }
    }

    frag_cd acc[4][4];
#pragma unroll
    for (int i = 0; i < 4; ++i)
#pragma unroll
        for (int j = 0; j < 4; ++j) acc[i][j] = (frag_cd){0.f, 0.f, 0.f, 0.f};

    const int swzf = (lm & 7) << 4;

    for (int kt = 0; kt < K; kt += 64) {
#pragma unroll
        for (int i = 0; i < 4; ++i) {
            int r = i * 32 + rt;
            size_t aoff;
            if (IM2COL) {
                int k = kt + skel;
                int p = k / 384, c = k - p * 384;
                aoff = ((size_t)pb4[i] + (p >> 1) * 56 + (p & 1)) * 384 + c;
            } else {
                aoff = (size_t)(m0 + r) * K + kt + skel;
            }
            GLD16(Ah + aoff, &sAh[i * 2048 + t * 8]);
            GLD16(Al + aoff, &sAl[i * 2048 + t * 8]);
            size_t boff = (size_t)(n0 + r) * K + kt + skel;
            GLD16(Bth + boff, &sBh[i * 2048 + t * 8]);
            GLD16(Btl + boff, &sBl[i * 2048 + t * 8]);
        }
        __syncthreads();

#pragma unroll
        for (int h = 0; h < 2; ++h) {
            const int kb = (h * 64 + lk * 16) ^ swzf;
            frag_ab ah[4], al[4], bh[4], bl[4];
#pragma unroll
            for (int m = 0; m < 4; ++m) {
                int arow = wr * 64 + m * 16 + lm;
                int brow = wc * 64 + m * 16 + lm;
                ah[m] = *reinterpret_cast<const frag_ab*>(reinterpret_cast<const char*>(sAh) + arow * 128 + kb);
                al[m] = *reinterpret_cast<const frag_ab*>(reinterpret_cast<const char*>(sAl) + arow * 128 + kb);
                bh[m] = *reinterpret_cast<const frag_ab*>(reinterpret_cast<const char*>(sBh) + brow * 128 + kb);
                bl[m] = *reinterpret_cast<const frag_ab*>(reinterpret_cast<const char*>(sBl) + brow * 128 + kb);
            }
#pragma unroll
            for (int m = 0; m < 4; ++m)
#pragma unroll
                for (int n = 0; n < 4; ++n) {
                    acc[m][n] = __builtin_amdgcn_mfma_f32_16x16x32_bf16(ah[m], bh[n], acc[m][n], 0, 0, 0);
                    acc[m][n] = __builtin_amdgcn_mfma_f32_16x16x32_bf16(al[m], bh[n], acc[m][n], 0, 0, 0);
                    acc[m][n] = __builtin_amdgcn_mfma_f32_16x16x32_bf16(ah[m], bl[n], acc[m][n], 0, 0, 0);
                }
        }
        __syncthreads();
    }

    // epilogue: C/D layout col=lane&15, row=(lane>>4)*4+reg (m89-verified)
#pragma unroll
    for (int m = 0; m < 4; ++m) {
#pragma unroll
        for (int n = 0; n < 4; ++n) {
            int row0 = m0 + wr * 64 + m * 16 + lk * 4;
            int col  = n0 + wc * 64 + n * 16 + lm;
            float bv = bias[col];
#pragma unroll
            for (int r = 0; r < 4; ++r) {
                float v = acc[m][n][r] + bv;
                if (GELU) v = 0.5f * v * (1.0f + erff(v * 0.70710678118654752f));
                size_t idx = (size_t)(row0 + r) * N + col;
                if (OUTSPLIT) {
                    u16 hi, lo; split2(v, hi, lo);
                    Chi[idx] = hi; Clo[idx] = lo;
                } else {
                    Cf[idx] = v;
                }
            }
        }
    }
}

// ---- row LayerNorm over D=384; writes f32 dst + hi/lo bf16 planes; ADD: dst += LN
template <int ADD>
__global__ __launch_bounds__(256) void ln_rows(
    const float* __restrict__ src, float* __restrict__ dst,
    u16* __restrict__ dhi, u16* __restrict__ dlo,
    const float* __restrict__ s, const float* __restrict__ bvec)
{
    int wid = blockIdx.x * 4 + (threadIdx.x >> 6);
    int lane = threadIdx.x & 63;
    const float* r = src + (size_t)wid * D_;
    float v[6]; float sum = 0.f;
#pragma unroll
    for (int t = 0; t < 6; ++t) { v[t] = r[lane + 64 * t]; sum += v[t]; }
    sum = wave_sum(sum);
    float mean = sum * (1.0f / D_);
    float vs = 0.f;
#pragma unroll
    for (int t = 0; t < 6; ++t) { float d = v[t] - mean; vs += d * d; }
    vs = wave_sum(vs);
    float rstd = rsqrtf(vs * (1.0f / D_) + 1e-5f);
    float* wo = dst + (size_t)wid * D_;
    u16* wh = dhi + (size_t)wid * D_;
    u16* wl = dlo + (size_t)wid * D_;
#pragma unroll
    for (int t = 0; t < 6; ++t) {
        int d = lane + 64 * t;
        float o = (v[t] - mean) * rstd * s[d] + bvec[d];
        float nv = ADD ? (wo[d] + o) : o;
        wo[d] = nv;
        u16 hi, lo; split2(nv, hi, lo);
        wh[d] = hi; wl[d] = lo;
    }
}

// ---- fused: windowed scores + softmax -> P, then new_centers = P@V,
//      X_out += LN(new_centers), refresh hi/lo planes. One wave per (b,o).
//      K/V interleaved in one [row][768] buffer (K at +0, V at +384).
__global__ __launch_bounds__(256) void attn_nc(
    const float* __restrict__ Q, const float* __restrict__ KV,
    const float* __restrict__ biasp, float* __restrict__ P,
    const float* __restrict__ lns, const float* __restrict__ lnb,
    float* __restrict__ Xout, u16* __restrict__ Xhi, u16* __restrict__ Xlo)
{
    int wid = blockIdx.x * 4 + (threadIdx.x >> 6);   // (b,o)
    int lane = threadIdx.x & 63;
    int b = wid / N_OUT, o = wid % N_OUT;
    int yo = o / 28, xo = o % 28;
    float q[6];
    const float* qr = Q + (size_t)wid * D_;
#pragma unroll
    for (int t = 0; t < 6; ++t) q[t] = qr[lane + 64 * t];

    float s[9]; bool valid[9];
#pragma unroll
    for (int j = 0; j < 9; ++j) {
        int dy = j / 3 - 1, dx = j % 3 - 1;
        int yi = 2 * yo + dy, xi = 2 * xo + dx;
        bool ok = (yi >= 0) && (yi < H_) && (xi >= 0) && (xi < W_);
        valid[j] = ok;
        float acc = 0.f;
        if (ok) {
            const float* kr = KV + (size_t)(b * N_IN + yi * W_ + xi) * KVSTR;
#pragma unroll
            for (int t = 0; t < 6; ++t) acc += q[t] * kr[lane + 64 * t];
        }
        s[j] = acc;
    }
#pragma unroll
    for (int j = 0; j < 9; ++j) s[j] = wave_sum(s[j]);
    float bias = *biasp;
    float mx = -1e30f;
#pragma unroll
    for (int j = 0; j < 9; ++j) if (valid[j]) mx = fmaxf(mx, s[j] + bias);
    float e[9]; float tot = 0.f;
#pragma unroll
    for (int j = 0; j < 9; ++j) { e[j] = valid[j] ? expf(s[j] + bias - mx) : 0.0f; tot += e[j]; }
    float inv = 1.0f / tot;
#pragma unroll
    for (int j = 0; j < 9; ++j) e[j] *= inv;
    if (lane < 12) P[(size_t)wid * 12 + lane] = (lane < 9) ? e[lane] : 0.0f;

    // ---- P @ V over the window
    float acc[6] = {0, 0, 0, 0, 0, 0};
#pragma unroll
    for (int j = 0; j < 9; ++j) {
        if (valid[j]) {
            int dy = j / 3 - 1, dx = j % 3 - 1;
            int yi = 2 * yo + dy, xi = 2 * xo + dx;
            const float* vr = KV + (size_t)(b * N_IN + yi * W_ + xi) * KVSTR + 384;
#pragma unroll
            for (int t = 0; t < 6; ++t) acc[t] += e[j] * vr[lane + 64 * t];
        }
    }
    float sum = 0.f;
#pragma unroll
    for (int t = 0; t < 6; ++t) sum += acc[t];
    sum = wave_sum(sum);
    float mean = sum * (1.0f / D_);
    float vs = 0.f;
#pragma unroll
    for (int t = 0; t < 6; ++t) { float d = acc[t] - mean; vs += d * d; }
    vs = wave_sum(vs);
    float rstd = rsqrtf(vs * (1.0f / D_) + 1e-5f);
    float* wo = Xout + (size_t)wid * D_;
    u16* wh = Xhi + (size_t)wid * D_;
    u16* wl = Xlo + (size_t)wid * D_;
#pragma unroll
    for (int t = 0; t < 6; ++t) {
        int d = lane + 64 * t;
        float nv = wo[d] + (acc[t] - mean) * rstd * lns[d] + lnb[d];
        wo[d] = nv;
        u16 hi, lo; split2(nv, hi, lo);
        wh[d] = hi; wl[d] = lo;
    }
}

// ---- per-(b, input pixel) column sum of A_ups
__global__ void colsum_k(const float* __restrict__ P, float* __restrict__ cs) {
    int idx = blockIdx.x * 256 + threadIdx.x;
    if (idx >= B_ * N_IN) return;
    int b = idx / N_IN, i = idx % N_IN;
    int yi = i / W_, xi = i % W_;
    float sum = 0.f;
    int yc = yi >> 1, xc = xi >> 1;
    for (int yo = yc - 1; yo <= yc + 1; ++yo) {
        if (yo < 0 || yo >= 28) continue;
        int dy = yi - 2 * yo;
        if (dy < -1 || dy > 1) continue;
        for (int xo = xc - 1; xo <= xc + 1; ++xo) {
            if (xo < 0 || xo >= 28) continue;
            int dx = xi - 2 * xo;
            if (dx < -1 || dx > 1) continue;
            int j = (dy + 1) * 3 + (dx + 1);
            sum += P[((size_t)(b * N_OUT + yo * 28 + xo)) * 12 + j];
        }
    }
    cs[idx] = sum;
}

// ---- dense A_ups/A_down writer: one block per (b,o) row; zero row then fix window
__global__ __launch_bounds__(256) void write_A(
    const float* __restrict__ P, const float* __restrict__ cs,
    float* __restrict__ Aups, float* __restrict__ Adown)
{
    int wid = blockIdx.x;                 // (b,o)
    int b = wid / N_OUT, o = wid % N_OUT;
    int yo = o / 28, xo = o % 28;
    float4 z = {0.f, 0.f, 0.f, 0.f};
    float4* up = reinterpret_cast<float4*>(Aups + (size_t)wid * N_IN);
    float4* dn = reinterpret_cast<float4*>(Adown + (size_t)wid * N_IN);
    for (int i = threadIdx.x; i < N_IN / 4; i += 256) { up[i] = z; dn[i] = z; }
    __syncthreads();
    int j = threadIdx.x;
    if (j < 9) {
        int dy = j / 3 - 1, dx = j % 3 - 1;
        int yi = 2 * yo + dy, xi = 2 * xo + dx;
        if (yi >= 0 && yi < H_ && xi >= 0 && xi < W_) {
            int i = yi * W_ + xi;
            float p = P[(size_t)wid * 12 + j];
            Aups[(size_t)wid * N_IN + i] = p;
            Adown[(size_t)wid * N_IN + i] = p / (1e-10f + cs[b * N_IN + i]);
        }
    }
}

extern "C" void kernel_launch(void* const* d_in, const int* in_sizes, int n_in,
                              void* d_out, int out_size, void* d_ws, size_t ws_size,
                              hipStream_t stream)
{
    const float* X_in      = (const float*)d_in[0];
    const float* conv_w    = (const float*)d_in[1];
    const float* conv_b    = (const float*)d_in[2];
    const float* ln_init_s = (const float*)d_in[3];
    const float* ln_init_b = (const float*)d_in[4];
    const float* qw        = (const float*)d_in[5];
    const float* qb        = (const float*)d_in[6];
    const float* kw        = (const float*)d_in[7];
    const float* kb        = (const float*)d_in[8];
    const float* vw        = (const float*)d_in[9];
    const float* vb        = (const float*)d_in[10];
    const float* ln_out_s  = (const float*)d_in[11];
    const float* ln_out_b  = (const float*)d_in[12];
    const float* w1        = (const float*)d_in[13];
    const float* b1        = (const float*)d_in[14];
    const float* w2        = (const float*)d_in[15];
    const float* b2        = (const float*)d_in[16];
    const float* mlp_s     = (const float*)d_in[17];
    const float* mlp_b     = (const float*)d_in[18];
    const float* rel_bias  = (const float*)d_in[19];
    (void)in_sizes; (void)n_in; (void)out_size; (void)ws_size;

    float* out   = (float*)d_out;
    float* Xout  = out;                    // (M_OUT, D) f32 — final output 0
    float* Adown = out + XOUT_ELEMS;       // (B, N_OUT, N_IN)
    float* Aups  = Adown + A_ELEMS;

    // dead A-region overlays (all dead before the final write_A):
    float* Abase = Adown;                            // 2*A_ELEMS floats total
    float* KVf   = Abase;                            // M_IN*768 f32 (154MB): K|V interleaved
    u16* XinHi = (u16*)(Abase + 38535168);           // M_IN*D u16
    u16* XinLo = (u16*)(Abase + 48168960);
    u16* h1Hi  = (u16*)(Abase + 57802752);           // M_OUT*HID u16
    u16* h1Lo  = (u16*)(Abase + 65028096);

    float* ws    = (float*)d_ws;
    float* tmpD  = ws;                               // M_OUT*D f32 (conv out / Q / h2)
    float* Pb    = tmpD + XOUT_ELEMS;                // M_OUT*12
    float* cs    = Pb + (size_t)M_OUT * 12;          // B_*N_IN
    float* biasv = cs + B_ * N_IN;                   // 4
    float* kvb   = biasv + 4;                        // 768
    u16* XoutHi = (u16*)(kvb + 768);                 // M_OUT*D
    u16* XoutLo = XoutHi + XOUT_ELEMS;
    u16* qwTh   = XoutLo + XOUT_ELEMS;               // 384*384 each
    u16* qwTl   = qwTh + 147456;
    u16* kvTh   = qwTl + 147456;                     // 768*384 (kw rows then vw rows)
    u16* kvTl   = kvTh + 294912;
    u16* w1Th   = kvTl + 294912;                     // 1152*384
    u16* w1Tl   = w1Th + 442368;
    u16* w2Th   = w1Tl + 442368;                     // 384*1152
    u16* w2Tl   = w2Th + 442368;
    u16* cvTh   = w2Tl + 442368;                     // 384*1536
    u16* cvTl   = cvTh + 589824;

    // ---- prep: split conversions + weight transposes
    hipLaunchKernelGGL(cvt_split, dim3(2048), dim3(256), 0, stream,
                       X_in, XinHi, XinLo, (size_t)M_IN * D_ / 4);
    hipLaunchKernelGGL(transpose_split, dim3(12, 12), dim3(256), 0, stream, qw, qwTh, qwTl, 384, 384);
    hipLaunchKernelGGL(transpose_split, dim3(12, 12), dim3(256), 0, stream, kw, kvTh, kvTl, 384, 384);
    hipLaunchKernelGGL(transpose_split, dim3(12, 12), dim3(256), 0, stream,
                       vw, kvTh + 147456, kvTl + 147456, 384, 384);
    hipLaunchKernelGGL(transpose_split, dim3(36, 12), dim3(256), 0, stream, w1, w1Th, w1Tl, 384, 1152);
    hipLaunchKernelGGL(transpose_split, dim3(12, 36), dim3(256), 0, stream, w2, w2Th, w2Tl, 1152, 384);
    hipLaunchKernelGGL(prep_convw_split, dim3((384 * 1536 + 255) / 256), dim3(256), 0, stream,
                       conv_w, cvTh, cvTl);
    hipLaunchKernelGGL(bias_mean, dim3(1), dim3(64), 0, stream, rel_bias, biasv);
    hipLaunchKernelGGL(concat_bias, dim3(3), dim3(256), 0, stream, kb, vb, kvb);

    // ---- init_proj conv (im2col split GEMM) -> tmpD, X_out = LN(tmpD)
    hipLaunchKernelGGL((gemm_split<1, 0, 0>), dim3(3, 98), dim3(256), 0, stream,
                       XinHi, XinLo, cvTh, cvTl, conv_b, tmpD, (u16*)0, (u16*)0, M_OUT, D_, 4 * D_);
    hipLaunchKernelGGL((ln_rows<0>), dim3(M_OUT / 4), dim3(256), 0, stream,
                       tmpD, Xout, XoutHi, XoutLo, ln_init_s, ln_init_b);

    // ---- K|V projection (single GEMM, N=768, f32 out in dead A-region)
    hipLaunchKernelGGL((gemm_split<0, 0, 0>), dim3(6, 392), dim3(256), 0, stream,
                       XinHi, XinLo, kvTh, kvTl, kvb, KVf, (u16*)0, (u16*)0, M_IN, KVSTR, D_);

    for (int it = 0; it < 3; ++it) {
        hipLaunchKernelGGL((gemm_split<0, 0, 0>), dim3(3, 98), dim3(256), 0, stream,
                           XoutHi, XoutLo, qwTh, qwTl, qb, tmpD, (u16*)0, (u16*)0, M_OUT, D_, D_);
        hipLaunchKernelGGL(attn_nc, dim3(M_OUT / 4), dim3(256), 0, stream,
                           tmpD, KVf, biasv, Pb, ln_out_s, ln_out_b, Xout, XoutHi, XoutLo);
        hipLaunchKernelGGL((gemm_split<0, 1, 1>), dim3(9, 98), dim3(256), 0, stream,
                           XoutHi, XoutLo, w1Th, w1Tl, b1, (float*)0, h1Hi, h1Lo, M_OUT, HID_, D_);
        hipLaunchKernelGGL((gemm_split<0, 0, 0>), dim3(3, 98), dim3(256), 0, stream,
                           h1Hi, h1Lo, w2Th, w2Tl, b2, tmpD, (u16*)0, (u16*)0, M_OUT, D_, HID_);
        hipLaunchKernelGGL((ln_rows<1>), dim3(M_OUT / 4), dim3(256), 0, stream,
                           tmpD, Xout, XoutHi, XoutLo, mlp_s, mlp_b);
    }

    // ---- all A-region temporaries dead now; build dense A_ups/A_down from it==2's Pb
    hipLaunchKernelGGL(colsum_k, dim3((B_ * N_IN + 255) / 256), dim3(256), 0, stream, Pb, cs);
    hipLaunchKernelGGL(write_A, dim3(M_OUT), dim3(256), 0, stream, Pb, cs, Aups, Adown);
}

// Round 9
// 846.527 us; speedup vs baseline: 2.3426x; 1.0238x over previous
//
#include <hip/hip_runtime.h>
#include <hip/hip_bf16.h>
#include <math.h>

#define B_    16
#define H_    56
#define W_    56
#define D_    384
#define HID_  1152
#define N_IN  3136
#define N_OUT 784
#define M_OUT (B_ * N_OUT)   // 12544
#define M_IN  (B_ * N_IN)    // 50176
#define KVSTR 768

#define XOUT_ELEMS ((size_t)M_OUT * D_)          // 4,816,896
#define A_ELEMS    ((size_t)B_ * N_OUT * N_IN)   // 39,337,984

typedef unsigned short u16;
using frag_ab = __attribute__((ext_vector_type(8))) short;  // 8 bf16 (4 VGPRs)
using frag_cd = __attribute__((ext_vector_type(4))) float;  // 4 fp32

__device__ __forceinline__ void split2(float f, u16& hi, u16& lo) {
    __hip_bfloat16 h = __float2bfloat16(f);
    hi = *reinterpret_cast<u16*>(&h);
    float r = f - __bfloat162float(h);
    __hip_bfloat16 l = __float2bfloat16(r);
    lo = *reinterpret_cast<u16*>(&l);
}

__device__ __forceinline__ float wave_sum(float x) {
#pragma unroll
    for (int off = 32; off; off >>= 1) x += __shfl_xor(x, off, 64);
    return x;
}

#define GLD16(g, l) __builtin_amdgcn_global_load_lds( \
    (const __attribute__((address_space(1))) void*)(g), \
    (__attribute__((address_space(3))) void*)(l), 16, 0, 0)

// ---- f32 -> (hi, lo) bf16 planes, float4 vectorized
__global__ void cvt_split(const float* __restrict__ in, u16* __restrict__ hi,
                          u16* __restrict__ lo, size_t n4) {
    size_t i = (size_t)blockIdx.x * 256 + threadIdx.x;
    size_t stride = (size_t)gridDim.x * 256;
    for (; i < n4; i += stride) {
        float4 v = reinterpret_cast<const float4*>(in)[i];
        ushort4 h, l;
        split2(v.x, h.x, l.x); split2(v.y, h.y, l.y);
        split2(v.z, h.z, l.z); split2(v.w, h.w, l.w);
        reinterpret_cast<ushort4*>(hi)[i] = h;
        reinterpret_cast<ushort4*>(lo)[i] = l;
    }
}

// ---- W[K][N] f32 -> Bt[N][K] hi/lo bf16 (LDS-tiled transpose)
__global__ void transpose_split(const float* __restrict__ Wm, u16* __restrict__ Bh,
                                u16* __restrict__ Bl, int K, int N) {
    __shared__ float t[32][33];
    int k0 = blockIdx.y * 32, n0 = blockIdx.x * 32;
    int r = threadIdx.x >> 5, c = threadIdx.x & 31;
#pragma unroll
    for (int i = 0; i < 4; ++i) t[r + 8 * i][c] = Wm[(size_t)(k0 + r + 8 * i) * N + n0 + c];
    __syncthreads();
#pragma unroll
    for (int i = 0; i < 4; ++i) {
        u16 hi, lo;
        split2(t[c][r + 8 * i], hi, lo);
        size_t idx = (size_t)(n0 + r + 8 * i) * K + k0 + c;
        Bh[idx] = hi; Bl[idx] = lo;
    }
}

// ---- conv weight: wknT[n][kk] hi/lo, kk = p*384 + c ; conv_w OIHW [n][c][p]
__global__ void prep_convw_split(const float* __restrict__ cw, u16* __restrict__ Bh,
                                 u16* __restrict__ Bl) {
    int idx = blockIdx.x * 256 + threadIdx.x;
    if (idx >= 384 * 1536) return;
    int n = idx / 1536, kk = idx % 1536;
    int p = kk / 384, c = kk % 384;
    u16 hi, lo;
    split2(cw[n * 1536 + c * 4 + p], hi, lo);
    Bh[idx] = hi; Bl[idx] = lo;
}

__global__ void bias_mean(const float* __restrict__ rb, float* __restrict__ out) {
    if (threadIdx.x == 0) {
        float s = 0.f;
        for (int i = 0; i < 25; ++i) s += rb[i];
        *out = s / 25.0f;
    }
}

// ---- concat kb|vb -> kvb[768]
__global__ void concat_bias(const float* __restrict__ a, const float* __restrict__ b,
                            float* __restrict__ o) {
    int i = threadIdx.x + blockIdx.x * 256;
    if (i < 384) o[i] = a[i];
    else if (i < 768) o[i] = b[i - 384];
}

// ---- split-bf16 MFMA GEMM: C = A @ Bt^T + bias, f32-accurate via 3 MFMA passes
// (AhBh + AlBh + AhBl). 2-pass variant exists but is NOT accuracy-safe for this
// net (R8 post-mortem: any bf16-level error in X_out is ~10x amplified through
// softmax; keep PASSES=3 everywhere).
// 128xBN tile (BN=128 or 64), BK=64, 4 waves (2x2; each wave 64 x BN/2).
// BN=64: LDS 48KB -> 3 blocks/CU, doubles block count for N=384 GEMMs.
// global_load_lds staging; XOR-swizzle LDS(row,b)=G(row, b^((row&7)<<4)).
// XCD remap: chunk of 8 M-panels x gridDim.x so same-XCD blocks share an M-panel.
template <int IM2COL, int GELU, int OUTSPLIT, int PASSES, int BN>
__global__ __launch_bounds__(256, (BN == 64) ? 3 : 2) void gemm_split(
    const u16* __restrict__ Ah, const u16* __restrict__ Al,
    const u16* __restrict__ Bth, const u16* __restrict__ Btl,
    const float* __restrict__ bias, float* __restrict__ Cf,
    u16* __restrict__ Chi, u16* __restrict__ Clo,
    int M, int N, int K)
{
    constexpr int NF = BN / 32;          // n-frags per wave
    __shared__ u16 sAh[128 * 64];
    __shared__ u16 sAl[128 * 64];
    __shared__ u16 sBh[BN * 64];
    __shared__ u16 sBl[(PASSES == 3) ? BN * 64 : 8];
    const int t = threadIdx.x;
    const int lane = t & 63;
    const int w = t >> 6;
    const int wr = w >> 1, wc = w & 1;
    const int lm = lane & 15, lk = lane >> 4;

    // ---- XCD-aware (y,x) remap
    const int gx = gridDim.x, ny = gridDim.y;
    int d = blockIdx.y * gx + blockIdx.x;
    const int covered = (ny >> 3) * 8 * gx;
    int m_y, n_x;
    if (d < covered) {
        int c = d / (8 * gx), l = d % (8 * gx);
        m_y = c * 8 + (l & 7);
        n_x = l >> 3;
    } else {
        int l = d - covered;
        m_y = (ny & ~7) + l / gx;
        n_x = l % gx;
    }
    const int m0 = m_y * 128;
    const int n0 = n_x * BN;

    const int rt = t >> 3, st = t & 7;                    // staging row-sub, 16B slot
    const int skel = ((st * 16) ^ ((rt & 7) << 4)) >> 1;  // swizzle-inverse src k-elem

    int pb4[4];
    if (IM2COL) {
#pragma unroll
        for (int i = 0; i < 4; ++i) {
            int m = m0 + i * 32 + rt;
            int bb = m / N_OUT, o = m - bb * N_OUT;
            pb4[i] = bb * N_IN + (o / 28) * 112 + (o % 28) * 2;
        }
    }

    frag_cd acc[4][NF];
#pragma unroll
    for (int i = 0; i < 4; ++i)
#pragma unroll
        for (int j = 0; j < NF; ++j) acc[i][j] = (frag_cd){0.f, 0.f, 0.f, 0.f};

    const int swzf = (lm & 7) << 4;

    for (int kt = 0; kt < K; kt += 64) {
#pragma unroll
        for (int i = 0; i < 4; ++i) {
            int r = i * 32 + rt;
            size_t aoff;
            if (IM2COL) {
                int k = kt + skel;
                int p = k / 384, c = k - p * 384;
                aoff = ((size_t)pb4[i] + (p >> 1) * 56 + (p & 1)) * 384 + c;
            } else {
                aoff = (size_t)(m0 + r) * K + kt + skel;
            }
            GLD16(Ah + aoff, &sAh[i * 2048 + t * 8]);
            GLD16(Al + aoff, &sAl[i * 2048 + t * 8]);
        }
#pragma unroll
        for (int i = 0; i < BN / 32; ++i) {
            int r = i * 32 + rt;
            size_t boff = (size_t)(n0 + r) * K + kt + skel;
            GLD16(Bth + boff, &sBh[i * 2048 + t * 8]);
            if (PASSES == 3) GLD16(Btl + boff, &sBl[i * 2048 + t * 8]);
        }
        __syncthreads();

#pragma unroll
        for (int h = 0; h < 2; ++h) {
            const int kb = (h * 64 + lk * 16) ^ swzf;
            frag_ab ah[4], al[4], bh[NF], bl[NF];
#pragma unroll
            for (int m = 0; m < 4; ++m) {
                int arow = wr * 64 + m * 16 + lm;
                ah[m] = *reinterpret_cast<const frag_ab*>(reinterpret_cast<const char*>(sAh) + arow * 128 + kb);
                al[m] = *reinterpret_cast<const frag_ab*>(reinterpret_cast<const char*>(sAl) + arow * 128 + kb);
            }
#pragma unroll
            for (int n = 0; n < NF; ++n) {
                int brow = wc * (BN / 2) + n * 16 + lm;
                bh[n] = *reinterpret_cast<const frag_ab*>(reinterpret_cast<const char*>(sBh) + brow * 128 + kb);
                if (PASSES == 3)
                    bl[n] = *reinterpret_cast<const frag_ab*>(reinterpret_cast<const char*>(sBl) + brow * 128 + kb);
            }
#pragma unroll
            for (int m = 0; m < 4; ++m)
#pragma unroll
                for (int n = 0; n < NF; ++n) {
                    acc[m][n] = __builtin_amdgcn_mfma_f32_16x16x32_bf16(ah[m], bh[n], acc[m][n], 0, 0, 0);
                    acc[m][n] = __builtin_amdgcn_mfma_f32_16x16x32_bf16(al[m], bh[n], acc[m][n], 0, 0, 0);
                    if (PASSES == 3)
                        acc[m][n] = __builtin_amdgcn_mfma_f32_16x16x32_bf16(ah[m], bl[n], acc[m][n], 0, 0, 0);
                }
        }
        __syncthreads();
    }

    // epilogue: C/D layout col=lane&15, row=(lane>>4)*4+reg (m89-verified)
#pragma unroll
    for (int m = 0; m < 4; ++m) {
#pragma unroll
        for (int n = 0; n < NF; ++n) {
            int row0 = m0 + wr * 64 + m * 16 + lk * 4;
            int col  = n0 + wc * (BN / 2) + n * 16 + lm;
            float bv = bias[col];
#pragma unroll
            for (int r = 0; r < 4; ++r) {
                float v = acc[m][n][r] + bv;
                if (GELU) v = 0.5f * v * (1.0f + erff(v * 0.70710678118654752f));
                size_t idx = (size_t)(row0 + r) * N + col;
                if (OUTSPLIT) {
                    u16 hi, lo; split2(v, hi, lo);
                    Chi[idx] = hi; Clo[idx] = lo;
                } else {
                    Cf[idx] = v;
                }
            }
        }
    }
}

// ---- row LayerNorm over D=384; writes f32 dst + hi/lo bf16 planes; ADD: dst += LN
template <int ADD>
__global__ __launch_bounds__(256) void ln_rows(
    const float* __restrict__ src, float* __restrict__ dst,
    u16* __restrict__ dhi, u16* __restrict__ dlo,
    const float* __restrict__ s, const float* __restrict__ bvec)
{
    int wid = blockIdx.x * 4 + (threadIdx.x >> 6);
    int lane = threadIdx.x & 63;
    const float* r = src + (size_t)wid * D_;
    float v[6]; float sum = 0.f;
#pragma unroll
    for (int t = 0; t < 6; ++t) { v[t] = r[lane + 64 * t]; sum += v[t]; }
    sum = wave_sum(sum);
    float mean = sum * (1.0f / D_);
    float vs = 0.f;
#pragma unroll
    for (int t = 0; t < 6; ++t) { float d = v[t] - mean; vs += d * d; }
    vs = wave_sum(vs);
    float rstd = rsqrtf(vs * (1.0f / D_) + 1e-5f);
    float* wo = dst + (size_t)wid * D_;
    u16* wh = dhi + (size_t)wid * D_;
    u16* wl = dlo + (size_t)wid * D_;
#pragma unroll
    for (int t = 0; t < 6; ++t) {
        int d = lane + 64 * t;
        float o = (v[t] - mean) * rstd * s[d] + bvec[d];
        float nv = ADD ? (wo[d] + o) : o;
        wo[d] = nv;
        u16 hi, lo; split2(nv, hi, lo);
        wh[d] = hi; wl[d] = lo;
    }
}

// ---- fused: windowed scores + softmax -> P, then new_centers = P@V,
//      X_out += LN(new_centers), refresh hi/lo planes. One wave per (b,o).
//      K/V interleaved in one [row][768] buffer (K at +0, V at +384).
__global__ __launch_bounds__(256) void attn_nc(
    const float* __restrict__ Q, const float* __restrict__ KV,
    const float* __restrict__ biasp, float* __restrict__ P,
    const float* __restrict__ lns, const float* __restrict__ lnb,
    float* __restrict__ Xout, u16* __restrict__ Xhi, u16* __restrict__ Xlo)
{
    int wid = blockIdx.x * 4 + (threadIdx.x >> 6);   // (b,o)
    int lane = threadIdx.x & 63;
    int b = wid / N_OUT, o = wid % N_OUT;
    int yo = o / 28, xo = o % 28;
    float q[6];
    const float* qr = Q + (size_t)wid * D_;
#pragma unroll
    for (int t = 0; t < 6; ++t) q[t] = qr[lane + 64 * t];

    float s[9]; bool valid[9];
#pragma unroll
    for (int j = 0; j < 9; ++j) {
        int dy = j / 3 - 1, dx = j % 3 - 1;
        int yi = 2 * yo + dy, xi = 2 * xo + dx;
        bool ok = (yi >= 0) && (yi < H_) && (xi >= 0) && (xi < W_);
        valid[j] = ok;
        float acc = 0.f;
        if (ok) {
            const float* kr = KV + (size_t)(b * N_IN + yi * W_ + xi) * KVSTR;
#pragma unroll
            for (int t = 0; t < 6; ++t) acc += q[t] * kr[lane + 64 * t];
        }
        s[j] = acc;
    }
#pragma unroll
    for (int j = 0; j < 9; ++j) s[j] = wave_sum(s[j]);
    float bias = *biasp;
    float mx = -1e30f;
#pragma unroll
    for (int j = 0; j < 9; ++j) if (valid[j]) mx = fmaxf(mx, s[j] + bias);
    float e[9]; float tot = 0.f;
#pragma unroll
    for (int j = 0; j < 9; ++j) { e[j] = valid[j] ? expf(s[j] + bias - mx) : 0.0f; tot += e[j]; }
    float inv = 1.0f / tot;
#pragma unroll
    for (int j = 0; j < 9; ++j) e[j] *= inv;
    if (lane < 12) P[(size_t)wid * 12 + lane] = (lane < 9) ? e[lane] : 0.0f;

    // ---- P @ V over the window
    float acc[6] = {0, 0, 0, 0, 0, 0};
#pragma unroll
    for (int j = 0; j < 9; ++j) {
        if (valid[j]) {
            int dy = j / 3 - 1, dx = j % 3 - 1;
            int yi = 2 * yo + dy, xi = 2 * xo + dx;
            const float* vr = KV + (size_t)(b * N_IN + yi * W_ + xi) * KVSTR + 384;
#pragma unroll
            for (int t = 0; t < 6; ++t) acc[t] += e[j] * vr[lane + 64 * t];
        }
    }
    float sum = 0.f;
#pragma unroll
    for (int t = 0; t < 6; ++t) sum += acc[t];
    sum = wave_sum(sum);
    float mean = sum * (1.0f / D_);
    float vs = 0.f;
#pragma unroll
    for (int t = 0; t < 6; ++t) { float d = acc[t] - mean; vs += d * d; }
    vs = wave_sum(vs);
    float rstd = rsqrtf(vs * (1.0f / D_) + 1e-5f);
    float* wo = Xout + (size_t)wid * D_;
    u16* wh = Xhi + (size_t)wid * D_;
    u16* wl = Xlo + (size_t)wid * D_;
#pragma unroll
    for (int t = 0; t < 6; ++t) {
        int d = lane + 64 * t;
        float nv = wo[d] + (acc[t] - mean) * rstd * lns[d] + lnb[d];
        wo[d] = nv;
        u16 hi, lo; split2(nv, hi, lo);
        wh[d] = hi; wl[d] = lo;
    }
}

// ---- per-(b, input pixel) column sum of A_ups
__global__ void colsum_k(const float* __restrict__ P, float* __restrict__ cs) {
    int idx = blockIdx.x * 256 + threadIdx.x;
    if (idx >= B_ * N_IN) return;
    int b = idx / N_IN, i = idx % N_IN;
    int yi = i / W_, xi = i % W_;
    float sum = 0.f;
    int yc = yi >> 1, xc = xi >> 1;
    for (int yo = yc - 1; yo <= yc + 1; ++yo) {
        if (yo < 0 || yo >= 28) continue;
        int dy = yi - 2 * yo;
        if (dy < -1 || dy > 1) continue;
        for (int xo = xc - 1; xo <= xc + 1; ++xo) {
            if (xo < 0 || xo >= 28) continue;
            int dx = xi - 2 * xo;
            if (dx < -1 || dx > 1) continue;
            int j = (dy + 1) * 3 + (dx + 1);
            sum += P[((size_t)(b * N_OUT + yo * 28 + xo)) * 12 + j];
        }
    }
    cs[idx] = sum;
}

// ---- dense A_ups/A_down writer: one block per (b,o) row; zero row then fix window
__global__ __launch_bounds__(256) void write_A(
    const float* __restrict__ P, const float* __restrict__ cs,
    float* __restrict__ Aups, float* __restrict__ Adown)
{
    int wid = blockIdx.x;                 // (b,o)
    int b = wid / N_OUT, o = wid % N_OUT;
    int yo = o / 28, xo = o % 28;
    float4 z = {0.f, 0.f, 0.f, 0.f};
    float4* up = reinterpret_cast<float4*>(Aups + (size_t)wid * N_IN);
    float4* dn = reinterpret_cast<float4*>(Adown + (size_t)wid * N_IN);
    for (int i = threadIdx.x; i < N_IN / 4; i += 256) { up[i] = z; dn[i] = z; }
    __syncthreads();
    int j = threadIdx.x;
    if (j < 9) {
        int dy = j / 3 - 1, dx = j % 3 - 1;
        int yi = 2 * yo + dy, xi = 2 * xo + dx;
        if (yi >= 0 && yi < H_ && xi >= 0 && xi < W_) {
            int i = yi * W_ + xi;
            float p = P[(size_t)wid * 12 + j];
            Aups[(size_t)wid * N_IN + i] = p;
            Adown[(size_t)wid * N_IN + i] = p / (1e-10f + cs[b * N_IN + i]);
        }
    }
}

extern "C" void kernel_launch(void* const* d_in, const int* in_sizes, int n_in,
                              void* d_out, int out_size, void* d_ws, size_t ws_size,
                              hipStream_t stream)
{
    const float* X_in      = (const float*)d_in[0];
    const float* conv_w    = (const float*)d_in[1];
    const float* conv_b    = (const float*)d_in[2];
    const float* ln_init_s = (const float*)d_in[3];
    const float* ln_init_b = (const float*)d_in[4];
    const float* qw        = (const float*)d_in[5];
    const float* qb        = (const float*)d_in[6];
    const float* kw        = (const float*)d_in[7];
    const float* kb        = (const float*)d_in[8];
    const float* vw        = (const float*)d_in[9];
    const float* vb        = (const float*)d_in[10];
    const float* ln_out_s  = (const float*)d_in[11];
    const float* ln_out_b  = (const float*)d_in[12];
    const float* w1        = (const float*)d_in[13];
    const float* b1        = (const float*)d_in[14];
    const float* w2        = (const float*)d_in[15];
    const float* b2        = (const float*)d_in[16];
    const float* mlp_s     = (const float*)d_in[17];
    const float* mlp_b     = (const float*)d_in[18];
    const float* rel_bias  = (const float*)d_in[19];
    (void)in_sizes; (void)n_in; (void)out_size; (void)ws_size;

    float* out   = (float*)d_out;
    float* Xout  = out;                    // (M_OUT, D) f32 — final output 0
    float* Adown = out + XOUT_ELEMS;       // (B, N_OUT, N_IN)
    float* Aups  = Adown + A_ELEMS;

    // dead A-region overlays (all dead before the final write_A):
    float* Abase = Adown;                            // 2*A_ELEMS floats total
    float* KVf   = Abase;                            // M_IN*768 f32 (154MB): K|V interleaved
    u16* XinHi = (u16*)(Abase + 38535168);           // M_IN*D u16
    u16* XinLo = (u16*)(Abase + 48168960);
    u16* h1Hi  = (u16*)(Abase + 57802752);           // M_OUT*HID u16
    u16* h1Lo  = (u16*)(Abase + 65028096);

    float* ws    = (float*)d_ws;
    float* tmpD  = ws;                               // M_OUT*D f32 (conv out / Q / h2)
    float* Pb    = tmpD + XOUT_ELEMS;                // M_OUT*12
    float* cs    = Pb + (size_t)M_OUT * 12;          // B_*N_IN
    float* biasv = cs + B_ * N_IN;                   // 4
    float* kvb   = biasv + 4;                        // 768
    u16* XoutHi = (u16*)(kvb + 768);                 // M_OUT*D
    u16* XoutLo = XoutHi + XOUT_ELEMS;
    u16* qwTh   = XoutLo + XOUT_ELEMS;               // 384*384 each
    u16* qwTl   = qwTh + 147456;
    u16* kvTh   = qwTl + 147456;                     // 768*384 (kw rows then vw rows)
    u16* kvTl   = kvTh + 294912;
    u16* w1Th   = kvTl + 294912;                     // 1152*384
    u16* w1Tl   = w1Th + 442368;
    u16* w2Th   = w1Tl + 442368;                     // 384*1152
    u16* w2Tl   = w2Th + 442368;
    u16* cvTh   = w2Tl + 442368;                     // 384*1536
    u16* cvTl   = cvTh + 589824;

    // ---- prep: split conversions + weight transposes
    hipLaunchKernelGGL(cvt_split, dim3(2048), dim3(256), 0, stream,
                       X_in, XinHi, XinLo, (size_t)M_IN * D_ / 4);
    hipLaunchKernelGGL(transpose_split, dim3(12, 12), dim3(256), 0, stream, qw, qwTh, qwTl, 384, 384);
    hipLaunchKernelGGL(transpose_split, dim3(12, 12), dim3(256), 0, stream, kw, kvTh, kvTl, 384, 384);
    hipLaunchKernelGGL(transpose_split, dim3(12, 12), dim3(256), 0, stream,
                       vw, kvTh + 147456, kvTl + 147456, 384, 384);
    hipLaunchKernelGGL(transpose_split, dim3(36, 12), dim3(256), 0, stream, w1, w1Th, w1Tl, 384, 1152);
    hipLaunchKernelGGL(transpose_split, dim3(12, 36), dim3(256), 0, stream, w2, w2Th, w2Tl, 1152, 384);
    hipLaunchKernelGGL(prep_convw_split, dim3((384 * 1536 + 255) / 256), dim3(256), 0, stream,
                       conv_w, cvTh, cvTl);
    hipLaunchKernelGGL(bias_mean, dim3(1), dim3(64), 0, stream, rel_bias, biasv);
    hipLaunchKernelGGL(concat_bias, dim3(3), dim3(256), 0, stream, kb, vb, kvb);

    // ---- init_proj conv (im2col split GEMM, BN=64) -> tmpD, X_out = LN(tmpD)
    hipLaunchKernelGGL((gemm_split<1, 0, 0, 3, 64>), dim3(6, 98), dim3(256), 0, stream,
                       XinHi, XinLo, cvTh, cvTl, conv_b, tmpD, (u16*)0, (u16*)0, M_OUT, D_, 4 * D_);
    hipLaunchKernelGGL((ln_rows<0>), dim3(M_OUT / 4), dim3(256), 0, stream,
                       tmpD, Xout, XoutHi, XoutLo, ln_init_s, ln_init_b);

    // ---- K|V projection (single GEMM, N=768, BN=128, f32 out in dead A-region)
    hipLaunchKernelGGL((gemm_split<0, 0, 0, 3, 128>), dim3(6, 392), dim3(256), 0, stream,
                       XinHi, XinLo, kvTh, kvTl, kvb, KVf, (u16*)0, (u16*)0, M_IN, KVSTR, D_);

    for (int it = 0; it < 3; ++it) {
        hipLaunchKernelGGL((gemm_split<0, 0, 0, 3, 64>), dim3(6, 98), dim3(256), 0, stream,
                           XoutHi, XoutLo, qwTh, qwTl, qb, tmpD, (u16*)0, (u16*)0, M_OUT, D_, D_);
        hipLaunchKernelGGL(attn_nc, dim3(M_OUT / 4), dim3(256), 0, stream,
                           tmpD, KVf, biasv, Pb, ln_out_s, ln_out_b, Xout, XoutHi, XoutLo);
        hipLaunchKernelGGL((gemm_split<0, 1, 1, 3, 128>), dim3(9, 98), dim3(256), 0, stream,
                           XoutHi, XoutLo, w1Th, w1Tl, b1, (float*)0, h1Hi, h1Lo, M_OUT, HID_, D_);
        hipLaunchKernelGGL((gemm_split<0, 0, 0, 3, 64>), dim3(6, 98), dim3(256), 0, stream,
                           h1Hi, h1Lo, w2Th, w2Tl, b2, tmpD, (u16*)0, (u16*)0, M_OUT, D_, HID_);
        hipLaunchKernelGGL((ln_rows<1>), dim3(M_OUT / 4), dim3(256), 0, stream,
                           tmpD, Xout, XoutHi, XoutLo, mlp_s, mlp_b);
    }

    // ---- all A-region temporaries dead now; build dense A_ups/A_down from it==2's Pb
    hipLaunchKernelGGL(colsum_k, dim3((B_ * N_IN + 255) / 256), dim3(256), 0, stream, Pb, cs);
    hipLaunchKernelGGL(write_A, dim3(M_OUT), dim3(256), 0, stream, Pb, cs, Aups, Adown);
}

// Round 10
// 771.308 us; speedup vs baseline: 2.5710x; 1.0975x over previous
//
#include <hip/hip_runtime.h>
#include <hip/hip_bf16.h>
#include <math.h>

#define B_    16
#define H_    56
#define W_    56
#define D_    384
#define HID_  1152
#define N_IN  3136
#define N_OUT 784
#define M_OUT (B_ * N_OUT)   // 12544
#define M_IN  (B_ * N_IN)    // 50176
#define KVSTR 768

#define XOUT_ELEMS ((size_t)M_OUT * D_)          // 4,816,896
#define A_ELEMS    ((size_t)B_ * N_OUT * N_IN)   // 39,337,984

typedef unsigned short u16;
using frag_h  = __attribute__((ext_vector_type(8))) _Float16;  // 8 fp16 (4 VGPRs)
using frag_cd = __attribute__((ext_vector_type(4))) float;     // 4 fp32

// fp16 two-plane split: hi 11-bit mantissa, lo covers to ~2^-22 rel.
__device__ __forceinline__ void split2(float f, u16& hi, u16& lo) {
    _Float16 h = (_Float16)f;
    hi = *reinterpret_cast<u16*>(&h);
    float r = f - (float)h;
    _Float16 l = (_Float16)r;
    lo = *reinterpret_cast<u16*>(&l);
}

__device__ __forceinline__ float wave_sum(float x) {
#pragma unroll
    for (int off = 32; off; off >>= 1) x += __shfl_xor(x, off, 64);
    return x;
}

#define GLD16(g, l) __builtin_amdgcn_global_load_lds( \
    (const __attribute__((address_space(1))) void*)(g), \
    (__attribute__((address_space(3))) void*)(l), 16, 0, 0)

// ---- f32 -> (hi, lo) fp16 planes, float4 vectorized
__global__ void cvt_split(const float* __restrict__ in, u16* __restrict__ hi,
                          u16* __restrict__ lo, size_t n4) {
    size_t i = (size_t)blockIdx.x * 256 + threadIdx.x;
    size_t stride = (size_t)gridDim.x * 256;
    for (; i < n4; i += stride) {
        float4 v = reinterpret_cast<const float4*>(in)[i];
        ushort4 h, l;
        split2(v.x, h.x, l.x); split2(v.y, h.y, l.y);
        split2(v.z, h.z, l.z); split2(v.w, h.w, l.w);
        reinterpret_cast<ushort4*>(hi)[i] = h;
        reinterpret_cast<ushort4*>(lo)[i] = l;
    }
}

// ---- W[K][N] f32 -> Bt[N][K] hi/lo fp16 (LDS-tiled transpose)
__global__ void transpose_split(const float* __restrict__ Wm, u16* __restrict__ Bh,
                                u16* __restrict__ Bl, int K, int N) {
    __shared__ float t[32][33];
    int k0 = blockIdx.y * 32, n0 = blockIdx.x * 32;
    int r = threadIdx.x >> 5, c = threadIdx.x & 31;
#pragma unroll
    for (int i = 0; i < 4; ++i) t[r + 8 * i][c] = Wm[(size_t)(k0 + r + 8 * i) * N + n0 + c];
    __syncthreads();
#pragma unroll
    for (int i = 0; i < 4; ++i) {
        u16 hi, lo;
        split2(t[c][r + 8 * i], hi, lo);
        size_t idx = (size_t)(n0 + r + 8 * i) * K + k0 + c;
        Bh[idx] = hi; Bl[idx] = lo;
    }
}

// ---- conv weight: wknT[n][kk] hi/lo, kk = p*384 + c ; conv_w OIHW [n][c][p]
__global__ void prep_convw_split(const float* __restrict__ cw, u16* __restrict__ Bh,
                                 u16* __restrict__ Bl) {
    int idx = blockIdx.x * 256 + threadIdx.x;
    if (idx >= 384 * 1536) return;
    int n = idx / 1536, kk = idx % 1536;
    int p = kk / 384, c = kk % 384;
    u16 hi, lo;
    split2(cw[n * 1536 + c * 4 + p], hi, lo);
    Bh[idx] = hi; Bl[idx] = lo;
}

__global__ void bias_mean(const float* __restrict__ rb, float* __restrict__ out) {
    if (threadIdx.x == 0) {
        float s = 0.f;
        for (int i = 0; i < 25; ++i) s += rb[i];
        *out = s / 25.0f;
    }
}

// ---- concat kb|vb -> kvb[768]
__global__ void concat_bias(const float* __restrict__ a, const float* __restrict__ b,
                            float* __restrict__ o) {
    int i = threadIdx.x + blockIdx.x * 256;
    if (i < 384) o[i] = a[i];
    else if (i < 768) o[i] = b[i - 384];
}

// ---- split-fp16 MFMA GEMM: C = A @ Bt^T + bias.
// PASSES==3: AhBh + AlBh + AhBl -> rel err ~2^-22 (f32-exact for our ranges).
// PASSES==2: AhBh + AlBh -> B-side rel err 2^-11. Safe for conv/w1/w2 (R8 measured
//   bf16 2-pass B-err 2^-8 -> 0.72 absmax; linear scaling -> fp16 ~0.09). Keep
//   3-pass for Q/KV (softmax-score paths).
// 128xBN tile (BN=128 or 64), BK=64, 4 waves (2x2; each wave 64 x BN/2).
// global_load_lds staging; XOR-swizzle LDS(row,b)=G(row, b^((row&7)<<4)).
// XCD remap: chunk of 8 M-panels x gridDim.x so same-XCD blocks share an M-panel.
template <int IM2COL, int GELU, int OUTSPLIT, int PASSES, int BN>
__global__ __launch_bounds__(256,
    ((32768 + BN * 128 * ((PASSES == 3) ? 2 : 1)) <= 40960) ? 4 :
    ((32768 + BN * 128 * ((PASSES == 3) ? 2 : 1)) <= 49152) ? 3 : 2)
void gemm_split(
    const u16* __restrict__ Ah, const u16* __restrict__ Al,
    const u16* __restrict__ Bth, const u16* __restrict__ Btl,
    const float* __restrict__ bias, float* __restrict__ Cf,
    u16* __restrict__ Chi, u16* __restrict__ Clo,
    int M, int N, int K)
{
    constexpr int NF = BN / 32;          // n-frags per wave
    __shared__ u16 sAh[128 * 64];
    __shared__ u16 sAl[128 * 64];
    __shared__ u16 sBh[BN * 64];
    __shared__ u16 sBl[(PASSES == 3) ? BN * 64 : 8];
    const int t = threadIdx.x;
    const int lane = t & 63;
    const int w = t >> 6;
    const int wr = w >> 1, wc = w & 1;
    const int lm = lane & 15, lk = lane >> 4;

    // ---- XCD-aware (y,x) remap
    const int gx = gridDim.x, ny = gridDim.y;
    int d = blockIdx.y * gx + blockIdx.x;
    const int covered = (ny >> 3) * 8 * gx;
    int m_y, n_x;
    if (d < covered) {
        int c = d / (8 * gx), l = d % (8 * gx);
        m_y = c * 8 + (l & 7);
        n_x = l >> 3;
    } else {
        int l = d - covered;
        m_y = (ny & ~7) + l / gx;
        n_x = l % gx;
    }
    const int m0 = m_y * 128;
    const int n0 = n_x * BN;

    const int rt = t >> 3, st = t & 7;                    // staging row-sub, 16B slot
    const int skel = ((st * 16) ^ ((rt & 7) << 4)) >> 1;  // swizzle-inverse src k-elem

    int pb4[4];
    if (IM2COL) {
#pragma unroll
        for (int i = 0; i < 4; ++i) {
            int m = m0 + i * 32 + rt;
            int bb = m / N_OUT, o = m - bb * N_OUT;
            pb4[i] = bb * N_IN + (o / 28) * 112 + (o % 28) * 2;
        }
    }

    frag_cd acc[4][NF];
#pragma unroll
    for (int i = 0; i < 4; ++i)
#pragma unroll
        for (int j = 0; j < NF; ++j) acc[i][j] = (frag_cd){0.f, 0.f, 0.f, 0.f};

    const int swzf = (lm & 7) << 4;

    for (int kt = 0; kt < K; kt += 64) {
#pragma unroll
        for (int i = 0; i < 4; ++i) {
            int r = i * 32 + rt;
            size_t aoff;
            if (IM2COL) {
                int k = kt + skel;
                int p = k / 384, c = k - p * 384;
                aoff = ((size_t)pb4[i] + (p >> 1) * 56 + (p & 1)) * 384 + c;
            } else {
                aoff = (size_t)(m0 + r) * K + kt + skel;
            }
            GLD16(Ah + aoff, &sAh[i * 2048 + t * 8]);
            GLD16(Al + aoff, &sAl[i * 2048 + t * 8]);
        }
#pragma unroll
        for (int i = 0; i < BN / 32; ++i) {
            int r = i * 32 + rt;
            size_t boff = (size_t)(n0 + r) * K + kt + skel;
            GLD16(Bth + boff, &sBh[i * 2048 + t * 8]);
            if (PASSES == 3) GLD16(Btl + boff, &sBl[i * 2048 + t * 8]);
        }
        __syncthreads();

#pragma unroll
        for (int h = 0; h < 2; ++h) {
            const int kb = (h * 64 + lk * 16) ^ swzf;
            frag_h ah[4], al[4], bh[NF], bl[NF];
#pragma unroll
            for (int m = 0; m < 4; ++m) {
                int arow = wr * 64 + m * 16 + lm;
                ah[m] = *reinterpret_cast<const frag_h*>(reinterpret_cast<const char*>(sAh) + arow * 128 + kb);
                al[m] = *reinterpret_cast<const frag_h*>(reinterpret_cast<const char*>(sAl) + arow * 128 + kb);
            }
#pragma unroll
            for (int n = 0; n < NF; ++n) {
                int brow = wc * (BN / 2) + n * 16 + lm;
                bh[n] = *reinterpret_cast<const frag_h*>(reinterpret_cast<const char*>(sBh) + brow * 128 + kb);
                if (PASSES == 3)
                    bl[n] = *reinterpret_cast<const frag_h*>(reinterpret_cast<const char*>(sBl) + brow * 128 + kb);
            }
#pragma unroll
            for (int m = 0; m < 4; ++m)
#pragma unroll
                for (int n = 0; n < NF; ++n) {
                    acc[m][n] = __builtin_amdgcn_mfma_f32_16x16x32_f16(ah[m], bh[n], acc[m][n], 0, 0, 0);
                    acc[m][n] = __builtin_amdgcn_mfma_f32_16x16x32_f16(al[m], bh[n], acc[m][n], 0, 0, 0);
                    if (PASSES == 3)
                        acc[m][n] = __builtin_amdgcn_mfma_f32_16x16x32_f16(ah[m], bl[n], acc[m][n], 0, 0, 0);
                }
        }
        __syncthreads();
    }

    // epilogue: C/D layout col=lane&15, row=(lane>>4)*4+reg (m89-verified)
#pragma unroll
    for (int m = 0; m < 4; ++m) {
#pragma unroll
        for (int n = 0; n < NF; ++n) {
            int row0 = m0 + wr * 64 + m * 16 + lk * 4;
            int col  = n0 + wc * (BN / 2) + n * 16 + lm;
            float bv = bias[col];
#pragma unroll
            for (int r = 0; r < 4; ++r) {
                float v = acc[m][n][r] + bv;
                if (GELU) v = 0.5f * v * (1.0f + erff(v * 0.70710678118654752f));
                size_t idx = (size_t)(row0 + r) * N + col;
                if (OUTSPLIT) {
                    u16 hi, lo; split2(v, hi, lo);
                    Chi[idx] = hi; Clo[idx] = lo;
                } else {
                    Cf[idx] = v;
                }
            }
        }
    }
}

// ---- row LayerNorm over D=384; writes f32 dst + hi/lo fp16 planes; ADD: dst += LN
template <int ADD>
__global__ __launch_bounds__(256) void ln_rows(
    const float* __restrict__ src, float* __restrict__ dst,
    u16* __restrict__ dhi, u16* __restrict__ dlo,
    const float* __restrict__ s, const float* __restrict__ bvec)
{
    int wid = blockIdx.x * 4 + (threadIdx.x >> 6);
    int lane = threadIdx.x & 63;
    const float* r = src + (size_t)wid * D_;
    float v[6]; float sum = 0.f;
#pragma unroll
    for (int t = 0; t < 6; ++t) { v[t] = r[lane + 64 * t]; sum += v[t]; }
    sum = wave_sum(sum);
    float mean = sum * (1.0f / D_);
    float vs = 0.f;
#pragma unroll
    for (int t = 0; t < 6; ++t) { float d = v[t] - mean; vs += d * d; }
    vs = wave_sum(vs);
    float rstd = rsqrtf(vs * (1.0f / D_) + 1e-5f);
    float* wo = dst + (size_t)wid * D_;
    u16* wh = dhi + (size_t)wid * D_;
    u16* wl = dlo + (size_t)wid * D_;
#pragma unroll
    for (int t = 0; t < 6; ++t) {
        int d = lane + 64 * t;
        float o = (v[t] - mean) * rstd * s[d] + bvec[d];
        float nv = ADD ? (wo[d] + o) : o;
        wo[d] = nv;
        u16 hi, lo; split2(nv, hi, lo);
        wh[d] = hi; wl[d] = lo;
    }
}

// ---- fused: windowed scores + softmax -> P, then new_centers = P@V,
//      X_out += LN(new_centers), refresh hi/lo planes. One wave per (b,o).
//      K/V interleaved in one [row][768] buffer (K at +0, V at +384).
__global__ __launch_bounds__(256) void attn_nc(
    const float* __restrict__ Q, const float* __restrict__ KV,
    const float* __restrict__ biasp, float* __restrict__ P,
    const float* __restrict__ lns, const float* __restrict__ lnb,
    float* __restrict__ Xout, u16* __restrict__ Xhi, u16* __restrict__ Xlo)
{
    int wid = blockIdx.x * 4 + (threadIdx.x >> 6);   // (b,o)
    int lane = threadIdx.x & 63;
    int b = wid / N_OUT, o = wid % N_OUT;
    int yo = o / 28, xo = o % 28;
    float q[6];
    const float* qr = Q + (size_t)wid * D_;
#pragma unroll
    for (int t = 0; t < 6; ++t) q[t] = qr[lane + 64 * t];

    float s[9]; bool valid[9];
#pragma unroll
    for (int j = 0; j < 9; ++j) {
        int dy = j / 3 - 1, dx = j % 3 - 1;
        int yi = 2 * yo + dy, xi = 2 * xo + dx;
        bool ok = (yi >= 0) && (yi < H_) && (xi >= 0) && (xi < W_);
        valid[j] = ok;
        float acc = 0.f;
        if (ok) {
            const float* kr = KV + (size_t)(b * N_IN + yi * W_ + xi) * KVSTR;
#pragma unroll
            for (int t = 0; t < 6; ++t) acc += q[t] * kr[lane + 64 * t];
        }
        s[j] = acc;
    }
#pragma unroll
    for (int j = 0; j < 9; ++j) s[j] = wave_sum(s[j]);
    float bias = *biasp;
    float mx = -1e30f;
#pragma unroll
    for (int j = 0; j < 9; ++j) if (valid[j]) mx = fmaxf(mx, s[j] + bias);
    float e[9]; float tot = 0.f;
#pragma unroll
    for (int j = 0; j < 9; ++j) { e[j] = valid[j] ? expf(s[j] + bias - mx) : 0.0f; tot += e[j]; }
    float inv = 1.0f / tot;
#pragma unroll
    for (int j = 0; j < 9; ++j) e[j] *= inv;
    if (lane < 12) P[(size_t)wid * 12 + lane] = (lane < 9) ? e[lane] : 0.0f;

    // ---- P @ V over the window
    float acc[6] = {0, 0, 0, 0, 0, 0};
#pragma unroll
    for (int j = 0; j < 9; ++j) {
        if (valid[j]) {
            int dy = j / 3 - 1, dx = j % 3 - 1;
            int yi = 2 * yo + dy, xi = 2 * xo + dx;
            const float* vr = KV + (size_t)(b * N_IN + yi * W_ + xi) * KVSTR + 384;
#pragma unroll
            for (int t = 0; t < 6; ++t) acc[t] += e[j] * vr[lane + 64 * t];
        }
    }
    float sum = 0.f;
#pragma unroll
    for (int t = 0; t < 6; ++t) sum += acc[t];
    sum = wave_sum(sum);
    float mean = sum * (1.0f / D_);
    float vs = 0.f;
#pragma unroll
    for (int t = 0; t < 6; ++t) { float d = acc[t] - mean; vs += d * d; }
    vs = wave_sum(vs);
    float rstd = rsqrtf(vs * (1.0f / D_) + 1e-5f);
    float* wo = Xout + (size_t)wid * D_;
    u16* wh = Xhi + (size_t)wid * D_;
    u16* wl = Xlo + (size_t)wid * D_;
#pragma unroll
    for (int t = 0; t < 6; ++t) {
        int d = lane + 64 * t;
        float nv = wo[d] + (acc[t] - mean) * rstd * lns[d] + lnb[d];
        wo[d] = nv;
        u16 hi, lo; split2(nv, hi, lo);
        wh[d] = hi; wl[d] = lo;
    }
}

// ---- per-(b, input pixel) column sum of A_ups
__global__ void colsum_k(const float* __restrict__ P, float* __restrict__ cs) {
    int idx = blockIdx.x * 256 + threadIdx.x;
    if (idx >= B_ * N_IN) return;
    int b = idx / N_IN, i = idx % N_IN;
    int yi = i / W_, xi = i % W_;
    float sum = 0.f;
    int yc = yi >> 1, xc = xi >> 1;
    for (int yo = yc - 1; yo <= yc + 1; ++yo) {
        if (yo < 0 || yo >= 28) continue;
        int dy = yi - 2 * yo;
        if (dy < -1 || dy > 1) continue;
        for (int xo = xc - 1; xo <= xc + 1; ++xo) {
            if (xo < 0 || xo >= 28) continue;
            int dx = xi - 2 * xo;
            if (dx < -1 || dx > 1) continue;
            int j = (dy + 1) * 3 + (dx + 1);
            sum += P[((size_t)(b * N_OUT + yo * 28 + xo)) * 12 + j];
        }
    }
    cs[idx] = sum;
}

// ---- dense A_ups/A_down writer: one block per (b,o) row; zero row then fix window
__global__ __launch_bounds__(256) void write_A(
    const float* __restrict__ P, const float* __restrict__ cs,
    float* __restrict__ Aups, float* __restrict__ Adown)
{
    int wid = blockIdx.x;                 // (b,o)
    int b = wid / N_OUT, o = wid % N_OUT;
    int yo = o / 28, xo = o % 28;
    float4 z = {0.f, 0.f, 0.f, 0.f};
    float4* up = reinterpret_cast<float4*>(Aups + (size_t)wid * N_IN);
    float4* dn = reinterpret_cast<float4*>(Adown + (size_t)wid * N_IN);
    for (int i = threadIdx.x; i < N_IN / 4; i += 256) { up[i] = z; dn[i] = z; }
    __syncthreads();
    int j = threadIdx.x;
    if (j < 9) {
        int dy = j / 3 - 1, dx = j % 3 - 1;
        int yi = 2 * yo + dy, xi = 2 * xo + dx;
        if (yi >= 0 && yi < H_ && xi >= 0 && xi < W_) {
            int i = yi * W_ + xi;
            float p = P[(size_t)wid * 12 + j];
            Aups[(size_t)wid * N_IN + i] = p;
            Adown[(size_t)wid * N_IN + i] = p / (1e-10f + cs[b * N_IN + i]);
        }
    }
}

extern "C" void kernel_launch(void* const* d_in, const int* in_sizes, int n_in,
                              void* d_out, int out_size, void* d_ws, size_t ws_size,
                              hipStream_t stream)
{
    const float* X_in      = (const float*)d_in[0];
    const float* conv_w    = (const float*)d_in[1];
    const float* conv_b    = (const float*)d_in[2];
    const float* ln_init_s = (const float*)d_in[3];
    const float* ln_init_b = (const float*)d_in[4];
    const float* qw        = (const float*)d_in[5];
    const float* qb        = (const float*)d_in[6];
    const float* kw        = (const float*)d_in[7];
    const float* kb        = (const float*)d_in[8];
    const float* vw        = (const float*)d_in[9];
    const float* vb        = (const float*)d_in[10];
    const float* ln_out_s  = (const float*)d_in[11];
    const float* ln_out_b  = (const float*)d_in[12];
    const float* w1        = (const float*)d_in[13];
    const float* b1        = (const float*)d_in[14];
    const float* w2        = (const float*)d_in[15];
    const float* b2        = (const float*)d_in[16];
    const float* mlp_s     = (const float*)d_in[17];
    const float* mlp_b     = (const float*)d_in[18];
    const float* rel_bias  = (const float*)d_in[19];
    (void)in_sizes; (void)n_in; (void)out_size; (void)ws_size;

    float* out   = (float*)d_out;
    float* Xout  = out;                    // (M_OUT, D) f32 — final output 0
    float* Adown = out + XOUT_ELEMS;       // (B, N_OUT, N_IN)
    float* Aups  = Adown + A_ELEMS;

    // dead A-region overlays (all dead before the final write_A):
    float* Abase = Adown;                            // 2*A_ELEMS floats total
    float* KVf   = Abase;                            // M_IN*768 f32 (154MB): K|V interleaved
    u16* XinHi = (u16*)(Abase + 38535168);           // M_IN*D u16
    u16* XinLo = (u16*)(Abase + 48168960);
    u16* h1Hi  = (u16*)(Abase + 57802752);           // M_OUT*HID u16
    u16* h1Lo  = (u16*)(Abase + 65028096);

    float* ws    = (float*)d_ws;
    float* tmpD  = ws;                               // M_OUT*D f32 (conv out / Q / h2)
    float* Pb    = tmpD + XOUT_ELEMS;                // M_OUT*12
    float* cs    = Pb + (size_t)M_OUT * 12;          // B_*N_IN
    float* biasv = cs + B_ * N_IN;                   // 4
    float* kvb   = biasv + 4;                        // 768
    u16* XoutHi = (u16*)(kvb + 768);                 // M_OUT*D
    u16* XoutLo = XoutHi + XOUT_ELEMS;
    u16* qwTh   = XoutLo + XOUT_ELEMS;               // 384*384 each
    u16* qwTl   = qwTh + 147456;
    u16* kvTh   = qwTl + 147456;                     // 768*384 (kw rows then vw rows)
    u16* kvTl   = kvTh + 294912;
    u16* w1Th   = kvTl + 294912;                     // 1152*384
    u16* w1Tl   = w1Th + 442368;
    u16* w2Th   = w1Tl + 442368;                     // 384*1152
    u16* w2Tl   = w2Th + 442368;
    u16* cvTh   = w2Tl + 442368;                     // 384*1536
    u16* cvTl   = cvTh + 589824;

    // ---- prep: split conversions + weight transposes
    hipLaunchKernelGGL(cvt_split, dim3(2048), dim3(256), 0, stream,
                       X_in, XinHi, XinLo, (size_t)M_IN * D_ / 4);
    hipLaunchKernelGGL(transpose_split, dim3(12, 12), dim3(256), 0, stream, qw, qwTh, qwTl, 384, 384);
    hipLaunchKernelGGL(transpose_split, dim3(12, 12), dim3(256), 0, stream, kw, kvTh, kvTl, 384, 384);
    hipLaunchKernelGGL(transpose_split, dim3(12, 12), dim3(256), 0, stream,
                       vw, kvTh + 147456, kvTl + 147456, 384, 384);
    hipLaunchKernelGGL(transpose_split, dim3(36, 12), dim3(256), 0, stream, w1, w1Th, w1Tl, 384, 1152);
    hipLaunchKernelGGL(transpose_split, dim3(12, 36), dim3(256), 0, stream, w2, w2Th, w2Tl, 1152, 384);
    hipLaunchKernelGGL(prep_convw_split, dim3((384 * 1536 + 255) / 256), dim3(256), 0, stream,
                       conv_w, cvTh, cvTl);
    hipLaunchKernelGGL(bias_mean, dim3(1), dim3(64), 0, stream, rel_bias, biasv);
    hipLaunchKernelGGL(concat_bias, dim3(3), dim3(256), 0, stream, kb, vb, kvb);

    // ---- init_proj conv (im2col, fp16 2-pass, BN=64) -> tmpD, X_out = LN(tmpD)
    hipLaunchKernelGGL((gemm_split<1, 0, 0, 2, 64>), dim3(6, 98), dim3(256), 0, stream,
                       XinHi, XinLo, cvTh, cvTl, conv_b, tmpD, (u16*)0, (u16*)0, M_OUT, D_, 4 * D_);
    hipLaunchKernelGGL((ln_rows<0>), dim3(M_OUT / 4), dim3(256), 0, stream,
                       tmpD, Xout, XoutHi, XoutLo, ln_init_s, ln_init_b);

    // ---- K|V projection (single GEMM, N=768, fp16 3-pass, BN=128)
    hipLaunchKernelGGL((gemm_split<0, 0, 0, 3, 128>), dim3(6, 392), dim3(256), 0, stream,
                       XinHi, XinLo, kvTh, kvTl, kvb, KVf, (u16*)0, (u16*)0, M_IN, KVSTR, D_);

    for (int it = 0; it < 3; ++it) {
        hipLaunchKernelGGL((gemm_split<0, 0, 0, 3, 64>), dim3(6, 98), dim3(256), 0, stream,
                           XoutHi, XoutLo, qwTh, qwTl, qb, tmpD, (u16*)0, (u16*)0, M_OUT, D_, D_);
        hipLaunchKernelGGL(attn_nc, dim3(M_OUT / 4), dim3(256), 0, stream,
                           tmpD, KVf, biasv, Pb, ln_out_s, ln_out_b, Xout, XoutHi, XoutLo);
        hipLaunchKernelGGL((gemm_split<0, 1, 1, 2, 128>), dim3(9, 98), dim3(256), 0, stream,
                           XoutHi, XoutLo, w1Th, w1Tl, b1, (float*)0, h1Hi, h1Lo, M_OUT, HID_, D_);
        hipLaunchKernelGGL((gemm_split<0, 0, 0, 2, 64>), dim3(6, 98), dim3(256), 0, stream,
                           h1Hi, h1Lo, w2Th, w2Tl, b2, tmpD, (u16*)0, (u16*)0, M_OUT, D_, HID_);
        hipLaunchKernelGGL((ln_rows<1>), dim3(M_OUT / 4), dim3(256), 0, stream,
                           tmpD, Xout, XoutHi, XoutLo, mlp_s, mlp_b);
    }

    // ---- all A-region temporaries dead now; build dense A_ups/A_down from it==2's Pb
    hipLaunchKernelGGL(colsum_k, dim3((B_ * N_IN + 255) / 256), dim3(256), 0, stream, Pb, cs);
    hipLaunchKernelGGL(write_A, dim3(M_OUT), dim3(256), 0, stream, Pb, cs, Aups, Adown);
}

// Round 11
// 752.267 us; speedup vs baseline: 2.6361x; 1.0253x over previous
//
#include <hip/hip_runtime.h>
#include <hip/hip_bf16.h>
#include <math.h>

#define B_    16
#define H_    56
#define W_    56
#define D_    384
#define HID_  1152
#define N_IN  3136
#define N_OUT 784
#define M_OUT (B_ * N_OUT)   // 12544
#define M_IN  (B_ * N_IN)    // 50176
#define KVSTR 768

#define XOUT_ELEMS ((size_t)M_OUT * D_)          // 4,816,896
#define A_ELEMS    ((size_t)B_ * N_OUT * N_IN)   // 39,337,984

typedef unsigned short u16;
using frag_h  = __attribute__((ext_vector_type(8))) _Float16;  // 8 fp16 (4 VGPRs)
using frag_cd = __attribute__((ext_vector_type(4))) float;     // 4 fp32

// fp16 two-plane split: hi 11-bit mantissa, lo covers to ~2^-22 rel.
__device__ __forceinline__ void split2(float f, u16& hi, u16& lo) {
    _Float16 h = (_Float16)f;
    hi = *reinterpret_cast<u16*>(&h);
    float r = f - (float)h;
    _Float16 l = (_Float16)r;
    lo = *reinterpret_cast<u16*>(&l);
}

__device__ __forceinline__ float wave_sum(float x) {
#pragma unroll
    for (int off = 32; off; off >>= 1) x += __shfl_xor(x, off, 64);
    return x;
}

#define GLD16(g, l) __builtin_amdgcn_global_load_lds( \
    (const __attribute__((address_space(1))) void*)(g), \
    (__attribute__((address_space(3))) void*)(l), 16, 0, 0)

// ---- f32 -> (hi, lo) fp16 planes, float4 vectorized
__global__ void cvt_split(const float* __restrict__ in, u16* __restrict__ hi,
                          u16* __restrict__ lo, size_t n4) {
    size_t i = (size_t)blockIdx.x * 256 + threadIdx.x;
    size_t stride = (size_t)gridDim.x * 256;
    for (; i < n4; i += stride) {
        float4 v = reinterpret_cast<const float4*>(in)[i];
        ushort4 h, l;
        split2(v.x, h.x, l.x); split2(v.y, h.y, l.y);
        split2(v.z, h.z, l.z); split2(v.w, h.w, l.w);
        reinterpret_cast<ushort4*>(hi)[i] = h;
        reinterpret_cast<ushort4*>(lo)[i] = l;
    }
}

// ---- W[K][N] f32 -> Bt[N][K] hi/lo fp16 (LDS-tiled transpose)
__global__ void transpose_split(const float* __restrict__ Wm, u16* __restrict__ Bh,
                                u16* __restrict__ Bl, int K, int N) {
    __shared__ float t[32][33];
    int k0 = blockIdx.y * 32, n0 = blockIdx.x * 32;
    int r = threadIdx.x >> 5, c = threadIdx.x & 31;
#pragma unroll
    for (int i = 0; i < 4; ++i) t[r + 8 * i][c] = Wm[(size_t)(k0 + r + 8 * i) * N + n0 + c];
    __syncthreads();
#pragma unroll
    for (int i = 0; i < 4; ++i) {
        u16 hi, lo;
        split2(t[c][r + 8 * i], hi, lo);
        size_t idx = (size_t)(n0 + r + 8 * i) * K + k0 + c;
        Bh[idx] = hi; Bl[idx] = lo;
    }
}

// ---- conv weight: wknT[n][kk] hi/lo, kk = p*384 + c ; conv_w OIHW [n][c][p]
__global__ void prep_convw_split(const float* __restrict__ cw, u16* __restrict__ Bh,
                                 u16* __restrict__ Bl) {
    int idx = blockIdx.x * 256 + threadIdx.x;
    if (idx >= 384 * 1536) return;
    int n = idx / 1536, kk = idx % 1536;
    int p = kk / 384, c = kk % 384;
    u16 hi, lo;
    split2(cw[n * 1536 + c * 4 + p], hi, lo);
    Bh[idx] = hi; Bl[idx] = lo;
}

__global__ void bias_mean(const float* __restrict__ rb, float* __restrict__ out) {
    if (threadIdx.x == 0) {
        float s = 0.f;
        for (int i = 0; i < 25; ++i) s += rb[i];
        *out = s / 25.0f;
    }
}

// ---- concat kb|vb -> kvb[768]
__global__ void concat_bias(const float* __restrict__ a, const float* __restrict__ b,
                            float* __restrict__ o) {
    int i = threadIdx.x + blockIdx.x * 256;
    if (i < 384) o[i] = a[i];
    else if (i < 768) o[i] = b[i - 384];
}

// ---- split-fp16 MFMA GEMM: C = A @ Bt^T + bias.
// PASSES==2: AhBh + AlBh. A-side (activations) f32-accurate via 2 planes;
//   B-side (weights) single fp16, rel err 2^-11. Measured (R10): conv/w1/w2
//   2-pass contributed +0.0625 absmax; R11 extends to Q/KV (score-path B-err
//   2^-11 -> ds ~ 0.003, modeled +~0.1). PASSES==3 (AhBl term) kept available.
// 128xBN tile (BN=128 or 64), BK=64, 4 waves (2x2; each wave 64 x BN/2).
// global_load_lds staging; XOR-swizzle LDS(row,b)=G(row, b^((row&7)<<4)).
// XCD remap: chunk of 8 M-panels x gridDim.x so same-XCD blocks share an M-panel.
template <int IM2COL, int GELU, int OUTSPLIT, int PASSES, int BN>
__global__ __launch_bounds__(256,
    ((32768 + BN * 128 * ((PASSES == 3) ? 2 : 1)) <= 40960) ? 4 :
    ((32768 + BN * 128 * ((PASSES == 3) ? 2 : 1)) <= 49152) ? 3 : 2)
void gemm_split(
    const u16* __restrict__ Ah, const u16* __restrict__ Al,
    const u16* __restrict__ Bth, const u16* __restrict__ Btl,
    const float* __restrict__ bias, float* __restrict__ Cf,
    u16* __restrict__ Chi, u16* __restrict__ Clo,
    int M, int N, int K)
{
    constexpr int NF = BN / 32;          // n-frags per wave
    __shared__ u16 sAh[128 * 64];
    __shared__ u16 sAl[128 * 64];
    __shared__ u16 sBh[BN * 64];
    __shared__ u16 sBl[(PASSES == 3) ? BN * 64 : 8];
    const int t = threadIdx.x;
    const int lane = t & 63;
    const int w = t >> 6;
    const int wr = w >> 1, wc = w & 1;
    const int lm = lane & 15, lk = lane >> 4;

    // ---- XCD-aware (y,x) remap
    const int gx = gridDim.x, ny = gridDim.y;
    int d = blockIdx.y * gx + blockIdx.x;
    const int covered = (ny >> 3) * 8 * gx;
    int m_y, n_x;
    if (d < covered) {
        int c = d / (8 * gx), l = d % (8 * gx);
        m_y = c * 8 + (l & 7);
        n_x = l >> 3;
    } else {
        int l = d - covered;
        m_y = (ny & ~7) + l / gx;
        n_x = l % gx;
    }
    const int m0 = m_y * 128;
    const int n0 = n_x * BN;

    const int rt = t >> 3, st = t & 7;                    // staging row-sub, 16B slot
    const int skel = ((st * 16) ^ ((rt & 7) << 4)) >> 1;  // swizzle-inverse src k-elem

    int pb4[4];
    if (IM2COL) {
#pragma unroll
        for (int i = 0; i < 4; ++i) {
            int m = m0 + i * 32 + rt;
            int bb = m / N_OUT, o = m - bb * N_OUT;
            pb4[i] = bb * N_IN + (o / 28) * 112 + (o % 28) * 2;
        }
    }

    frag_cd acc[4][NF];
#pragma unroll
    for (int i = 0; i < 4; ++i)
#pragma unroll
        for (int j = 0; j < NF; ++j) acc[i][j] = (frag_cd){0.f, 0.f, 0.f, 0.f};

    const int swzf = (lm & 7) << 4;

    for (int kt = 0; kt < K; kt += 64) {
#pragma unroll
        for (int i = 0; i < 4; ++i) {
            int r = i * 32 + rt;
            size_t aoff;
            if (IM2COL) {
                int k = kt + skel;
                int p = k / 384, c = k - p * 384;
                aoff = ((size_t)pb4[i] + (p >> 1) * 56 + (p & 1)) * 384 + c;
            } else {
                aoff = (size_t)(m0 + r) * K + kt + skel;
            }
            GLD16(Ah + aoff, &sAh[i * 2048 + t * 8]);
            GLD16(Al + aoff, &sAl[i * 2048 + t * 8]);
        }
#pragma unroll
        for (int i = 0; i < BN / 32; ++i) {
            int r = i * 32 + rt;
            size_t boff = (size_t)(n0 + r) * K + kt + skel;
            GLD16(Bth + boff, &sBh[i * 2048 + t * 8]);
            if (PASSES == 3) GLD16(Btl + boff, &sBl[i * 2048 + t * 8]);
        }
        __syncthreads();

#pragma unroll
        for (int h = 0; h < 2; ++h) {
            const int kb = (h * 64 + lk * 16) ^ swzf;
            frag_h ah[4], al[4], bh[NF], bl[NF];
#pragma unroll
            for (int m = 0; m < 4; ++m) {
                int arow = wr * 64 + m * 16 + lm;
                ah[m] = *reinterpret_cast<const frag_h*>(reinterpret_cast<const char*>(sAh) + arow * 128 + kb);
                al[m] = *reinterpret_cast<const frag_h*>(reinterpret_cast<const char*>(sAl) + arow * 128 + kb);
            }
#pragma unroll
            for (int n = 0; n < NF; ++n) {
                int brow = wc * (BN / 2) + n * 16 + lm;
                bh[n] = *reinterpret_cast<const frag_h*>(reinterpret_cast<const char*>(sBh) + brow * 128 + kb);
                if (PASSES == 3)
                    bl[n] = *reinterpret_cast<const frag_h*>(reinterpret_cast<const char*>(sBl) + brow * 128 + kb);
            }
#pragma unroll
            for (int m = 0; m < 4; ++m)
#pragma unroll
                for (int n = 0; n < NF; ++n) {
                    acc[m][n] = __builtin_amdgcn_mfma_f32_16x16x32_f16(ah[m], bh[n], acc[m][n], 0, 0, 0);
                    acc[m][n] = __builtin_amdgcn_mfma_f32_16x16x32_f16(al[m], bh[n], acc[m][n], 0, 0, 0);
                    if (PASSES == 3)
                        acc[m][n] = __builtin_amdgcn_mfma_f32_16x16x32_f16(ah[m], bl[n], acc[m][n], 0, 0, 0);
                }
        }
        __syncthreads();
    }

    // epilogue: C/D layout col=lane&15, row=(lane>>4)*4+reg (m89-verified)
#pragma unroll
    for (int m = 0; m < 4; ++m) {
#pragma unroll
        for (int n = 0; n < NF; ++n) {
            int row0 = m0 + wr * 64 + m * 16 + lk * 4;
            int col  = n0 + wc * (BN / 2) + n * 16 + lm;
            float bv = bias[col];
#pragma unroll
            for (int r = 0; r < 4; ++r) {
                float v = acc[m][n][r] + bv;
                if (GELU) v = 0.5f * v * (1.0f + erff(v * 0.70710678118654752f));
                size_t idx = (size_t)(row0 + r) * N + col;
                if (OUTSPLIT) {
                    u16 hi, lo; split2(v, hi, lo);
                    Chi[idx] = hi; Clo[idx] = lo;
                } else {
                    Cf[idx] = v;
                }
            }
        }
    }
}

// ---- row LayerNorm over D=384; writes f32 dst + hi/lo fp16 planes; ADD: dst += LN
template <int ADD>
__global__ __launch_bounds__(256) void ln_rows(
    const float* __restrict__ src, float* __restrict__ dst,
    u16* __restrict__ dhi, u16* __restrict__ dlo,
    const float* __restrict__ s, const float* __restrict__ bvec)
{
    int wid = blockIdx.x * 4 + (threadIdx.x >> 6);
    int lane = threadIdx.x & 63;
    const float* r = src + (size_t)wid * D_;
    float v[6]; float sum = 0.f;
#pragma unroll
    for (int t = 0; t < 6; ++t) { v[t] = r[lane + 64 * t]; sum += v[t]; }
    sum = wave_sum(sum);
    float mean = sum * (1.0f / D_);
    float vs = 0.f;
#pragma unroll
    for (int t = 0; t < 6; ++t) { float d = v[t] - mean; vs += d * d; }
    vs = wave_sum(vs);
    float rstd = rsqrtf(vs * (1.0f / D_) + 1e-5f);
    float* wo = dst + (size_t)wid * D_;
    u16* wh = dhi + (size_t)wid * D_;
    u16* wl = dlo + (size_t)wid * D_;
#pragma unroll
    for (int t = 0; t < 6; ++t) {
        int d = lane + 64 * t;
        float o = (v[t] - mean) * rstd * s[d] + bvec[d];
        float nv = ADD ? (wo[d] + o) : o;
        wo[d] = nv;
        u16 hi, lo; split2(nv, hi, lo);
        wh[d] = hi; wl[d] = lo;
    }
}

// ---- fused: windowed scores + softmax -> P, then new_centers = P@V,
//      X_out += LN(new_centers), refresh hi/lo planes. One wave per (b,o).
//      K/V interleaved in one [row][768] buffer (K at +0, V at +384).
__global__ __launch_bounds__(256) void attn_nc(
    const float* __restrict__ Q, const float* __restrict__ KV,
    const float* __restrict__ biasp, float* __restrict__ P,
    const float* __restrict__ lns, const float* __restrict__ lnb,
    float* __restrict__ Xout, u16* __restrict__ Xhi, u16* __restrict__ Xlo)
{
    int wid = blockIdx.x * 4 + (threadIdx.x >> 6);   // (b,o)
    int lane = threadIdx.x & 63;
    int b = wid / N_OUT, o = wid % N_OUT;
    int yo = o / 28, xo = o % 28;
    float q[6];
    const float* qr = Q + (size_t)wid * D_;
#pragma unroll
    for (int t = 0; t < 6; ++t) q[t] = qr[lane + 64 * t];

    float s[9]; bool valid[9];
#pragma unroll
    for (int j = 0; j < 9; ++j) {
        int dy = j / 3 - 1, dx = j % 3 - 1;
        int yi = 2 * yo + dy, xi = 2 * xo + dx;
        bool ok = (yi >= 0) && (yi < H_) && (xi >= 0) && (xi < W_);
        valid[j] = ok;
        float acc = 0.f;
        if (ok) {
            const float* kr = KV + (size_t)(b * N_IN + yi * W_ + xi) * KVSTR;
#pragma unroll
            for (int t = 0; t < 6; ++t) acc += q[t] * kr[lane + 64 * t];
        }
        s[j] = acc;
    }
#pragma unroll
    for (int j = 0; j < 9; ++j) s[j] = wave_sum(s[j]);
    float bias = *biasp;
    float mx = -1e30f;
#pragma unroll
    for (int j = 0; j < 9; ++j) if (valid[j]) mx = fmaxf(mx, s[j] + bias);
    float e[9]; float tot = 0.f;
#pragma unroll
    for (int j = 0; j < 9; ++j) { e[j] = valid[j] ? expf(s[j] + bias - mx) : 0.0f; tot += e[j]; }
    float inv = 1.0f / tot;
#pragma unroll
    for (int j = 0; j < 9; ++j) e[j] *= inv;
    if (lane < 12) P[(size_t)wid * 12 + lane] = (lane < 9) ? e[lane] : 0.0f;

    // ---- P @ V over the window
    float acc[6] = {0, 0, 0, 0, 0, 0};
#pragma unroll
    for (int j = 0; j < 9; ++j) {
        if (valid[j]) {
            int dy = j / 3 - 1, dx = j % 3 - 1;
            int yi = 2 * yo + dy, xi = 2 * xo + dx;
            const float* vr = KV + (size_t)(b * N_IN + yi * W_ + xi) * KVSTR + 384;
#pragma unroll
            for (int t = 0; t < 6; ++t) acc[t] += e[j] * vr[lane + 64 * t];
        }
    }
    float sum = 0.f;
#pragma unroll
    for (int t = 0; t < 6; ++t) sum += acc[t];
    sum = wave_sum(sum);
    float mean = sum * (1.0f / D_);
    float vs = 0.f;
#pragma unroll
    for (int t = 0; t < 6; ++t) { float d = acc[t] - mean; vs += d * d; }
    vs = wave_sum(vs);
    float rstd = rsqrtf(vs * (1.0f / D_) + 1e-5f);
    float* wo = Xout + (size_t)wid * D_;
    u16* wh = Xhi + (size_t)wid * D_;
    u16* wl = Xlo + (size_t)wid * D_;
#pragma unroll
    for (int t = 0; t < 6; ++t) {
        int d = lane + 64 * t;
        float nv = wo[d] + (acc[t] - mean) * rstd * lns[d] + lnb[d];
        wo[d] = nv;
        u16 hi, lo; split2(nv, hi, lo);
        wh[d] = hi; wl[d] = lo;
    }
}

// ---- per-(b, input pixel) column sum of A_ups
__global__ void colsum_k(const float* __restrict__ P, float* __restrict__ cs) {
    int idx = blockIdx.x * 256 + threadIdx.x;
    if (idx >= B_ * N_IN) return;
    int b = idx / N_IN, i = idx % N_IN;
    int yi = i / W_, xi = i % W_;
    float sum = 0.f;
    int yc = yi >> 1, xc = xi >> 1;
    for (int yo = yc - 1; yo <= yc + 1; ++yo) {
        if (yo < 0 || yo >= 28) continue;
        int dy = yi - 2 * yo;
        if (dy < -1 || dy > 1) continue;
        for (int xo = xc - 1; xo <= xc + 1; ++xo) {
            if (xo < 0 || xo >= 28) continue;
            int dx = xi - 2 * xo;
            if (dx < -1 || dx > 1) continue;
            int j = (dy + 1) * 3 + (dx + 1);
            sum += P[((size_t)(b * N_OUT + yo * 28 + xo)) * 12 + j];
        }
    }
    cs[idx] = sum;
}

// ---- dense A_ups/A_down writer: one block per (b,o) row; zero row then fix window
__global__ __launch_bounds__(256) void write_A(
    const float* __restrict__ P, const float* __restrict__ cs,
    float* __restrict__ Aups, float* __restrict__ Adown)
{
    int wid = blockIdx.x;                 // (b,o)
    int b = wid / N_OUT, o = wid % N_OUT;
    int yo = o / 28, xo = o % 28;
    float4 z = {0.f, 0.f, 0.f, 0.f};
    float4* up = reinterpret_cast<float4*>(Aups + (size_t)wid * N_IN);
    float4* dn = reinterpret_cast<float4*>(Adown + (size_t)wid * N_IN);
    for (int i = threadIdx.x; i < N_IN / 4; i += 256) { up[i] = z; dn[i] = z; }
    __syncthreads();
    int j = threadIdx.x;
    if (j < 9) {
        int dy = j / 3 - 1, dx = j % 3 - 1;
        int yi = 2 * yo + dy, xi = 2 * xo + dx;
        if (yi >= 0 && yi < H_ && xi >= 0 && xi < W_) {
            int i = yi * W_ + xi;
            float p = P[(size_t)wid * 12 + j];
            Aups[(size_t)wid * N_IN + i] = p;
            Adown[(size_t)wid * N_IN + i] = p / (1e-10f + cs[b * N_IN + i]);
        }
    }
}

extern "C" void kernel_launch(void* const* d_in, const int* in_sizes, int n_in,
                              void* d_out, int out_size, void* d_ws, size_t ws_size,
                              hipStream_t stream)
{
    const float* X_in      = (const float*)d_in[0];
    const float* conv_w    = (const float*)d_in[1];
    const float* conv_b    = (const float*)d_in[2];
    const float* ln_init_s = (const float*)d_in[3];
    const float* ln_init_b = (const float*)d_in[4];
    const float* qw        = (const float*)d_in[5];
    const float* qb        = (const float*)d_in[6];
    const float* kw        = (const float*)d_in[7];
    const float* kb        = (const float*)d_in[8];
    const float* vw        = (const float*)d_in[9];
    const float* vb        = (const float*)d_in[10];
    const float* ln_out_s  = (const float*)d_in[11];
    const float* ln_out_b  = (const float*)d_in[12];
    const float* w1        = (const float*)d_in[13];
    const float* b1        = (const float*)d_in[14];
    const float* w2        = (const float*)d_in[15];
    const float* b2        = (const float*)d_in[16];
    const float* mlp_s     = (const float*)d_in[17];
    const float* mlp_b     = (const float*)d_in[18];
    const float* rel_bias  = (const float*)d_in[19];
    (void)in_sizes; (void)n_in; (void)out_size; (void)ws_size;

    float* out   = (float*)d_out;
    float* Xout  = out;                    // (M_OUT, D) f32 — final output 0
    float* Adown = out + XOUT_ELEMS;       // (B, N_OUT, N_IN)
    float* Aups  = Adown + A_ELEMS;

    // dead A-region overlays (all dead before the final write_A):
    float* Abase = Adown;                            // 2*A_ELEMS floats total
    float* KVf   = Abase;                            // M_IN*768 f32 (154MB): K|V interleaved
    u16* XinHi = (u16*)(Abase + 38535168);           // M_IN*D u16
    u16* XinLo = (u16*)(Abase + 48168960);
    u16* h1Hi  = (u16*)(Abase + 57802752);           // M_OUT*HID u16
    u16* h1Lo  = (u16*)(Abase + 65028096);

    float* ws    = (float*)d_ws;
    float* tmpD  = ws;                               // M_OUT*D f32 (conv out / Q / h2)
    float* Pb    = tmpD + XOUT_ELEMS;                // M_OUT*12
    float* cs    = Pb + (size_t)M_OUT * 12;          // B_*N_IN
    float* biasv = cs + B_ * N_IN;                   // 4
    float* kvb   = biasv + 4;                        // 768
    u16* XoutHi = (u16*)(kvb + 768);                 // M_OUT*D
    u16* XoutLo = XoutHi + XOUT_ELEMS;
    u16* qwTh   = XoutLo + XOUT_ELEMS;               // 384*384 each
    u16* qwTl   = qwTh + 147456;
    u16* kvTh   = qwTl + 147456;                     // 768*384 (kw rows then vw rows)
    u16* kvTl   = kvTh + 294912;
    u16* w1Th   = kvTl + 294912;                     // 1152*384
    u16* w1Tl   = w1Th + 442368;
    u16* w2Th   = w1Tl + 442368;                     // 384*1152
    u16* w2Tl   = w2Th + 442368;
    u16* cvTh   = w2Tl + 442368;                     // 384*1536
    u16* cvTl   = cvTh + 589824;

    // ---- prep: split conversions + weight transposes
    hipLaunchKernelGGL(cvt_split, dim3(2048), dim3(256), 0, stream,
                       X_in, XinHi, XinLo, (size_t)M_IN * D_ / 4);
    hipLaunchKernelGGL(transpose_split, dim3(12, 12), dim3(256), 0, stream, qw, qwTh, qwTl, 384, 384);
    hipLaunchKernelGGL(transpose_split, dim3(12, 12), dim3(256), 0, stream, kw, kvTh, kvTl, 384, 384);
    hipLaunchKernelGGL(transpose_split, dim3(12, 12), dim3(256), 0, stream,
                       vw, kvTh + 147456, kvTl + 147456, 384, 384);
    hipLaunchKernelGGL(transpose_split, dim3(36, 12), dim3(256), 0, stream, w1, w1Th, w1Tl, 384, 1152);
    hipLaunchKernelGGL(transpose_split, dim3(12, 36), dim3(256), 0, stream, w2, w2Th, w2Tl, 1152, 384);
    hipLaunchKernelGGL(prep_convw_split, dim3((384 * 1536 + 255) / 256), dim3(256), 0, stream,
                       conv_w, cvTh, cvTl);
    hipLaunchKernelGGL(bias_mean, dim3(1), dim3(64), 0, stream, rel_bias, biasv);
    hipLaunchKernelGGL(concat_bias, dim3(3), dim3(256), 0, stream, kb, vb, kvb);

    // ---- init_proj conv (im2col, fp16 2-pass, BN=64) -> tmpD, X_out = LN(tmpD)
    hipLaunchKernelGGL((gemm_split<1, 0, 0, 2, 64>), dim3(6, 98), dim3(256), 0, stream,
                       XinHi, XinLo, cvTh, cvTl, conv_b, tmpD, (u16*)0, (u16*)0, M_OUT, D_, 4 * D_);
    hipLaunchKernelGGL((ln_rows<0>), dim3(M_OUT / 4), dim3(256), 0, stream,
                       tmpD, Xout, XoutHi, XoutLo, ln_init_s, ln_init_b);

    // ---- K|V projection (single GEMM, N=768, fp16 2-pass, BN=128)
    hipLaunchKernelGGL((gemm_split<0, 0, 0, 2, 128>), dim3(6, 392), dim3(256), 0, stream,
                       XinHi, XinLo, kvTh, kvTl, kvb, KVf, (u16*)0, (u16*)0, M_IN, KVSTR, D_);

    for (int it = 0; it < 3; ++it) {
        hipLaunchKernelGGL((gemm_split<0, 0, 0, 2, 64>), dim3(6, 98), dim3(256), 0, stream,
                           XoutHi, XoutLo, qwTh, qwTl, qb, tmpD, (u16*)0, (u16*)0, M_OUT, D_, D_);
        hipLaunchKernelGGL(attn_nc, dim3(M_OUT / 4), dim3(256), 0, stream,
                           tmpD, KVf, biasv, Pb, ln_out_s, ln_out_b, Xout, XoutHi, XoutLo);
        hipLaunchKernelGGL((gemm_split<0, 1, 1, 2, 128>), dim3(9, 98), dim3(256), 0, stream,
                           XoutHi, XoutLo, w1Th, w1Tl, b1, (float*)0, h1Hi, h1Lo, M_OUT, HID_, D_);
        hipLaunchKernelGGL((gemm_split<0, 0, 0, 2, 64>), dim3(6, 98), dim3(256), 0, stream,
                           h1Hi, h1Lo, w2Th, w2Tl, b2, tmpD, (u16*)0, (u16*)0, M_OUT, D_, HID_);
        hipLaunchKernelGGL((ln_rows<1>), dim3(M_OUT / 4), dim3(256), 0, stream,
                           tmpD, Xout, XoutHi, XoutLo, mlp_s, mlp_b);
    }

    // ---- all A-region temporaries dead now; build dense A_ups/A_down from it==2's Pb
    hipLaunchKernelGGL(colsum_k, dim3((B_ * N_IN + 255) / 256), dim3(256), 0, stream, Pb, cs);
    hipLaunchKernelGGL(write_A, dim3(M_OUT), dim3(256), 0, stream, Pb, cs, Aups, Adown);
}

// Round 12
// 651.049 us; speedup vs baseline: 3.0459x; 1.1555x over previous
//
#include <hip/hip_runtime.h>
#include <hip/hip_bf16.h>
#include <math.h>

#define B_    16
#define H_    56
#define W_    56
#define D_    384
#define HID_  1152
#define N_IN  3136
#define N_OUT 784
#define M_OUT (B_ * N_OUT)   // 12544
#define M_IN  (B_ * N_IN)    // 50176
#define KVSTR 768

#define XOUT_ELEMS ((size_t)M_OUT * D_)          // 4,816,896
#define A_ELEMS    ((size_t)B_ * N_OUT * N_IN)   // 39,337,984

typedef unsigned short u16;
using frag_h  = __attribute__((ext_vector_type(8))) _Float16;  // 8 fp16 (4 VGPRs)
using frag_cd = __attribute__((ext_vector_type(4))) float;     // 4 fp32

// fp16 two-plane split: hi 11-bit mantissa, lo covers to ~2^-22 rel.
__device__ __forceinline__ void split2(float f, u16& hi, u16& lo) {
    _Float16 h = (_Float16)f;
    hi = *reinterpret_cast<u16*>(&h);
    float r = f - (float)h;
    _Float16 l = (_Float16)r;
    lo = *reinterpret_cast<u16*>(&l);
}
__device__ __forceinline__ u16 f2h(float f) {
    _Float16 h = (_Float16)f;
    return *reinterpret_cast<u16*>(&h);
}
__device__ __forceinline__ float h2f(u16 u) {
    _Float16 h = *reinterpret_cast<_Float16*>(&u);
    return (float)h;
}

__device__ __forceinline__ float wave_sum(float x) {
#pragma unroll
    for (int off = 32; off; off >>= 1) x += __shfl_xor(x, off, 64);
    return x;
}

#define GLD16(g, l) __builtin_amdgcn_global_load_lds( \
    (const __attribute__((address_space(1))) void*)(g), \
    (__attribute__((address_space(3))) void*)(l), 16, 0, 0)

// ---- f32 -> (hi, lo) fp16 planes, float4 vectorized
__global__ void cvt_split(const float* __restrict__ in, u16* __restrict__ hi,
                          u16* __restrict__ lo, size_t n4) {
    size_t i = (size_t)blockIdx.x * 256 + threadIdx.x;
    size_t stride = (size_t)gridDim.x * 256;
    for (; i < n4; i += stride) {
        float4 v = reinterpret_cast<const float4*>(in)[i];
        ushort4 h, l;
        split2(v.x, h.x, l.x); split2(v.y, h.y, l.y);
        split2(v.z, h.z, l.z); split2(v.w, h.w, l.w);
        reinterpret_cast<ushort4*>(hi)[i] = h;
        reinterpret_cast<ushort4*>(lo)[i] = l;
    }
}

// ---- W[K][N] f32 -> Bt[N][K] hi/lo fp16 (LDS-tiled transpose)
__global__ void transpose_split(const float* __restrict__ Wm, u16* __restrict__ Bh,
                                u16* __restrict__ Bl, int K, int N) {
    __shared__ float t[32][33];
    int k0 = blockIdx.y * 32, n0 = blockIdx.x * 32;
    int r = threadIdx.x >> 5, c = threadIdx.x & 31;
#pragma unroll
    for (int i = 0; i < 4; ++i) t[r + 8 * i][c] = Wm[(size_t)(k0 + r + 8 * i) * N + n0 + c];
    __syncthreads();
#pragma unroll
    for (int i = 0; i < 4; ++i) {
        u16 hi, lo;
        split2(t[c][r + 8 * i], hi, lo);
        size_t idx = (size_t)(n0 + r + 8 * i) * K + k0 + c;
        Bh[idx] = hi; Bl[idx] = lo;
    }
}

// ---- conv weight: wknT[n][kk] hi/lo, kk = p*384 + c ; conv_w OIHW [n][c][p]
__global__ void prep_convw_split(const float* __restrict__ cw, u16* __restrict__ Bh,
                                 u16* __restrict__ Bl) {
    int idx = blockIdx.x * 256 + threadIdx.x;
    if (idx >= 384 * 1536) return;
    int n = idx / 1536, kk = idx % 1536;
    int p = kk / 384, c = kk % 384;
    u16 hi, lo;
    split2(cw[n * 1536 + c * 4 + p], hi, lo);
    Bh[idx] = hi; Bl[idx] = lo;
}

__global__ void bias_mean(const float* __restrict__ rb, float* __restrict__ out) {
    if (threadIdx.x == 0) {
        float s = 0.f;
        for (int i = 0; i < 25; ++i) s += rb[i];
        *out = s / 25.0f;
    }
}

// ---- concat kb|vb -> kvb[768]
__global__ void concat_bias(const float* __restrict__ a, const float* __restrict__ b,
                            float* __restrict__ o) {
    int i = threadIdx.x + blockIdx.x * 256;
    if (i < 384) o[i] = a[i];
    else if (i < 768) o[i] = b[i - 384];
}

// ---- split-fp16 MFMA GEMM: C = A @ Bt^T + bias.
// 2-pass: AhBh + AlBh (A f32-accurate, B fp16 2^-11 — measured safe R10/R11).
// OUTMODE: 0 = f32, 1 = split hi/lo planes, 2 = single fp16 (KV buffer).
// 128xBN tile, BK=64, 4 waves; global_load_lds + XOR-swizzle; XCD remap.
template <int IM2COL, int GELU, int OUTMODE, int PASSES, int BN>
__global__ __launch_bounds__(256,
    ((32768 + BN * 128 * ((PASSES == 3) ? 2 : 1)) <= 40960) ? 4 :
    ((32768 + BN * 128 * ((PASSES == 3) ? 2 : 1)) <= 49152) ? 3 : 2)
void gemm_split(
    const u16* __restrict__ Ah, const u16* __restrict__ Al,
    const u16* __restrict__ Bth, const u16* __restrict__ Btl,
    const float* __restrict__ bias, float* __restrict__ Cf,
    u16* __restrict__ Chi, u16* __restrict__ Clo,
    int M, int N, int K)
{
    constexpr int NF = BN / 32;          // n-frags per wave
    __shared__ u16 sAh[128 * 64];
    __shared__ u16 sAl[128 * 64];
    __shared__ u16 sBh[BN * 64];
    __shared__ u16 sBl[(PASSES == 3) ? BN * 64 : 8];
    const int t = threadIdx.x;
    const int lane = t & 63;
    const int w = t >> 6;
    const int wr = w >> 1, wc = w & 1;
    const int lm = lane & 15, lk = lane >> 4;

    // ---- XCD-aware (y,x) remap
    const int gx = gridDim.x, ny = gridDim.y;
    int d = blockIdx.y * gx + blockIdx.x;
    const int covered = (ny >> 3) * 8 * gx;
    int m_y, n_x;
    if (d < covered) {
        int c = d / (8 * gx), l = d % (8 * gx);
        m_y = c * 8 + (l & 7);
        n_x = l >> 3;
    } else {
        int l = d - covered;
        m_y = (ny & ~7) + l / gx;
        n_x = l % gx;
    }
    const int m0 = m_y * 128;
    const int n0 = n_x * BN;

    const int rt = t >> 3, st = t & 7;                    // staging row-sub, 16B slot
    const int skel = ((st * 16) ^ ((rt & 7) << 4)) >> 1;  // swizzle-inverse src k-elem

    int pb4[4];
    if (IM2COL) {
#pragma unroll
        for (int i = 0; i < 4; ++i) {
            int m = m0 + i * 32 + rt;
            int bb = m / N_OUT, o = m - bb * N_OUT;
            pb4[i] = bb * N_IN + (o / 28) * 112 + (o % 28) * 2;
        }
    }

    frag_cd acc[4][NF];
#pragma unroll
    for (int i = 0; i < 4; ++i)
#pragma unroll
        for (int j = 0; j < NF; ++j) acc[i][j] = (frag_cd){0.f, 0.f, 0.f, 0.f};

    const int swzf = (lm & 7) << 4;

    for (int kt = 0; kt < K; kt += 64) {
#pragma unroll
        for (int i = 0; i < 4; ++i) {
            int r = i * 32 + rt;
            size_t aoff;
            if (IM2COL) {
                int k = kt + skel;
                int p = k / 384, c = k - p * 384;
                aoff = ((size_t)pb4[i] + (p >> 1) * 56 + (p & 1)) * 384 + c;
            } else {
                aoff = (size_t)(m0 + r) * K + kt + skel;
            }
            GLD16(Ah + aoff, &sAh[i * 2048 + t * 8]);
            GLD16(Al + aoff, &sAl[i * 2048 + t * 8]);
        }
#pragma unroll
        for (int i = 0; i < BN / 32; ++i) {
            int r = i * 32 + rt;
            size_t boff = (size_t)(n0 + r) * K + kt + skel;
            GLD16(Bth + boff, &sBh[i * 2048 + t * 8]);
            if (PASSES == 3) GLD16(Btl + boff, &sBl[i * 2048 + t * 8]);
        }
        __syncthreads();

#pragma unroll
        for (int h = 0; h < 2; ++h) {
            const int kb = (h * 64 + lk * 16) ^ swzf;
            frag_h ah[4], al[4], bh[NF], bl[NF];
#pragma unroll
            for (int m = 0; m < 4; ++m) {
                int arow = wr * 64 + m * 16 + lm;
                ah[m] = *reinterpret_cast<const frag_h*>(reinterpret_cast<const char*>(sAh) + arow * 128 + kb);
                al[m] = *reinterpret_cast<const frag_h*>(reinterpret_cast<const char*>(sAl) + arow * 128 + kb);
            }
#pragma unroll
            for (int n = 0; n < NF; ++n) {
                int brow = wc * (BN / 2) + n * 16 + lm;
                bh[n] = *reinterpret_cast<const frag_h*>(reinterpret_cast<const char*>(sBh) + brow * 128 + kb);
                if (PASSES == 3)
                    bl[n] = *reinterpret_cast<const frag_h*>(reinterpret_cast<const char*>(sBl) + brow * 128 + kb);
            }
#pragma unroll
            for (int m = 0; m < 4; ++m)
#pragma unroll
                for (int n = 0; n < NF; ++n) {
                    acc[m][n] = __builtin_amdgcn_mfma_f32_16x16x32_f16(ah[m], bh[n], acc[m][n], 0, 0, 0);
                    acc[m][n] = __builtin_amdgcn_mfma_f32_16x16x32_f16(al[m], bh[n], acc[m][n], 0, 0, 0);
                    if (PASSES == 3)
                        acc[m][n] = __builtin_amdgcn_mfma_f32_16x16x32_f16(ah[m], bl[n], acc[m][n], 0, 0, 0);
                }
        }
        __syncthreads();
    }

    // epilogue: C/D layout col=lane&15, row=(lane>>4)*4+reg (m89-verified)
#pragma unroll
    for (int m = 0; m < 4; ++m) {
#pragma unroll
        for (int n = 0; n < NF; ++n) {
            int row0 = m0 + wr * 64 + m * 16 + lk * 4;
            int col  = n0 + wc * (BN / 2) + n * 16 + lm;
            float bv = bias[col];
#pragma unroll
            for (int r = 0; r < 4; ++r) {
                float v = acc[m][n][r] + bv;
                if (GELU) v = 0.5f * v * (1.0f + erff(v * 0.70710678118654752f));
                size_t idx = (size_t)(row0 + r) * N + col;
                if (OUTMODE == 1) {
                    u16 hi, lo; split2(v, hi, lo);
                    Chi[idx] = hi; Clo[idx] = lo;
                } else if (OUTMODE == 2) {
                    Chi[idx] = f2h(v);
                } else {
                    Cf[idx] = v;
                }
            }
        }
    }
}

// ---- row LayerNorm over D=384; dst planes hi/lo fp16; residual from hi+lo.
// WF32: also write f32 dst (final output pass only).
template <int ADD, int WF32>
__global__ __launch_bounds__(256) void ln_rows(
    const float* __restrict__ src, float* __restrict__ dst,
    u16* __restrict__ dhi, u16* __restrict__ dlo,
    const float* __restrict__ s, const float* __restrict__ bvec)
{
    int wid = blockIdx.x * 4 + (threadIdx.x >> 6);
    int lane = threadIdx.x & 63;
    const float* r = src + (size_t)wid * D_;
    float v[6]; float sum = 0.f;
#pragma unroll
    for (int t = 0; t < 6; ++t) { v[t] = r[lane + 64 * t]; sum += v[t]; }
    sum = wave_sum(sum);
    float mean = sum * (1.0f / D_);
    float vs = 0.f;
#pragma unroll
    for (int t = 0; t < 6; ++t) { float d = v[t] - mean; vs += d * d; }
    vs = wave_sum(vs);
    float rstd = rsqrtf(vs * (1.0f / D_) + 1e-5f);
    float* wo = dst + (size_t)wid * D_;
    u16* wh = dhi + (size_t)wid * D_;
    u16* wl = dlo + (size_t)wid * D_;
#pragma unroll
    for (int t = 0; t < 6; ++t) {
        int d = lane + 64 * t;
        float o = (v[t] - mean) * rstd * s[d] + bvec[d];
        float nv = ADD ? (h2f(wh[d]) + h2f(wl[d]) + o) : o;
        if (WF32) wo[d] = nv;
        u16 hi, lo; split2(nv, hi, lo);
        wh[d] = hi; wl[d] = lo;
    }
}

// ---- fused: windowed scores + softmax -> P, then new_centers = P@V,
//      X_out += LN(new_centers) (planes only). KV is single-fp16 [row][768].
__global__ __launch_bounds__(256) void attn_nc(
    const float* __restrict__ Q, const u16* __restrict__ KV,
    const float* __restrict__ biasp, float* __restrict__ P,
    const float* __restrict__ lns, const float* __restrict__ lnb,
    u16* __restrict__ Xhi, u16* __restrict__ Xlo)
{
    int wid = blockIdx.x * 4 + (threadIdx.x >> 6);   // (b,o)
    int lane = threadIdx.x & 63;
    int b = wid / N_OUT, o = wid % N_OUT;
    int yo = o / 28, xo = o % 28;
    float q[6];
    const float* qr = Q + (size_t)wid * D_;
#pragma unroll
    for (int t = 0; t < 6; ++t) q[t] = qr[lane + 64 * t];

    float s[9]; bool valid[9];
#pragma unroll
    for (int j = 0; j < 9; ++j) {
        int dy = j / 3 - 1, dx = j % 3 - 1;
        int yi = 2 * yo + dy, xi = 2 * xo + dx;
        bool ok = (yi >= 0) && (yi < H_) && (xi >= 0) && (xi < W_);
        valid[j] = ok;
        float acc = 0.f;
        if (ok) {
            const u16* kr = KV + (size_t)(b * N_IN + yi * W_ + xi) * KVSTR;
#pragma unroll
            for (int t = 0; t < 6; ++t) acc += q[t] * h2f(kr[lane + 64 * t]);
        }
        s[j] = acc;
    }
#pragma unroll
    for (int j = 0; j < 9; ++j) s[j] = wave_sum(s[j]);
    float bias = *biasp;
    float mx = -1e30f;
#pragma unroll
    for (int j = 0; j < 9; ++j) if (valid[j]) mx = fmaxf(mx, s[j] + bias);
    float e[9]; float tot = 0.f;
#pragma unroll
    for (int j = 0; j < 9; ++j) { e[j] = valid[j] ? expf(s[j] + bias - mx) : 0.0f; tot += e[j]; }
    float inv = 1.0f / tot;
#pragma unroll
    for (int j = 0; j < 9; ++j) e[j] *= inv;
    if (lane < 12) P[(size_t)wid * 12 + lane] = (lane < 9) ? e[lane] : 0.0f;

    // ---- P @ V over the window
    float acc[6] = {0, 0, 0, 0, 0, 0};
#pragma unroll
    for (int j = 0; j < 9; ++j) {
        if (valid[j]) {
            int dy = j / 3 - 1, dx = j % 3 - 1;
            int yi = 2 * yo + dy, xi = 2 * xo + dx;
            const u16* vr = KV + (size_t)(b * N_IN + yi * W_ + xi) * KVSTR + 384;
#pragma unroll
            for (int t = 0; t < 6; ++t) acc[t] += e[j] * h2f(vr[lane + 64 * t]);
        }
    }
    float sum = 0.f;
#pragma unroll
    for (int t = 0; t < 6; ++t) sum += acc[t];
    sum = wave_sum(sum);
    float mean = sum * (1.0f / D_);
    float vs = 0.f;
#pragma unroll
    for (int t = 0; t < 6; ++t) { float d = acc[t] - mean; vs += d * d; }
    vs = wave_sum(vs);
    float rstd = rsqrtf(vs * (1.0f / D_) + 1e-5f);
    u16* wh = Xhi + (size_t)wid * D_;
    u16* wl = Xlo + (size_t)wid * D_;
#pragma unroll
    for (int t = 0; t < 6; ++t) {
        int d = lane + 64 * t;
        float nv = h2f(wh[d]) + h2f(wl[d]) + (acc[t] - mean) * rstd * lns[d] + lnb[d];
        u16 hi, lo; split2(nv, hi, lo);
        wh[d] = hi; wl[d] = lo;
    }
}

// ---- per-(b, input pixel) column sum of A_ups
__global__ void colsum_k(const float* __restrict__ P, float* __restrict__ cs) {
    int idx = blockIdx.x * 256 + threadIdx.x;
    if (idx >= B_ * N_IN) return;
    int b = idx / N_IN, i = idx % N_IN;
    int yi = i / W_, xi = i % W_;
    float sum = 0.f;
    int yc = yi >> 1, xc = xi >> 1;
    for (int yo = yc - 1; yo <= yc + 1; ++yo) {
        if (yo < 0 || yo >= 28) continue;
        int dy = yi - 2 * yo;
        if (dy < -1 || dy > 1) continue;
        for (int xo = xc - 1; xo <= xc + 1; ++xo) {
            if (xo < 0 || xo >= 28) continue;
            int dx = xi - 2 * xo;
            if (dx < -1 || dx > 1) continue;
            int j = (dy + 1) * 3 + (dx + 1);
            sum += P[((size_t)(b * N_OUT + yo * 28 + xo)) * 12 + j];
        }
    }
    cs[idx] = sum;
}

// ---- dense A_ups/A_down writer: one block per (b,o) row; zero row then fix window
__global__ __launch_bounds__(256) void write_A(
    const float* __restrict__ P, const float* __restrict__ cs,
    float* __restrict__ Aups, float* __restrict__ Adown)
{
    int wid = blockIdx.x;                 // (b,o)
    int b = wid / N_OUT, o = wid % N_OUT;
    int yo = o / 28, xo = o % 28;
    float4 z = {0.f, 0.f, 0.f, 0.f};
    float4* up = reinterpret_cast<float4*>(Aups + (size_t)wid * N_IN);
    float4* dn = reinterpret_cast<float4*>(Adown + (size_t)wid * N_IN);
    for (int i = threadIdx.x; i < N_IN / 4; i += 256) { up[i] = z; dn[i] = z; }
    __syncthreads();
    int j = threadIdx.x;
    if (j < 9) {
        int dy = j / 3 - 1, dx = j % 3 - 1;
        int yi = 2 * yo + dy, xi = 2 * xo + dx;
        if (yi >= 0 && yi < H_ && xi >= 0 && xi < W_) {
            int i = yi * W_ + xi;
            float p = P[(size_t)wid * 12 + j];
            Aups[(size_t)wid * N_IN + i] = p;
            Adown[(size_t)wid * N_IN + i] = p / (1e-10f + cs[b * N_IN + i]);
        }
    }
}

extern "C" void kernel_launch(void* const* d_in, const int* in_sizes, int n_in,
                              void* d_out, int out_size, void* d_ws, size_t ws_size,
                              hipStream_t stream)
{
    const float* X_in      = (const float*)d_in[0];
    const float* conv_w    = (const float*)d_in[1];
    const float* conv_b    = (const float*)d_in[2];
    const float* ln_init_s = (const float*)d_in[3];
    const float* ln_init_b = (const float*)d_in[4];
    const float* qw        = (const float*)d_in[5];
    const float* qb        = (const float*)d_in[6];
    const float* kw        = (const float*)d_in[7];
    const float* kb        = (const float*)d_in[8];
    const float* vw        = (const float*)d_in[9];
    const float* vb        = (const float*)d_in[10];
    const float* ln_out_s  = (const float*)d_in[11];
    const float* ln_out_b  = (const float*)d_in[12];
    const float* w1        = (const float*)d_in[13];
    const float* b1        = (const float*)d_in[14];
    const float* w2        = (const float*)d_in[15];
    const float* b2        = (const float*)d_in[16];
    const float* mlp_s     = (const float*)d_in[17];
    const float* mlp_b     = (const float*)d_in[18];
    const float* rel_bias  = (const float*)d_in[19];
    (void)in_sizes; (void)n_in; (void)out_size; (void)ws_size;

    float* out   = (float*)d_out;
    float* Xout  = out;                    // (M_OUT, D) f32 — final output 0 (written last)
    float* Adown = out + XOUT_ELEMS;       // (B, N_OUT, N_IN)
    float* Aups  = Adown + A_ELEMS;

    // dead A-region overlays (all dead before the final write_A):
    float* Abase = Adown;                            // 2*A_ELEMS floats total
    u16* KVu   = (u16*)Abase;                        // M_IN*768 fp16 (77MB): K|V interleaved
    u16* XinHi = (u16*)(Abase + 38535168);           // M_IN*D u16
    u16* XinLo = (u16*)(Abase + 48168960);
    u16* h1Hi  = (u16*)(Abase + 57802752);           // M_OUT*HID u16
    u16* h1Lo  = (u16*)(Abase + 65028096);

    float* ws    = (float*)d_ws;
    float* tmpD  = ws;                               // M_OUT*D f32 (conv out / Q / h2)
    float* Pb    = tmpD + XOUT_ELEMS;                // M_OUT*12
    float* cs    = Pb + (size_t)M_OUT * 12;          // B_*N_IN
    float* biasv = cs + B_ * N_IN;                   // 4
    float* kvb   = biasv + 4;                        // 768
    u16* XoutHi = (u16*)(kvb + 768);                 // M_OUT*D
    u16* XoutLo = XoutHi + XOUT_ELEMS;
    u16* qwTh   = XoutLo + XOUT_ELEMS;               // 384*384 each
    u16* qwTl   = qwTh + 147456;
    u16* kvTh   = qwTl + 147456;                     // 768*384 (kw rows then vw rows)
    u16* kvTl   = kvTh + 294912;
    u16* w1Th   = kvTl + 294912;                     // 1152*384
    u16* w1Tl   = w1Th + 442368;
    u16* w2Th   = w1Tl + 442368;                     // 384*1152
    u16* w2Tl   = w2Th + 442368;
    u16* cvTh   = w2Tl + 442368;                     // 384*1536
    u16* cvTl   = cvTh + 589824;

    // ---- prep: split conversions + weight transposes
    hipLaunchKernelGGL(cvt_split, dim3(2048), dim3(256), 0, stream,
                       X_in, XinHi, XinLo, (size_t)M_IN * D_ / 4);
    hipLaunchKernelGGL(transpose_split, dim3(12, 12), dim3(256), 0, stream, qw, qwTh, qwTl, 384, 384);
    hipLaunchKernelGGL(transpose_split, dim3(12, 12), dim3(256), 0, stream, kw, kvTh, kvTl, 384, 384);
    hipLaunchKernelGGL(transpose_split, dim3(12, 12), dim3(256), 0, stream,
                       vw, kvTh + 147456, kvTl + 147456, 384, 384);
    hipLaunchKernelGGL(transpose_split, dim3(36, 12), dim3(256), 0, stream, w1, w1Th, w1Tl, 384, 1152);
    hipLaunchKernelGGL(transpose_split, dim3(12, 36), dim3(256), 0, stream, w2, w2Th, w2Tl, 1152, 384);
    hipLaunchKernelGGL(prep_convw_split, dim3((384 * 1536 + 255) / 256), dim3(256), 0, stream,
                       conv_w, cvTh, cvTl);
    hipLaunchKernelGGL(bias_mean, dim3(1), dim3(64), 0, stream, rel_bias, biasv);
    hipLaunchKernelGGL(concat_bias, dim3(3), dim3(256), 0, stream, kb, vb, kvb);

    // ---- init_proj conv (im2col, fp16 2-pass, BN=64) -> tmpD, X_out = LN(tmpD) [planes]
    hipLaunchKernelGGL((gemm_split<1, 0, 0, 2, 64>), dim3(6, 98), dim3(256), 0, stream,
                       XinHi, XinLo, cvTh, cvTl, conv_b, tmpD, (u16*)0, (u16*)0, M_OUT, D_, 4 * D_);
    hipLaunchKernelGGL((ln_rows<0, 0>), dim3(M_OUT / 4), dim3(256), 0, stream,
                       tmpD, Xout, XoutHi, XoutLo, ln_init_s, ln_init_b);

    // ---- K|V projection (single GEMM, N=768, fp16 2-pass, fp16 OUT, BN=128)
    hipLaunchKernelGGL((gemm_split<0, 0, 2, 2, 128>), dim3(6, 392), dim3(256), 0, stream,
                       XinHi, XinLo, kvTh, kvTl, kvb, (float*)0, KVu, (u16*)0, M_IN, KVSTR, D_);

    for (int it = 0; it < 3; ++it) {
        hipLaunchKernelGGL((gemm_split<0, 0, 0, 2, 64>), dim3(6, 98), dim3(256), 0, stream,
                           XoutHi, XoutLo, qwTh, qwTl, qb, tmpD, (u16*)0, (u16*)0, M_OUT, D_, D_);
        hipLaunchKernelGGL(attn_nc, dim3(M_OUT / 4), dim3(256), 0, stream,
                           tmpD, KVu, biasv, Pb, ln_out_s, ln_out_b, XoutHi, XoutLo);
        hipLaunchKernelGGL((gemm_split<0, 1, 1, 2, 128>), dim3(9, 98), dim3(256), 0, stream,
                           XoutHi, XoutLo, w1Th, w1Tl, b1, (float*)0, h1Hi, h1Lo, M_OUT, HID_, D_);
        hipLaunchKernelGGL((gemm_split<0, 0, 0, 2, 64>), dim3(6, 98), dim3(256), 0, stream,
                           h1Hi, h1Lo, w2Th, w2Tl, b2, tmpD, (u16*)0, (u16*)0, M_OUT, D_, HID_);
        if (it < 2) {
            hipLaunchKernelGGL((ln_rows<1, 0>), dim3(M_OUT / 4), dim3(256), 0, stream,
                               tmpD, Xout, XoutHi, XoutLo, mlp_s, mlp_b);
        } else {
            // final pass: also materialize f32 Xout (output 0)
            hipLaunchKernelGGL((ln_rows<1, 1>), dim3(M_OUT / 4), dim3(256), 0, stream,
                               tmpD, Xout, XoutHi, XoutLo, mlp_s, mlp_b);
        }
    }

    // ---- all A-region temporaries dead now; build dense A_ups/A_down from it==2's Pb
    hipLaunchKernelGGL(colsum_k, dim3((B_ * N_IN + 255) / 256), dim3(256), 0, stream, Pb, cs);
    hipLaunchKernelGGL(write_A, dim3(M_OUT), dim3(256), 0, stream, Pb, cs, Aups, Adown);
}

// Round 13
// 591.869 us; speedup vs baseline: 3.3505x; 1.1000x over previous
//
#include <hip/hip_runtime.h>
#include <hip/hip_bf16.h>
#include <math.h>

#define B_    16
#define H_    56
#define W_    56
#define D_    384
#define HID_  1152
#define N_IN  3136
#define N_OUT 784
#define M_OUT (B_ * N_OUT)   // 12544
#define M_IN  (B_ * N_IN)    // 50176
#define KVSTR 768

#define XOUT_ELEMS ((size_t)M_OUT * D_)          // 4,816,896
#define A_ELEMS    ((size_t)B_ * N_OUT * N_IN)   // 39,337,984

typedef unsigned short u16;
using frag_h  = __attribute__((ext_vector_type(8))) _Float16;  // 8 fp16 (4 VGPRs)
using frag_cd = __attribute__((ext_vector_type(4))) float;     // 4 fp32

// fp16 two-plane split: hi 11-bit mantissa, lo covers to ~2^-22 rel.
__device__ __forceinline__ void split2(float f, u16& hi, u16& lo) {
    _Float16 h = (_Float16)f;
    hi = *reinterpret_cast<u16*>(&h);
    float r = f - (float)h;
    _Float16 l = (_Float16)r;
    lo = *reinterpret_cast<u16*>(&l);
}
__device__ __forceinline__ u16 f2h(float f) {
    _Float16 h = (_Float16)f;
    return *reinterpret_cast<u16*>(&h);
}
__device__ __forceinline__ float h2f(u16 u) {
    _Float16 h = *reinterpret_cast<_Float16*>(&u);
    return (float)h;
}

__device__ __forceinline__ float wave_sum(float x) {
#pragma unroll
    for (int off = 32; off; off >>= 1) x += __shfl_xor(x, off, 64);
    return x;
}

#define GLD16(g, l) __builtin_amdgcn_global_load_lds( \
    (const __attribute__((address_space(1))) void*)(g), \
    (__attribute__((address_space(3))) void*)(l), 16, 0, 0)

// ---- f32 -> (hi, lo) fp16 planes, float4 vectorized
__global__ void cvt_split(const float* __restrict__ in, u16* __restrict__ hi,
                          u16* __restrict__ lo, size_t n4) {
    size_t i = (size_t)blockIdx.x * 256 + threadIdx.x;
    size_t stride = (size_t)gridDim.x * 256;
    for (; i < n4; i += stride) {
        float4 v = reinterpret_cast<const float4*>(in)[i];
        ushort4 h, l;
        split2(v.x, h.x, l.x); split2(v.y, h.y, l.y);
        split2(v.z, h.z, l.z); split2(v.w, h.w, l.w);
        reinterpret_cast<ushort4*>(hi)[i] = h;
        reinterpret_cast<ushort4*>(lo)[i] = l;
    }
}

// ---- W[K][N] f32 -> Bt[N][K] hi/lo fp16 (LDS-tiled transpose)
__global__ void transpose_split(const float* __restrict__ Wm, u16* __restrict__ Bh,
                                u16* __restrict__ Bl, int K, int N) {
    __shared__ float t[32][33];
    int k0 = blockIdx.y * 32, n0 = blockIdx.x * 32;
    int r = threadIdx.x >> 5, c = threadIdx.x & 31;
#pragma unroll
    for (int i = 0; i < 4; ++i) t[r + 8 * i][c] = Wm[(size_t)(k0 + r + 8 * i) * N + n0 + c];
    __syncthreads();
#pragma unroll
    for (int i = 0; i < 4; ++i) {
        u16 hi, lo;
        split2(t[c][r + 8 * i], hi, lo);
        size_t idx = (size_t)(n0 + r + 8 * i) * K + k0 + c;
        Bh[idx] = hi; Bl[idx] = lo;
    }
}

// ---- conv weight: wknT[n][kk] hi/lo, kk = p*384 + c ; conv_w OIHW [n][c][p]
__global__ void prep_convw_split(const float* __restrict__ cw, u16* __restrict__ Bh,
                                 u16* __restrict__ Bl) {
    int idx = blockIdx.x * 256 + threadIdx.x;
    if (idx >= 384 * 1536) return;
    int n = idx / 1536, kk = idx % 1536;
    int p = kk / 384, c = kk % 384;
    u16 hi, lo;
    split2(cw[n * 1536 + c * 4 + p], hi, lo);
    Bh[idx] = hi; Bl[idx] = lo;
}

__global__ void bias_mean(const float* __restrict__ rb, float* __restrict__ out) {
    if (threadIdx.x == 0) {
        float s = 0.f;
        for (int i = 0; i < 25; ++i) s += rb[i];
        *out = s / 25.0f;
    }
}

// ---- concat kb|vb -> kvb[768]
__global__ void concat_bias(const float* __restrict__ a, const float* __restrict__ b,
                            float* __restrict__ o) {
    int i = threadIdx.x + blockIdx.x * 256;
    if (i < 384) o[i] = a[i];
    else if (i < 768) o[i] = b[i - 384];
}

// ---- split-fp16 MFMA GEMM: C = A @ Bt^T + bias.
// PASSES: 1 = AhBh (A and B single fp16, 2^-11 each — w2 path),
//         2 = AhBh + AlBh (A f32-accurate, B 2^-11 — measured safe R10-R12),
//         3 = + AhBl (kept available).
// OUTMODE: 0 = f32, 1 = split hi/lo planes, 2 = single fp16.
// 128xBN tile, BK=64, 4 waves; global_load_lds + XOR-swizzle; XCD remap.
template <int IM2COL, int GELU, int OUTMODE, int PASSES, int BN>
__global__ __launch_bounds__(256,
    ((((PASSES >= 2) ? 32768 : 16384) + BN * 128 * ((PASSES == 3) ? 2 : 1)) <= 40960) ? 4 :
    ((((PASSES >= 2) ? 32768 : 16384) + BN * 128 * ((PASSES == 3) ? 2 : 1)) <= 49152) ? 3 : 2)
void gemm_split(
    const u16* __restrict__ Ah, const u16* __restrict__ Al,
    const u16* __restrict__ Bth, const u16* __restrict__ Btl,
    const float* __restrict__ bias, float* __restrict__ Cf,
    u16* __restrict__ Chi, u16* __restrict__ Clo,
    int M, int N, int K)
{
    constexpr int NF = BN / 32;          // n-frags per wave
    __shared__ u16 sAh[128 * 64];
    __shared__ u16 sAl[(PASSES >= 2) ? 128 * 64 : 8];
    __shared__ u16 sBh[BN * 64];
    __shared__ u16 sBl[(PASSES == 3) ? BN * 64 : 8];
    const int t = threadIdx.x;
    const int lane = t & 63;
    const int w = t >> 6;
    const int wr = w >> 1, wc = w & 1;
    const int lm = lane & 15, lk = lane >> 4;

    // ---- XCD-aware (y,x) remap
    const int gx = gridDim.x, ny = gridDim.y;
    int d = blockIdx.y * gx + blockIdx.x;
    const int covered = (ny >> 3) * 8 * gx;
    int m_y, n_x;
    if (d < covered) {
        int c = d / (8 * gx), l = d % (8 * gx);
        m_y = c * 8 + (l & 7);
        n_x = l >> 3;
    } else {
        int l = d - covered;
        m_y = (ny & ~7) + l / gx;
        n_x = l % gx;
    }
    const int m0 = m_y * 128;
    const int n0 = n_x * BN;

    const int rt = t >> 3, st = t & 7;                    // staging row-sub, 16B slot
    const int skel = ((st * 16) ^ ((rt & 7) << 4)) >> 1;  // swizzle-inverse src k-elem

    int pb4[4];
    if (IM2COL) {
#pragma unroll
        for (int i = 0; i < 4; ++i) {
            int m = m0 + i * 32 + rt;
            int bb = m / N_OUT, o = m - bb * N_OUT;
            pb4[i] = bb * N_IN + (o / 28) * 112 + (o % 28) * 2;
        }
    }

    frag_cd acc[4][NF];
#pragma unroll
    for (int i = 0; i < 4; ++i)
#pragma unroll
        for (int j = 0; j < NF; ++j) acc[i][j] = (frag_cd){0.f, 0.f, 0.f, 0.f};

    const int swzf = (lm & 7) << 4;

    for (int kt = 0; kt < K; kt += 64) {
#pragma unroll
        for (int i = 0; i < 4; ++i) {
            int r = i * 32 + rt;
            size_t aoff;
            if (IM2COL) {
                int k = kt + skel;
                int p = k / 384, c = k - p * 384;
                aoff = ((size_t)pb4[i] + (p >> 1) * 56 + (p & 1)) * 384 + c;
            } else {
                aoff = (size_t)(m0 + r) * K + kt + skel;
            }
            GLD16(Ah + aoff, &sAh[i * 2048 + t * 8]);
            if (PASSES >= 2) GLD16(Al + aoff, &sAl[i * 2048 + t * 8]);
        }
#pragma unroll
        for (int i = 0; i < BN / 32; ++i) {
            int r = i * 32 + rt;
            size_t boff = (size_t)(n0 + r) * K + kt + skel;
            GLD16(Bth + boff, &sBh[i * 2048 + t * 8]);
            if (PASSES == 3) GLD16(Btl + boff, &sBl[i * 2048 + t * 8]);
        }
        __syncthreads();

#pragma unroll
        for (int h = 0; h < 2; ++h) {
            const int kb = (h * 64 + lk * 16) ^ swzf;
            frag_h ah[4], al[4], bh[NF], bl[NF];
#pragma unroll
            for (int m = 0; m < 4; ++m) {
                int arow = wr * 64 + m * 16 + lm;
                ah[m] = *reinterpret_cast<const frag_h*>(reinterpret_cast<const char*>(sAh) + arow * 128 + kb);
                if (PASSES >= 2)
                    al[m] = *reinterpret_cast<const frag_h*>(reinterpret_cast<const char*>(sAl) + arow * 128 + kb);
            }
#pragma unroll
            for (int n = 0; n < NF; ++n) {
                int brow = wc * (BN / 2) + n * 16 + lm;
                bh[n] = *reinterpret_cast<const frag_h*>(reinterpret_cast<const char*>(sBh) + brow * 128 + kb);
                if (PASSES == 3)
                    bl[n] = *reinterpret_cast<const frag_h*>(reinterpret_cast<const char*>(sBl) + brow * 128 + kb);
            }
#pragma unroll
            for (int m = 0; m < 4; ++m)
#pragma unroll
                for (int n = 0; n < NF; ++n) {
                    acc[m][n] = __builtin_amdgcn_mfma_f32_16x16x32_f16(ah[m], bh[n], acc[m][n], 0, 0, 0);
                    if (PASSES >= 2)
                        acc[m][n] = __builtin_amdgcn_mfma_f32_16x16x32_f16(al[m], bh[n], acc[m][n], 0, 0, 0);
                    if (PASSES == 3)
                        acc[m][n] = __builtin_amdgcn_mfma_f32_16x16x32_f16(ah[m], bl[n], acc[m][n], 0, 0, 0);
                }
        }
        __syncthreads();
    }

    // epilogue: C/D layout col=lane&15, row=(lane>>4)*4+reg (m89-verified)
#pragma unroll
    for (int m = 0; m < 4; ++m) {
#pragma unroll
        for (int n = 0; n < NF; ++n) {
            int row0 = m0 + wr * 64 + m * 16 + lk * 4;
            int col  = n0 + wc * (BN / 2) + n * 16 + lm;
            float bv = bias[col];
#pragma unroll
            for (int r = 0; r < 4; ++r) {
                float v = acc[m][n][r] + bv;
                if (GELU) v = 0.5f * v * (1.0f + erff(v * 0.70710678118654752f));
                size_t idx = (size_t)(row0 + r) * N + col;
                if (OUTMODE == 1) {
                    u16 hi, lo; split2(v, hi, lo);
                    Chi[idx] = hi; Clo[idx] = lo;
                } else if (OUTMODE == 2) {
                    Chi[idx] = f2h(v);
                } else {
                    Cf[idx] = v;
                }
            }
        }
    }
}

// ---- row LayerNorm over D=384; dst planes hi/lo fp16; residual from hi+lo.
// WF32: also write f32 dst (final output pass only).
template <int ADD, int WF32>
__global__ __launch_bounds__(256) void ln_rows(
    const float* __restrict__ src, float* __restrict__ dst,
    u16* __restrict__ dhi, u16* __restrict__ dlo,
    const float* __restrict__ s, const float* __restrict__ bvec)
{
    int wid = blockIdx.x * 4 + (threadIdx.x >> 6);
    int lane = threadIdx.x & 63;
    const float* r = src + (size_t)wid * D_;
    float v[6]; float sum = 0.f;
#pragma unroll
    for (int t = 0; t < 6; ++t) { v[t] = r[lane + 64 * t]; sum += v[t]; }
    sum = wave_sum(sum);
    float mean = sum * (1.0f / D_);
    float vs = 0.f;
#pragma unroll
    for (int t = 0; t < 6; ++t) { float d = v[t] - mean; vs += d * d; }
    vs = wave_sum(vs);
    float rstd = rsqrtf(vs * (1.0f / D_) + 1e-5f);
    float* wo = dst + (size_t)wid * D_;
    u16* wh = dhi + (size_t)wid * D_;
    u16* wl = dlo + (size_t)wid * D_;
#pragma unroll
    for (int t = 0; t < 6; ++t) {
        int d = lane + 64 * t;
        float o = (v[t] - mean) * rstd * s[d] + bvec[d];
        float nv = ADD ? (h2f(wh[d]) + h2f(wl[d]) + o) : o;
        if (WF32) wo[d] = nv;
        u16 hi, lo; split2(nv, hi, lo);
        wh[d] = hi; wl[d] = lo;
    }
}

// ---- fused: windowed scores + softmax -> P, then new_centers = P@V,
//      X_out += LN(new_centers) (planes only). Q and KV single-fp16.
__global__ __launch_bounds__(256) void attn_nc(
    const u16* __restrict__ Q, const u16* __restrict__ KV,
    const float* __restrict__ biasp, float* __restrict__ P,
    const float* __restrict__ lns, const float* __restrict__ lnb,
    u16* __restrict__ Xhi, u16* __restrict__ Xlo)
{
    int wid = blockIdx.x * 4 + (threadIdx.x >> 6);   // (b,o)
    int lane = threadIdx.x & 63;
    int b = wid / N_OUT, o = wid % N_OUT;
    int yo = o / 28, xo = o % 28;
    float q[6];
    const u16* qr = Q + (size_t)wid * D_;
#pragma unroll
    for (int t = 0; t < 6; ++t) q[t] = h2f(qr[lane + 64 * t]);

    float s[9]; bool valid[9];
#pragma unroll
    for (int j = 0; j < 9; ++j) {
        int dy = j / 3 - 1, dx = j % 3 - 1;
        int yi = 2 * yo + dy, xi = 2 * xo + dx;
        bool ok = (yi >= 0) && (yi < H_) && (xi >= 0) && (xi < W_);
        valid[j] = ok;
        float acc = 0.f;
        if (ok) {
            const u16* kr = KV + (size_t)(b * N_IN + yi * W_ + xi) * KVSTR;
#pragma unroll
            for (int t = 0; t < 6; ++t) acc += q[t] * h2f(kr[lane + 64 * t]);
        }
        s[j] = acc;
    }
#pragma unroll
    for (int j = 0; j < 9; ++j) s[j] = wave_sum(s[j]);
    float bias = *biasp;
    float mx = -1e30f;
#pragma unroll
    for (int j = 0; j < 9; ++j) if (valid[j]) mx = fmaxf(mx, s[j] + bias);
    float e[9]; float tot = 0.f;
#pragma unroll
    for (int j = 0; j < 9; ++j) { e[j] = valid[j] ? expf(s[j] + bias - mx) : 0.0f; tot += e[j]; }
    float inv = 1.0f / tot;
#pragma unroll
    for (int j = 0; j < 9; ++j) e[j] *= inv;
    if (lane < 12) P[(size_t)wid * 12 + lane] = (lane < 9) ? e[lane] : 0.0f;

    // ---- P @ V over the window
    float acc[6] = {0, 0, 0, 0, 0, 0};
#pragma unroll
    for (int j = 0; j < 9; ++j) {
        if (valid[j]) {
            int dy = j / 3 - 1, dx = j % 3 - 1;
            int yi = 2 * yo + dy, xi = 2 * xo + dx;
            const u16* vr = KV + (size_t)(b * N_IN + yi * W_ + xi) * KVSTR + 384;
#pragma unroll
            for (int t = 0; t < 6; ++t) acc[t] += e[j] * h2f(vr[lane + 64 * t]);
        }
    }
    float sum = 0.f;
#pragma unroll
    for (int t = 0; t < 6; ++t) sum += acc[t];
    sum = wave_sum(sum);
    float mean = sum * (1.0f / D_);
    float vs = 0.f;
#pragma unroll
    for (int t = 0; t < 6; ++t) { float d = acc[t] - mean; vs += d * d; }
    vs = wave_sum(vs);
    float rstd = rsqrtf(vs * (1.0f / D_) + 1e-5f);
    u16* wh = Xhi + (size_t)wid * D_;
    u16* wl = Xlo + (size_t)wid * D_;
#pragma unroll
    for (int t = 0; t < 6; ++t) {
        int d = lane + 64 * t;
        float nv = h2f(wh[d]) + h2f(wl[d]) + (acc[t] - mean) * rstd * lns[d] + lnb[d];
        u16 hi, lo; split2(nv, hi, lo);
        wh[d] = hi; wl[d] = lo;
    }
}

// ---- dense A_ups/A_down writer: one block per (b,o) row; zero row, fix window.
// Column sums computed inline (<=4 P contributors per input pixel).
__global__ __launch_bounds__(256) void write_A(
    const float* __restrict__ P,
    float* __restrict__ Aups, float* __restrict__ Adown)
{
    int wid = blockIdx.x;                 // (b,o)
    int b = wid / N_OUT, o = wid % N_OUT;
    int yo = o / 28, xo = o % 28;
    float4 z = {0.f, 0.f, 0.f, 0.f};
    float4* up = reinterpret_cast<float4*>(Aups + (size_t)wid * N_IN);
    float4* dn = reinterpret_cast<float4*>(Adown + (size_t)wid * N_IN);
    for (int i = threadIdx.x; i < N_IN / 4; i += 256) { up[i] = z; dn[i] = z; }
    __syncthreads();
    int j = threadIdx.x;
    if (j < 9) {
        int dy = j / 3 - 1, dx = j % 3 - 1;
        int yi = 2 * yo + dy, xi = 2 * xo + dx;
        if (yi >= 0 && yi < H_ && xi >= 0 && xi < W_) {
            int i = yi * W_ + xi;
            float p = P[(size_t)wid * 12 + j];
            // column sum over all (yo2, xo2) windows containing pixel (yi, xi)
            float csum = 0.f;
            int yc = yi >> 1, xc = xi >> 1;
            for (int yo2 = yc - 1; yo2 <= yc + 1; ++yo2) {
                if (yo2 < 0 || yo2 >= 28) continue;
                int dy2 = yi - 2 * yo2;
                if (dy2 < -1 || dy2 > 1) continue;
                for (int xo2 = xc - 1; xo2 <= xc + 1; ++xo2) {
                    if (xo2 < 0 || xo2 >= 28) continue;
                    int dx2 = xi - 2 * xo2;
                    if (dx2 < -1 || dx2 > 1) continue;
                    int jj = (dy2 + 1) * 3 + (dx2 + 1);
                    csum += P[((size_t)(b * N_OUT + yo2 * 28 + xo2)) * 12 + jj];
                }
            }
            Aups[(size_t)wid * N_IN + i] = p;
            Adown[(size_t)wid * N_IN + i] = p / (1e-10f + csum);
        }
    }
}

extern "C" void kernel_launch(void* const* d_in, const int* in_sizes, int n_in,
                              void* d_out, int out_size, void* d_ws, size_t ws_size,
                              hipStream_t stream)
{
    const float* X_in      = (const float*)d_in[0];
    const float* conv_w    = (const float*)d_in[1];
    const float* conv_b    = (const float*)d_in[2];
    const float* ln_init_s = (const float*)d_in[3];
    const float* ln_init_b = (const float*)d_in[4];
    const float* qw        = (const float*)d_in[5];
    const float* qb        = (const float*)d_in[6];
    const float* kw        = (const float*)d_in[7];
    const float* kb        = (const float*)d_in[8];
    const float* vw        = (const float*)d_in[9];
    const float* vb        = (const float*)d_in[10];
    const float* ln_out_s  = (const float*)d_in[11];
    const float* ln_out_b  = (const float*)d_in[12];
    const float* w1        = (const float*)d_in[13];
    const float* b1        = (const float*)d_in[14];
    const float* w2        = (const float*)d_in[15];
    const float* b2        = (const float*)d_in[16];
    const float* mlp_s     = (const float*)d_in[17];
    const float* mlp_b     = (const float*)d_in[18];
    const float* rel_bias  = (const float*)d_in[19];
    (void)in_sizes; (void)n_in; (void)out_size; (void)ws_size;

    float* out   = (float*)d_out;
    float* Xout  = out;                    // (M_OUT, D) f32 — final output 0 (written last)
    float* Adown = out + XOUT_ELEMS;       // (B, N_OUT, N_IN)
    float* Aups  = Adown + A_ELEMS;

    // dead A-region overlays (all dead before the final write_A):
    float* Abase = Adown;                            // 2*A_ELEMS floats total
    u16* KVu   = (u16*)Abase;                        // M_IN*768 fp16 (77MB): K|V interleaved
    u16* XinHi = (u16*)(Abase + 38535168);           // M_IN*D u16
    u16* XinLo = (u16*)(Abase + 48168960);
    u16* h1U   = (u16*)(Abase + 57802752);           // M_OUT*HID u16 (single fp16)

    float* ws    = (float*)d_ws;
    float* tmpD  = ws;                               // M_OUT*D f32 (conv out / h2); Q aliases as u16
    float* Pb    = tmpD + XOUT_ELEMS;                // M_OUT*12
    float* biasv = Pb + (size_t)M_OUT * 12;          // 4
    float* kvb   = biasv + 4;                        // 768
    u16* XoutHi = (u16*)(kvb + 768);                 // M_OUT*D
    u16* XoutLo = XoutHi + XOUT_ELEMS;
    u16* qwTh   = XoutLo + XOUT_ELEMS;               // 384*384 each
    u16* qwTl   = qwTh + 147456;
    u16* kvTh   = qwTl + 147456;                     // 768*384 (kw rows then vw rows)
    u16* kvTl   = kvTh + 294912;
    u16* w1Th   = kvTl + 294912;                     // 1152*384
    u16* w1Tl   = w1Th + 442368;
    u16* w2Th   = w1Tl + 442368;                     // 384*1152
    u16* w2Tl   = w2Th + 442368;
    u16* cvTh   = w2Tl + 442368;                     // 384*1536
    u16* cvTl   = cvTh + 589824;
    u16* Qu     = (u16*)tmpD;                        // Q fp16 alias (used between conv and h2)

    // ---- prep: split conversions + weight transposes
    hipLaunchKernelGGL(cvt_split, dim3(2048), dim3(256), 0, stream,
                       X_in, XinHi, XinLo, (size_t)M_IN * D_ / 4);
    hipLaunchKernelGGL(transpose_split, dim3(12, 12), dim3(256), 0, stream, qw, qwTh, qwTl, 384, 384);
    hipLaunchKernelGGL(transpose_split, dim3(12, 12), dim3(256), 0, stream, kw, kvTh, kvTl, 384, 384);
    hipLaunchKernelGGL(transpose_split, dim3(12, 12), dim3(256), 0, stream,
                       vw, kvTh + 147456, kvTl + 147456, 384, 384);
    hipLaunchKernelGGL(transpose_split, dim3(36, 12), dim3(256), 0, stream, w1, w1Th, w1Tl, 384, 1152);
    hipLaunchKernelGGL(transpose_split, dim3(12, 36), dim3(256), 0, stream, w2, w2Th, w2Tl, 1152, 384);
    hipLaunchKernelGGL(prep_convw_split, dim3((384 * 1536 + 255) / 256), dim3(256), 0, stream,
                       conv_w, cvTh, cvTl);
    hipLaunchKernelGGL(bias_mean, dim3(1), dim3(64), 0, stream, rel_bias, biasv);
    hipLaunchKernelGGL(concat_bias, dim3(3), dim3(256), 0, stream, kb, vb, kvb);

    // ---- init_proj conv (im2col, fp16 2-pass, BN=64) -> tmpD, X_out = LN(tmpD) [planes]
    hipLaunchKernelGGL((gemm_split<1, 0, 0, 2, 64>), dim3(6, 98), dim3(256), 0, stream,
                       XinHi, XinLo, cvTh, cvTl, conv_b, tmpD, (u16*)0, (u16*)0, M_OUT, D_, 4 * D_);
    hipLaunchKernelGGL((ln_rows<0, 0>), dim3(M_OUT / 4), dim3(256), 0, stream,
                       tmpD, Xout, XoutHi, XoutLo, ln_init_s, ln_init_b);

    // ---- K|V projection (single GEMM, N=768, fp16 2-pass, fp16 OUT, BN=128)
    hipLaunchKernelGGL((gemm_split<0, 0, 2, 2, 128>), dim3(6, 392), dim3(256), 0, stream,
                       XinHi, XinLo, kvTh, kvTl, kvb, (float*)0, KVu, (u16*)0, M_IN, KVSTR, D_);

    for (int it = 0; it < 3; ++it) {
        // Q = Xout @ qw (2-pass A, fp16 single out into tmpD alias)
        hipLaunchKernelGGL((gemm_split<0, 0, 2, 2, 64>), dim3(6, 98), dim3(256), 0, stream,
                           XoutHi, XoutLo, qwTh, qwTl, qb, (float*)0, Qu, (u16*)0, M_OUT, D_, D_);
        hipLaunchKernelGGL(attn_nc, dim3(M_OUT / 4), dim3(256), 0, stream,
                           Qu, KVu, biasv, Pb, ln_out_s, ln_out_b, XoutHi, XoutLo);
        // h1 = GELU(Xout @ w1) (2-pass A, fp16 single out)
        hipLaunchKernelGGL((gemm_split<0, 1, 2, 2, 128>), dim3(9, 98), dim3(256), 0, stream,
                           XoutHi, XoutLo, w1Th, w1Tl, b1, (float*)0, h1U, (u16*)0, M_OUT, HID_, D_);
        // h2 = h1 @ w2 (1-pass: A single fp16, B single fp16) -> f32 tmpD
        hipLaunchKernelGGL((gemm_split<0, 0, 0, 1, 64>), dim3(6, 98), dim3(256), 0, stream,
                           h1U, (u16*)0, w2Th, w2Tl, b2, tmpD, (u16*)0, (u16*)0, M_OUT, D_, HID_);
        if (it < 2) {
            hipLaunchKernelGGL((ln_rows<1, 0>), dim3(M_OUT / 4), dim3(256), 0, stream,
                               tmpD, Xout, XoutHi, XoutLo, mlp_s, mlp_b);
        } else {
            // final pass: also materialize f32 Xout (output 0)
            hipLaunchKernelGGL((ln_rows<1, 1>), dim3(M_OUT / 4), dim3(256), 0, stream,
                               tmpD, Xout, XoutHi, XoutLo, mlp_s, mlp_b);
        }
    }

    // ---- all A-region temporaries dead now; build dense A_ups/A_down from it==2's Pb
    hipLaunchKernelGGL(write_A, dim3(M_OUT), dim3(256), 0, stream, Pb, Aups, Adown);
}

// Round 14
// 513.293 us; speedup vs baseline: 3.8634x; 1.1531x over previous
//
#include <hip/hip_runtime.h>
#include <hip/hip_bf16.h>
#include <math.h>

#define B_    16
#define H_    56
#define W_    56
#define D_    384
#define HID_  1152
#define N_IN  3136
#define N_OUT 784
#define M_OUT (B_ * N_OUT)   // 12544
#define M_IN  (B_ * N_IN)    // 50176
#define KVSTR 768

#define XOUT_ELEMS ((size_t)M_OUT * D_)          // 4,816,896
#define A_ELEMS    ((size_t)B_ * N_OUT * N_IN)   // 39,337,984

typedef unsigned short u16;
using frag_h  = __attribute__((ext_vector_type(8))) _Float16;  // 8 fp16 (4 VGPRs)
using frag_cd = __attribute__((ext_vector_type(4))) float;     // 4 fp32

// fp16 two-plane split: hi 11-bit mantissa, lo covers to ~2^-22 rel.
__device__ __forceinline__ void split2(float f, u16& hi, u16& lo) {
    _Float16 h = (_Float16)f;
    hi = *reinterpret_cast<u16*>(&h);
    float r = f - (float)h;
    _Float16 l = (_Float16)r;
    lo = *reinterpret_cast<u16*>(&l);
}
__device__ __forceinline__ u16 f2h(float f) {
    _Float16 h = (_Float16)f;
    return *reinterpret_cast<u16*>(&h);
}
__device__ __forceinline__ float h2f(u16 u) {
    _Float16 h = *reinterpret_cast<_Float16*>(&u);
    return (float)h;
}

__device__ __forceinline__ float wave_sum(float x) {
#pragma unroll
    for (int off = 32; off; off >>= 1) x += __shfl_xor(x, off, 64);
    return x;
}

#define GLD16(g, l) __builtin_amdgcn_global_load_lds( \
    (const __attribute__((address_space(1))) void*)(g), \
    (__attribute__((address_space(3))) void*)(l), 16, 0, 0)

// ---- f32 -> (hi, lo) fp16 planes, float4 vectorized
__global__ void cvt_split(const float* __restrict__ in, u16* __restrict__ hi,
                          u16* __restrict__ lo, size_t n4) {
    size_t i = (size_t)blockIdx.x * 256 + threadIdx.x;
    size_t stride = (size_t)gridDim.x * 256;
    for (; i < n4; i += stride) {
        float4 v = reinterpret_cast<const float4*>(in)[i];
        ushort4 h, l;
        split2(v.x, h.x, l.x); split2(v.y, h.y, l.y);
        split2(v.z, h.z, l.z); split2(v.w, h.w, l.w);
        reinterpret_cast<ushort4*>(hi)[i] = h;
        reinterpret_cast<ushort4*>(lo)[i] = l;
    }
}

// ---- W[K][N] f32 -> Bt[N][K] hi/lo fp16 (LDS-tiled transpose)
__global__ void transpose_split(const float* __restrict__ Wm, u16* __restrict__ Bh,
                                u16* __restrict__ Bl, int K, int N) {
    __shared__ float t[32][33];
    int k0 = blockIdx.y * 32, n0 = blockIdx.x * 32;
    int r = threadIdx.x >> 5, c = threadIdx.x & 31;
#pragma unroll
    for (int i = 0; i < 4; ++i) t[r + 8 * i][c] = Wm[(size_t)(k0 + r + 8 * i) * N + n0 + c];
    __syncthreads();
#pragma unroll
    for (int i = 0; i < 4; ++i) {
        u16 hi, lo;
        split2(t[c][r + 8 * i], hi, lo);
        size_t idx = (size_t)(n0 + r + 8 * i) * K + k0 + c;
        Bh[idx] = hi; Bl[idx] = lo;
    }
}

// ---- conv weight: wknT[n][kk] hi/lo, kk = p*384 + c ; conv_w OIHW [n][c][p]
__global__ void prep_convw_split(const float* __restrict__ cw, u16* __restrict__ Bh,
                                 u16* __restrict__ Bl) {
    int idx = blockIdx.x * 256 + threadIdx.x;
    if (idx >= 384 * 1536) return;
    int n = idx / 1536, kk = idx % 1536;
    int p = kk / 384, c = kk % 384;
    u16 hi, lo;
    split2(cw[n * 1536 + c * 4 + p], hi, lo);
    Bh[idx] = hi; Bl[idx] = lo;
}

__global__ void bias_mean(const float* __restrict__ rb, float* __restrict__ out) {
    if (threadIdx.x == 0) {
        float s = 0.f;
        for (int i = 0; i < 25; ++i) s += rb[i];
        *out = s / 25.0f;
    }
}

// ---- concat kb|vb -> kvb[768]
__global__ void concat_bias(const float* __restrict__ a, const float* __restrict__ b,
                            float* __restrict__ o) {
    int i = threadIdx.x + blockIdx.x * 256;
    if (i < 384) o[i] = a[i];
    else if (i < 768) o[i] = b[i - 384];
}

// ---- split-fp16 MFMA GEMM: C = A @ Bt^T + bias.
// PASSES: 1 = AhBh (both single fp16; safe when OUTPUT is also single fp16 —
//             the A-lo term would protect precision the output rounding discards),
//         2 = AhBh + AlBh (A f32-accurate; conv path — f32 out feeding residual),
//         3 = + AhBl (kept available).
// OUTMODE: 0 = f32, 1 = split hi/lo planes, 2 = single fp16.
// 128xBN tile, BK=64, 4 waves; global_load_lds + XOR-swizzle; XCD remap.
template <int IM2COL, int GELU, int OUTMODE, int PASSES, int BN>
__global__ __launch_bounds__(256,
    ((((PASSES >= 2) ? 32768 : 16384) + BN * 128 * ((PASSES == 3) ? 2 : 1)) <= 40960) ? 4 :
    ((((PASSES >= 2) ? 32768 : 16384) + BN * 128 * ((PASSES == 3) ? 2 : 1)) <= 49152) ? 3 : 2)
void gemm_split(
    const u16* __restrict__ Ah, const u16* __restrict__ Al,
    const u16* __restrict__ Bth, const u16* __restrict__ Btl,
    const float* __restrict__ bias, float* __restrict__ Cf,
    u16* __restrict__ Chi, u16* __restrict__ Clo,
    int M, int N, int K)
{
    constexpr int NF = BN / 32;          // n-frags per wave
    __shared__ u16 sAh[128 * 64];
    __shared__ u16 sAl[(PASSES >= 2) ? 128 * 64 : 8];
    __shared__ u16 sBh[BN * 64];
    __shared__ u16 sBl[(PASSES == 3) ? BN * 64 : 8];
    const int t = threadIdx.x;
    const int lane = t & 63;
    const int w = t >> 6;
    const int wr = w >> 1, wc = w & 1;
    const int lm = lane & 15, lk = lane >> 4;

    // ---- XCD-aware (y,x) remap
    const int gx = gridDim.x, ny = gridDim.y;
    int d = blockIdx.y * gx + blockIdx.x;
    const int covered = (ny >> 3) * 8 * gx;
    int m_y, n_x;
    if (d < covered) {
        int c = d / (8 * gx), l = d % (8 * gx);
        m_y = c * 8 + (l & 7);
        n_x = l >> 3;
    } else {
        int l = d - covered;
        m_y = (ny & ~7) + l / gx;
        n_x = l % gx;
    }
    const int m0 = m_y * 128;
    const int n0 = n_x * BN;

    const int rt = t >> 3, st = t & 7;                    // staging row-sub, 16B slot
    const int skel = ((st * 16) ^ ((rt & 7) << 4)) >> 1;  // swizzle-inverse src k-elem

    int pb4[4];
    if (IM2COL) {
#pragma unroll
        for (int i = 0; i < 4; ++i) {
            int m = m0 + i * 32 + rt;
            int bb = m / N_OUT, o = m - bb * N_OUT;
            pb4[i] = bb * N_IN + (o / 28) * 112 + (o % 28) * 2;
        }
    }

    frag_cd acc[4][NF];
#pragma unroll
    for (int i = 0; i < 4; ++i)
#pragma unroll
        for (int j = 0; j < NF; ++j) acc[i][j] = (frag_cd){0.f, 0.f, 0.f, 0.f};

    const int swzf = (lm & 7) << 4;

    for (int kt = 0; kt < K; kt += 64) {
#pragma unroll
        for (int i = 0; i < 4; ++i) {
            int r = i * 32 + rt;
            size_t aoff;
            if (IM2COL) {
                int k = kt + skel;
                int p = k / 384, c = k - p * 384;
                aoff = ((size_t)pb4[i] + (p >> 1) * 56 + (p & 1)) * 384 + c;
            } else {
                aoff = (size_t)(m0 + r) * K + kt + skel;
            }
            GLD16(Ah + aoff, &sAh[i * 2048 + t * 8]);
            if (PASSES >= 2) GLD16(Al + aoff, &sAl[i * 2048 + t * 8]);
        }
#pragma unroll
        for (int i = 0; i < BN / 32; ++i) {
            int r = i * 32 + rt;
            size_t boff = (size_t)(n0 + r) * K + kt + skel;
            GLD16(Bth + boff, &sBh[i * 2048 + t * 8]);
            if (PASSES == 3) GLD16(Btl + boff, &sBl[i * 2048 + t * 8]);
        }
        __syncthreads();

#pragma unroll
        for (int h = 0; h < 2; ++h) {
            const int kb = (h * 64 + lk * 16) ^ swzf;
            frag_h ah[4], al[4], bh[NF], bl[NF];
#pragma unroll
            for (int m = 0; m < 4; ++m) {
                int arow = wr * 64 + m * 16 + lm;
                ah[m] = *reinterpret_cast<const frag_h*>(reinterpret_cast<const char*>(sAh) + arow * 128 + kb);
                if (PASSES >= 2)
                    al[m] = *reinterpret_cast<const frag_h*>(reinterpret_cast<const char*>(sAl) + arow * 128 + kb);
            }
#pragma unroll
            for (int n = 0; n < NF; ++n) {
                int brow = wc * (BN / 2) + n * 16 + lm;
                bh[n] = *reinterpret_cast<const frag_h*>(reinterpret_cast<const char*>(sBh) + brow * 128 + kb);
                if (PASSES == 3)
                    bl[n] = *reinterpret_cast<const frag_h*>(reinterpret_cast<const char*>(sBl) + brow * 128 + kb);
            }
#pragma unroll
            for (int m = 0; m < 4; ++m)
#pragma unroll
                for (int n = 0; n < NF; ++n) {
                    acc[m][n] = __builtin_amdgcn_mfma_f32_16x16x32_f16(ah[m], bh[n], acc[m][n], 0, 0, 0);
                    if (PASSES >= 2)
                        acc[m][n] = __builtin_amdgcn_mfma_f32_16x16x32_f16(al[m], bh[n], acc[m][n], 0, 0, 0);
                    if (PASSES == 3)
                        acc[m][n] = __builtin_amdgcn_mfma_f32_16x16x32_f16(ah[m], bl[n], acc[m][n], 0, 0, 0);
                }
        }
        __syncthreads();
    }

    // epilogue: C/D layout col=lane&15, row=(lane>>4)*4+reg (m89-verified)
#pragma unroll
    for (int m = 0; m < 4; ++m) {
#pragma unroll
        for (int n = 0; n < NF; ++n) {
            int row0 = m0 + wr * 64 + m * 16 + lk * 4;
            int col  = n0 + wc * (BN / 2) + n * 16 + lm;
            float bv = bias[col];
#pragma unroll
            for (int r = 0; r < 4; ++r) {
                float v = acc[m][n][r] + bv;
                if (GELU) v = 0.5f * v * (1.0f + erff(v * 0.70710678118654752f));
                size_t idx = (size_t)(row0 + r) * N + col;
                if (OUTMODE == 1) {
                    u16 hi, lo; split2(v, hi, lo);
                    Chi[idx] = hi; Clo[idx] = lo;
                } else if (OUTMODE == 2) {
                    Chi[idx] = f2h(v);
                } else {
                    Cf[idx] = v;
                }
            }
        }
    }
}

// ---- row LayerNorm over D=384; dst planes hi/lo fp16; residual from hi+lo.
// WF32: also write f32 dst (final output pass only).
template <int ADD, int WF32>
__global__ __launch_bounds__(256) void ln_rows(
    const float* __restrict__ src, float* __restrict__ dst,
    u16* __restrict__ dhi, u16* __restrict__ dlo,
    const float* __restrict__ s, const float* __restrict__ bvec)
{
    int wid = blockIdx.x * 4 + (threadIdx.x >> 6);
    int lane = threadIdx.x & 63;
    const float* r = src + (size_t)wid * D_;
    float v[6]; float sum = 0.f;
#pragma unroll
    for (int t = 0; t < 6; ++t) { v[t] = r[lane + 64 * t]; sum += v[t]; }
    sum = wave_sum(sum);
    float mean = sum * (1.0f / D_);
    float vs = 0.f;
#pragma unroll
    for (int t = 0; t < 6; ++t) { float d = v[t] - mean; vs += d * d; }
    vs = wave_sum(vs);
    float rstd = rsqrtf(vs * (1.0f / D_) + 1e-5f);
    float* wo = dst + (size_t)wid * D_;
    u16* wh = dhi + (size_t)wid * D_;
    u16* wl = dlo + (size_t)wid * D_;
#pragma unroll
    for (int t = 0; t < 6; ++t) {
        int d = lane + 64 * t;
        float o = (v[t] - mean) * rstd * s[d] + bvec[d];
        float nv = ADD ? (h2f(wh[d]) + h2f(wl[d]) + o) : o;
        if (WF32) wo[d] = nv;
        u16 hi, lo; split2(nv, hi, lo);
        wh[d] = hi; wl[d] = lo;
    }
}

// ---- fused: windowed scores + softmax -> P, then new_centers = P@V,
//      X_out += LN(new_centers) (planes only). Q and KV single-fp16.
__global__ __launch_bounds__(256) void attn_nc(
    const u16* __restrict__ Q, const u16* __restrict__ KV,
    const float* __restrict__ biasp, float* __restrict__ P,
    const float* __restrict__ lns, const float* __restrict__ lnb,
    u16* __restrict__ Xhi, u16* __restrict__ Xlo)
{
    int wid = blockIdx.x * 4 + (threadIdx.x >> 6);   // (b,o)
    int lane = threadIdx.x & 63;
    int b = wid / N_OUT, o = wid % N_OUT;
    int yo = o / 28, xo = o % 28;
    float q[6];
    const u16* qr = Q + (size_t)wid * D_;
#pragma unroll
    for (int t = 0; t < 6; ++t) q[t] = h2f(qr[lane + 64 * t]);

    float s[9]; bool valid[9];
#pragma unroll
    for (int j = 0; j < 9; ++j) {
        int dy = j / 3 - 1, dx = j % 3 - 1;
        int yi = 2 * yo + dy, xi = 2 * xo + dx;
        bool ok = (yi >= 0) && (yi < H_) && (xi >= 0) && (xi < W_);
        valid[j] = ok;
        float acc = 0.f;
        if (ok) {
            const u16* kr = KV + (size_t)(b * N_IN + yi * W_ + xi) * KVSTR;
#pragma unroll
            for (int t = 0; t < 6; ++t) acc += q[t] * h2f(kr[lane + 64 * t]);
        }
        s[j] = acc;
    }
#pragma unroll
    for (int j = 0; j < 9; ++j) s[j] = wave_sum(s[j]);
    float bias = *biasp;
    float mx = -1e30f;
#pragma unroll
    for (int j = 0; j < 9; ++j) if (valid[j]) mx = fmaxf(mx, s[j] + bias);
    float e[9]; float tot = 0.f;
#pragma unroll
    for (int j = 0; j < 9; ++j) { e[j] = valid[j] ? expf(s[j] + bias - mx) : 0.0f; tot += e[j]; }
    float inv = 1.0f / tot;
#pragma unroll
    for (int j = 0; j < 9; ++j) e[j] *= inv;
    if (lane < 12) P[(size_t)wid * 12 + lane] = (lane < 9) ? e[lane] : 0.0f;

    // ---- P @ V over the window
    float acc[6] = {0, 0, 0, 0, 0, 0};
#pragma unroll
    for (int j = 0; j < 9; ++j) {
        if (valid[j]) {
            int dy = j / 3 - 1, dx = j % 3 - 1;
            int yi = 2 * yo + dy, xi = 2 * xo + dx;
            const u16* vr = KV + (size_t)(b * N_IN + yi * W_ + xi) * KVSTR + 384;
#pragma unroll
            for (int t = 0; t < 6; ++t) acc[t] += e[j] * h2f(vr[lane + 64 * t]);
        }
    }
    float sum = 0.f;
#pragma unroll
    for (int t = 0; t < 6; ++t) sum += acc[t];
    sum = wave_sum(sum);
    float mean = sum * (1.0f / D_);
    float vs = 0.f;
#pragma unroll
    for (int t = 0; t < 6; ++t) { float d = acc[t] - mean; vs += d * d; }
    vs = wave_sum(vs);
    float rstd = rsqrtf(vs * (1.0f / D_) + 1e-5f);
    u16* wh = Xhi + (size_t)wid * D_;
    u16* wl = Xlo + (size_t)wid * D_;
#pragma unroll
    for (int t = 0; t < 6; ++t) {
        int d = lane + 64 * t;
        float nv = h2f(wh[d]) + h2f(wl[d]) + (acc[t] - mean) * rstd * lns[d] + lnb[d];
        u16 hi, lo; split2(nv, hi, lo);
        wh[d] = hi; wl[d] = lo;
    }
}

// ---- dense A_ups/A_down writer: one block per (b,o) row; zero row, fix window.
// Column sums computed inline (<=4 P contributors per input pixel).
__global__ __launch_bounds__(256) void write_A(
    const float* __restrict__ P,
    float* __restrict__ Aups, float* __restrict__ Adown)
{
    int wid = blockIdx.x;                 // (b,o)
    int b = wid / N_OUT, o = wid % N_OUT;
    int yo = o / 28, xo = o % 28;
    float4 z = {0.f, 0.f, 0.f, 0.f};
    float4* up = reinterpret_cast<float4*>(Aups + (size_t)wid * N_IN);
    float4* dn = reinterpret_cast<float4*>(Adown + (size_t)wid * N_IN);
    for (int i = threadIdx.x; i < N_IN / 4; i += 256) { up[i] = z; dn[i] = z; }
    __syncthreads();
    int j = threadIdx.x;
    if (j < 9) {
        int dy = j / 3 - 1, dx = j % 3 - 1;
        int yi = 2 * yo + dy, xi = 2 * xo + dx;
        if (yi >= 0 && yi < H_ && xi >= 0 && xi < W_) {
            int i = yi * W_ + xi;
            float p = P[(size_t)wid * 12 + j];
            // column sum over all (yo2, xo2) windows containing pixel (yi, xi)
            float csum = 0.f;
            int yc = yi >> 1, xc = xi >> 1;
            for (int yo2 = yc - 1; yo2 <= yc + 1; ++yo2) {
                if (yo2 < 0 || yo2 >= 28) continue;
                int dy2 = yi - 2 * yo2;
                if (dy2 < -1 || dy2 > 1) continue;
                for (int xo2 = xc - 1; xo2 <= xc + 1; ++xo2) {
                    if (xo2 < 0 || xo2 >= 28) continue;
                    int dx2 = xi - 2 * xo2;
                    if (dx2 < -1 || dx2 > 1) continue;
                    int jj = (dy2 + 1) * 3 + (dx2 + 1);
                    csum += P[((size_t)(b * N_OUT + yo2 * 28 + xo2)) * 12 + jj];
                }
            }
            Aups[(size_t)wid * N_IN + i] = p;
            Adown[(size_t)wid * N_IN + i] = p / (1e-10f + csum);
        }
    }
}

extern "C" void kernel_launch(void* const* d_in, const int* in_sizes, int n_in,
                              void* d_out, int out_size, void* d_ws, size_t ws_size,
                              hipStream_t stream)
{
    const float* X_in      = (const float*)d_in[0];
    const float* conv_w    = (const float*)d_in[1];
    const float* conv_b    = (const float*)d_in[2];
    const float* ln_init_s = (const float*)d_in[3];
    const float* ln_init_b = (const float*)d_in[4];
    const float* qw        = (const float*)d_in[5];
    const float* qb        = (const float*)d_in[6];
    const float* kw        = (const float*)d_in[7];
    const float* kb        = (const float*)d_in[8];
    const float* vw        = (const float*)d_in[9];
    const float* vb        = (const float*)d_in[10];
    const float* ln_out_s  = (const float*)d_in[11];
    const float* ln_out_b  = (const float*)d_in[12];
    const float* w1        = (const float*)d_in[13];
    const float* b1        = (const float*)d_in[14];
    const float* w2        = (const float*)d_in[15];
    const float* b2        = (const float*)d_in[16];
    const float* mlp_s     = (const float*)d_in[17];
    const float* mlp_b     = (const float*)d_in[18];
    const float* rel_bias  = (const float*)d_in[19];
    (void)in_sizes; (void)n_in; (void)out_size; (void)ws_size;

    float* out   = (float*)d_out;
    float* Xout  = out;                    // (M_OUT, D) f32 — final output 0 (written last)
    float* Adown = out + XOUT_ELEMS;       // (B, N_OUT, N_IN)
    float* Aups  = Adown + A_ELEMS;

    // dead A-region overlays (all dead before the final write_A):
    float* Abase = Adown;                            // 2*A_ELEMS floats total
    u16* KVu   = (u16*)Abase;                        // M_IN*768 fp16 (77MB): K|V interleaved
    u16* XinHi = (u16*)(Abase + 38535168);           // M_IN*D u16
    u16* XinLo = (u16*)(Abase + 48168960);
    u16* h1U   = (u16*)(Abase + 57802752);           // M_OUT*HID u16 (single fp16)

    float* ws    = (float*)d_ws;
    float* tmpD  = ws;                               // M_OUT*D f32 (conv out / h2); Q aliases as u16
    float* Pb    = tmpD + XOUT_ELEMS;                // M_OUT*12
    float* biasv = Pb + (size_t)M_OUT * 12;          // 4
    float* kvb   = biasv + 4;                        // 768
    u16* XoutHi = (u16*)(kvb + 768);                 // M_OUT*D
    u16* XoutLo = XoutHi + XOUT_ELEMS;
    u16* qwTh   = XoutLo + XOUT_ELEMS;               // 384*384 each
    u16* qwTl   = qwTh + 147456;
    u16* kvTh   = qwTl + 147456;                     // 768*384 (kw rows then vw rows)
    u16* kvTl   = kvTh + 294912;
    u16* w1Th   = kvTl + 294912;                     // 1152*384
    u16* w1Tl   = w1Th + 442368;
    u16* w2Th   = w1Tl + 442368;                     // 384*1152
    u16* w2Tl   = w2Th + 442368;
    u16* cvTh   = w2Tl + 442368;                     // 384*1536
    u16* cvTl   = cvTh + 589824;
    u16* Qu     = (u16*)tmpD;                        // Q fp16 alias (used between conv and h2)

    // ---- prep: split conversions + weight transposes
    hipLaunchKernelGGL(cvt_split, dim3(2048), dim3(256), 0, stream,
                       X_in, XinHi, XinLo, (size_t)M_IN * D_ / 4);
    hipLaunchKernelGGL(transpose_split, dim3(12, 12), dim3(256), 0, stream, qw, qwTh, qwTl, 384, 384);
    hipLaunchKernelGGL(transpose_split, dim3(12, 12), dim3(256), 0, stream, kw, kvTh, kvTl, 384, 384);
    hipLaunchKernelGGL(transpose_split, dim3(12, 12), dim3(256), 0, stream,
                       vw, kvTh + 147456, kvTl + 147456, 384, 384);
    hipLaunchKernelGGL(transpose_split, dim3(36, 12), dim3(256), 0, stream, w1, w1Th, w1Tl, 384, 1152);
    hipLaunchKernelGGL(transpose_split, dim3(12, 36), dim3(256), 0, stream, w2, w2Th, w2Tl, 1152, 384);
    hipLaunchKernelGGL(prep_convw_split, dim3((384 * 1536 + 255) / 256), dim3(256), 0, stream,
                       conv_w, cvTh, cvTl);
    hipLaunchKernelGGL(bias_mean, dim3(1), dim3(64), 0, stream, rel_bias, biasv);
    hipLaunchKernelGGL(concat_bias, dim3(3), dim3(256), 0, stream, kb, vb, kvb);

    // ---- init_proj conv (im2col, fp16 2-pass, BN=64) -> tmpD, X_out = LN(tmpD) [planes]
    hipLaunchKernelGGL((gemm_split<1, 0, 0, 2, 64>), dim3(6, 98), dim3(256), 0, stream,
                       XinHi, XinLo, cvTh, cvTl, conv_b, tmpD, (u16*)0, (u16*)0, M_OUT, D_, 4 * D_);
    hipLaunchKernelGGL((ln_rows<0, 0>), dim3(M_OUT / 4), dim3(256), 0, stream,
                       tmpD, Xout, XoutHi, XoutLo, ln_init_s, ln_init_b);

    // ---- K|V projection (single GEMM, N=768, 1-pass, fp16 OUT, BN=128)
    hipLaunchKernelGGL((gemm_split<0, 0, 2, 1, 128>), dim3(6, 392), dim3(256), 0, stream,
                       XinHi, (u16*)0, kvTh, kvTl, kvb, (float*)0, KVu, (u16*)0, M_IN, KVSTR, D_);

    for (int it = 0; it < 3; ++it) {
        // Q = Xout @ qw (1-pass, fp16 single out into tmpD alias)
        hipLaunchKernelGGL((gemm_split<0, 0, 2, 1, 64>), dim3(6, 98), dim3(256), 0, stream,
                           XoutHi, (u16*)0, qwTh, qwTl, qb, (float*)0, Qu, (u16*)0, M_OUT, D_, D_);
        hipLaunchKernelGGL(attn_nc, dim3(M_OUT / 4), dim3(256), 0, stream,
                           Qu, KVu, biasv, Pb, ln_out_s, ln_out_b, XoutHi, XoutLo);
        // h1 = GELU(Xout @ w1) (1-pass, fp16 single out)
        hipLaunchKernelGGL((gemm_split<0, 1, 2, 1, 128>), dim3(9, 98), dim3(256), 0, stream,
                           XoutHi, (u16*)0, w1Th, w1Tl, b1, (float*)0, h1U, (u16*)0, M_OUT, HID_, D_);
        // h2 = h1 @ w2 (1-pass) -> f32 tmpD
        hipLaunchKernelGGL((gemm_split<0, 0, 0, 1, 64>), dim3(6, 98), dim3(256), 0, stream,
                           h1U, (u16*)0, w2Th, w2Tl, b2, tmpD, (u16*)0, (u16*)0, M_OUT, D_, HID_);
        if (it < 2) {
            hipLaunchKernelGGL((ln_rows<1, 0>), dim3(M_OUT / 4), dim3(256), 0, stream,
                               tmpD, Xout, XoutHi, XoutLo, mlp_s, mlp_b);
        } else {
            // final pass: also materialize f32 Xout (output 0)
            hipLaunchKernelGGL((ln_rows<1, 1>), dim3(M_OUT / 4), dim3(256), 0, stream,
                               tmpD, Xout, XoutHi, XoutLo, mlp_s, mlp_b);
        }
    }

    // ---- all A-region temporaries dead now; build dense A_ups/A_down from it==2's Pb
    hipLaunchKernelGGL(write_A, dim3(M_OUT), dim3(256), 0, stream, Pb, Aups, Adown);
}

// Round 16
// 467.830 us; speedup vs baseline: 4.2388x; 1.0972x over previous
//
#include <hip/hip_runtime.h>
#include <hip/hip_bf16.h>
#include <math.h>

#define B_    16
#define H_    56
#define W_    56
#define D_    384
#define HID_  1152
#define N_IN  3136
#define N_OUT 784
#define M_OUT (B_ * N_OUT)   // 12544
#define M_IN  (B_ * N_IN)    // 50176
#define KVSTR 768

#define XOUT_ELEMS ((size_t)M_OUT * D_)          // 4,816,896
#define A_ELEMS    ((size_t)B_ * N_OUT * N_IN)   // 39,337,984

typedef unsigned short u16;
using frag_h  = __attribute__((ext_vector_type(8))) _Float16;  // 8 fp16 (4 VGPRs)
using frag_cd = __attribute__((ext_vector_type(4))) float;     // 4 fp32

__device__ __forceinline__ u16 f2h(float f) {
    _Float16 h = (_Float16)f;
    return *reinterpret_cast<u16*>(&h);
}
__device__ __forceinline__ float h2f(u16 u) {
    _Float16 h = *reinterpret_cast<_Float16*>(&u);
    return (float)h;
}

__device__ __forceinline__ float wave_sum(float x) {
#pragma unroll
    for (int off = 32; off; off >>= 1) x += __shfl_xor(x, off, 64);
    return x;
}

#define GLD16(g, l) __builtin_amdgcn_global_load_lds( \
    (const __attribute__((address_space(1))) void*)(g), \
    (__attribute__((address_space(3))) void*)(l), 16, 0, 0)

// ---- f32 -> fp16 single plane, float4 vectorized
__global__ void cvt_h(const float* __restrict__ in, u16* __restrict__ hi, size_t n4) {
    size_t i = (size_t)blockIdx.x * 256 + threadIdx.x;
    size_t stride = (size_t)gridDim.x * 256;
    for (; i < n4; i += stride) {
        float4 v = reinterpret_cast<const float4*>(in)[i];
        ushort4 h;
        h.x = f2h(v.x); h.y = f2h(v.y); h.z = f2h(v.z); h.w = f2h(v.w);
        reinterpret_cast<ushort4*>(hi)[i] = h;
    }
}

// ---- W[K][N] f32 -> Bt[N][K] fp16 (LDS-tiled transpose)
__global__ void transpose_h(const float* __restrict__ Wm, u16* __restrict__ Bt, int K, int N) {
    __shared__ float t[32][33];
    int k0 = blockIdx.y * 32, n0 = blockIdx.x * 32;
    int r = threadIdx.x >> 5, c = threadIdx.x & 31;
#pragma unroll
    for (int i = 0; i < 4; ++i) t[r + 8 * i][c] = Wm[(size_t)(k0 + r + 8 * i) * N + n0 + c];
    __syncthreads();
#pragma unroll
    for (int i = 0; i < 4; ++i)
        Bt[(size_t)(n0 + r + 8 * i) * K + k0 + c] = f2h(t[c][r + 8 * i]);
}

// ---- three 384x384 transposes in one launch (qw, kw, vw)
__global__ void transpose3(const float* __restrict__ qw, const float* __restrict__ kw,
                           const float* __restrict__ vw, u16* __restrict__ qT,
                           u16* __restrict__ kT, u16* __restrict__ vT) {
    __shared__ float t[32][33];
    const float* src = (blockIdx.z == 0) ? qw : (blockIdx.z == 1) ? kw : vw;
    u16* dst = (blockIdx.z == 0) ? qT : (blockIdx.z == 1) ? kT : vT;
    int k0 = blockIdx.y * 32, n0 = blockIdx.x * 32;
    int r = threadIdx.x >> 5, c = threadIdx.x & 31;
#pragma unroll
    for (int i = 0; i < 4; ++i) t[r + 8 * i][c] = src[(size_t)(k0 + r + 8 * i) * 384 + n0 + c];
    __syncthreads();
#pragma unroll
    for (int i = 0; i < 4; ++i)
        dst[(size_t)(n0 + r + 8 * i) * 384 + k0 + c] = f2h(t[c][r + 8 * i]);
}

// ---- conv weight: cvT[n][kk] fp16, kk = p*384 + c ; conv_w OIHW [n][c][p]
__global__ void prep_convw_h(const float* __restrict__ cw, u16* __restrict__ Bt) {
    int idx = blockIdx.x * 256 + threadIdx.x;
    if (idx >= 384 * 1536) return;
    int n = idx / 1536, kk = idx % 1536;
    int p = kk / 384, c = kk % 384;
    Bt[idx] = f2h(cw[n * 1536 + c * 4 + p]);
}

// ---- bias_mean + kb|vb concat in one launch (grid 3 x 256)
__global__ void prep_misc(const float* __restrict__ rb, float* __restrict__ biasv,
                          const float* __restrict__ kb, const float* __restrict__ vb,
                          float* __restrict__ kvb) {
    int i = blockIdx.x * 256 + threadIdx.x;
    if (i == 0) {
        float s = 0.f;
        for (int k = 0; k < 25; ++k) s += rb[k];
        *biasv = s / 25.0f;
    }
    if (i < 384) kvb[i] = kb[i];
    else if (i < 768) kvb[i] = vb[i - 384];
}

// ---- fp16 MFMA GEMM: C = A @ Bt^T + bias. Single-pass AhBh (2^-11 per input —
// all paths measured-safe R10-R14; LN/softmax/residual math stays f32).
// PASSES kept for fallback (2 = +AlBh). OUTMODE: 0 = f32, 2 = single fp16.
// 128xBN tile, BK=64, 4 waves; global_load_lds + XOR-swizzle; XCD remap.
template <int IM2COL, int GELU, int OUTMODE, int PASSES, int BN>
__global__ __launch_bounds__(256,
    ((((PASSES >= 2) ? 32768 : 16384) + BN * 128) <= 40960) ? 4 :
    ((((PASSES >= 2) ? 32768 : 16384) + BN * 128) <= 49152) ? 3 : 2)
void gemm_split(
    const u16* __restrict__ Ah, const u16* __restrict__ Al,
    const u16* __restrict__ Bth,
    const float* __restrict__ bias, float* __restrict__ Cf,
    u16* __restrict__ Chi,
    int M, int N, int K)
{
    constexpr int NF = BN / 32;          // n-frags per wave
    __shared__ u16 sAh[128 * 64];
    __shared__ u16 sAl[(PASSES >= 2) ? 128 * 64 : 8];
    __shared__ u16 sBh[BN * 64];
    const int t = threadIdx.x;
    const int lane = t & 63;
    const int w = t >> 6;
    const int wr = w >> 1, wc = w & 1;
    const int lm = lane & 15, lk = lane >> 4;

    // ---- XCD-aware (y,x) remap
    const int gx = gridDim.x, ny = gridDim.y;
    int d = blockIdx.y * gx + blockIdx.x;
    const int covered = (ny >> 3) * 8 * gx;
    int m_y, n_x;
    if (d < covered) {
        int c = d / (8 * gx), l = d % (8 * gx);
        m_y = c * 8 + (l & 7);
        n_x = l >> 3;
    } else {
        int l = d - covered;
        m_y = (ny & ~7) + l / gx;
        n_x = l % gx;
    }
    const int m0 = m_y * 128;
    const int n0 = n_x * BN;

    const int rt = t >> 3, st = t & 7;                    // staging row-sub, 16B slot
    const int skel = ((st * 16) ^ ((rt & 7) << 4)) >> 1;  // swizzle-inverse src k-elem

    int pb4[4];
    if (IM2COL) {
#pragma unroll
        for (int i = 0; i < 4; ++i) {
            int m = m0 + i * 32 + rt;
            int bb = m / N_OUT, o = m - bb * N_OUT;
            pb4[i] = bb * N_IN + (o / 28) * 112 + (o % 28) * 2;
        }
    }

    frag_cd acc[4][NF];
#pragma unroll
    for (int i = 0; i < 4; ++i)
#pragma unroll
        for (int j = 0; j < NF; ++j) acc[i][j] = (frag_cd){0.f, 0.f, 0.f, 0.f};

    const int swzf = (lm & 7) << 4;

    for (int kt = 0; kt < K; kt += 64) {
#pragma unroll
        for (int i = 0; i < 4; ++i) {
            int r = i * 32 + rt;
            size_t aoff;
            if (IM2COL) {
                int k = kt + skel;
                int p = k / 384, c = k - p * 384;
                aoff = ((size_t)pb4[i] + (p >> 1) * 56 + (p & 1)) * 384 + c;
            } else {
                aoff = (size_t)(m0 + r) * K + kt + skel;
            }
            GLD16(Ah + aoff, &sAh[i * 2048 + t * 8]);
            if (PASSES >= 2) GLD16(Al + aoff, &sAl[i * 2048 + t * 8]);
        }
#pragma unroll
        for (int i = 0; i < BN / 32; ++i) {
            int r = i * 32 + rt;
            size_t boff = (size_t)(n0 + r) * K + kt + skel;
            GLD16(Bth + boff, &sBh[i * 2048 + t * 8]);
        }
        __syncthreads();

#pragma unroll
        for (int h = 0; h < 2; ++h) {
            const int kb = (h * 64 + lk * 16) ^ swzf;
            frag_h ah[4], al[4], bh[NF];
#pragma unroll
            for (int m = 0; m < 4; ++m) {
                int arow = wr * 64 + m * 16 + lm;
                ah[m] = *reinterpret_cast<const frag_h*>(reinterpret_cast<const char*>(sAh) + arow * 128 + kb);
                if (PASSES >= 2)
                    al[m] = *reinterpret_cast<const frag_h*>(reinterpret_cast<const char*>(sAl) + arow * 128 + kb);
            }
#pragma unroll
            for (int n = 0; n < NF; ++n) {
                int brow = wc * (BN / 2) + n * 16 + lm;
                bh[n] = *reinterpret_cast<const frag_h*>(reinterpret_cast<const char*>(sBh) + brow * 128 + kb);
            }
#pragma unroll
            for (int m = 0; m < 4; ++m)
#pragma unroll
                for (int n = 0; n < NF; ++n) {
                    acc[m][n] = __builtin_amdgcn_mfma_f32_16x16x32_f16(ah[m], bh[n], acc[m][n], 0, 0, 0);
                    if (PASSES >= 2)
                        acc[m][n] = __builtin_amdgcn_mfma_f32_16x16x32_f16(al[m], bh[n], acc[m][n], 0, 0, 0);
                }
        }
        __syncthreads();
    }

    // epilogue: C/D layout col=lane&15, row=(lane>>4)*4+reg (m89-verified)
#pragma unroll
    for (int m = 0; m < 4; ++m) {
#pragma unroll
        for (int n = 0; n < NF; ++n) {
            int row0 = m0 + wr * 64 + m * 16 + lk * 4;
            int col  = n0 + wc * (BN / 2) + n * 16 + lm;
            float bv = bias[col];
#pragma unroll
            for (int r = 0; r < 4; ++r) {
                float v = acc[m][n][r] + bv;
                if (GELU) v = 0.5f * v * (1.0f + erff(v * 0.70710678118654752f));
                size_t idx = (size_t)(row0 + r) * N + col;
                if (OUTMODE == 2) Chi[idx] = f2h(v);
                else              Cf[idx] = v;
            }
        }
    }
}

// ---- row LayerNorm over D=384; X kept as single fp16 plane; f32 math.
// ADD: residual add from fp16 X. WF32: also write f32 dst (final pass only).
template <int ADD, int WF32>
__global__ __launch_bounds__(256) void ln_rows(
    const float* __restrict__ src, float* __restrict__ dst,
    u16* __restrict__ dhi, const float* __restrict__ s, const float* __restrict__ bvec)
{
    int wid = blockIdx.x * 4 + (threadIdx.x >> 6);
    int lane = threadIdx.x & 63;
    const float* r = src + (size_t)wid * D_;
    float v[6]; float sum = 0.f;
#pragma unroll
    for (int t = 0; t < 6; ++t) { v[t] = r[lane + 64 * t]; sum += v[t]; }
    sum = wave_sum(sum);
    float mean = sum * (1.0f / D_);
    float vs = 0.f;
#pragma unroll
    for (int t = 0; t < 6; ++t) { float d = v[t] - mean; vs += d * d; }
    vs = wave_sum(vs);
    float rstd = rsqrtf(vs * (1.0f / D_) + 1e-5f);
    float* wo = dst + (size_t)wid * D_;
    u16* wh = dhi + (size_t)wid * D_;
#pragma unroll
    for (int t = 0; t < 6; ++t) {
        int d = lane + 64 * t;
        float o = (v[t] - mean) * rstd * s[d] + bvec[d];
        float nv = ADD ? (h2f(wh[d]) + o) : o;
        if (WF32) wo[d] = nv;
        wh[d] = f2h(nv);
    }
}

// ---- fused: windowed scores + softmax -> P, then new_centers = P@V,
//      X_out += LN(new_centers). Q, KV, X all single fp16; math f32.
__global__ __launch_bounds__(256) void attn_nc(
    const u16* __restrict__ Q, const u16* __restrict__ KV,
    const float* __restrict__ biasp, float* __restrict__ P,
    const float* __restrict__ lns, const float* __restrict__ lnb,
    u16* __restrict__ Xhi)
{
    int wid = blockIdx.x * 4 + (threadIdx.x >> 6);   // (b,o)
    int lane = threadIdx.x & 63;
    int b = wid / N_OUT, o = wid % N_OUT;
    int yo = o / 28, xo = o % 28;
    float q[6];
    const u16* qr = Q + (size_t)wid * D_;
#pragma unroll
    for (int t = 0; t < 6; ++t) q[t] = h2f(qr[lane + 64 * t]);

    float s[9]; bool valid[9];
#pragma unroll
    for (int j = 0; j < 9; ++j) {
        int dy = j / 3 - 1, dx = j % 3 - 1;
        int yi = 2 * yo + dy, xi = 2 * xo + dx;
        bool ok = (yi >= 0) && (yi < H_) && (xi >= 0) && (xi < W_);
        valid[j] = ok;
        float acc = 0.f;
        if (ok) {
            const u16* kr = KV + (size_t)(b * N_IN + yi * W_ + xi) * KVSTR;
#pragma unroll
            for (int t = 0; t < 6; ++t) acc += q[t] * h2f(kr[lane + 64 * t]);
        }
        s[j] = acc;
    }
#pragma unroll
    for (int j = 0; j < 9; ++j) s[j] = wave_sum(s[j]);
    float bias = *biasp;
    float mx = -1e30f;
#pragma unroll
    for (int j = 0; j < 9; ++j) if (valid[j]) mx = fmaxf(mx, s[j] + bias);
    float e[9]; float tot = 0.f;
#pragma unroll
    for (int j = 0; j < 9; ++j) { e[j] = valid[j] ? expf(s[j] + bias - mx) : 0.0f; tot += e[j]; }
    float inv = 1.0f / tot;
#pragma unroll
    for (int j = 0; j < 9; ++j) e[j] *= inv;
    if (lane < 12) P[(size_t)wid * 12 + lane] = (lane < 9) ? e[lane] : 0.0f;

    // ---- P @ V over the window
    float acc[6] = {0, 0, 0, 0, 0, 0};
#pragma unroll
    for (int j = 0; j < 9; ++j) {
        if (valid[j]) {
            int dy = j / 3 - 1, dx = j % 3 - 1;
            int yi = 2 * yo + dy, xi = 2 * xo + dx;
            const u16* vr = KV + (size_t)(b * N_IN + yi * W_ + xi) * KVSTR + 384;
#pragma unroll
            for (int t = 0; t < 6; ++t) acc[t] += e[j] * h2f(vr[lane + 64 * t]);
        }
    }
    float sum = 0.f;
#pragma unroll
    for (int t = 0; t < 6; ++t) sum += acc[t];
    sum = wave_sum(sum);
    float mean = sum * (1.0f / D_);
    float vs = 0.f;
#pragma unroll
    for (int t = 0; t < 6; ++t) { float d = acc[t] - mean; vs += d * d; }
    vs = wave_sum(vs);
    float rstd = rsqrtf(vs * (1.0f / D_) + 1e-5f);
    u16* wh = Xhi + (size_t)wid * D_;
#pragma unroll
    for (int t = 0; t < 6; ++t) {
        int d = lane + 64 * t;
        float nv = h2f(wh[d]) + (acc[t] - mean) * rstd * lns[d] + lnb[d];
        wh[d] = f2h(nv);
    }
}

// ---- dense A_ups/A_down writer: one block per (b,o) row; zero row, fix window.
// Column sums computed inline (<=4 P contributors per input pixel).
__global__ __launch_bounds__(256) void write_A(
    const float* __restrict__ P,
    float* __restrict__ Aups, float* __restrict__ Adown)
{
    int wid = blockIdx.x;                 // (b,o)
    int b = wid / N_OUT, o = wid % N_OUT;
    int yo = o / 28, xo = o % 28;
    float4 z = {0.f, 0.f, 0.f, 0.f};
    float4* up = reinterpret_cast<float4*>(Aups + (size_t)wid * N_IN);
    float4* dn = reinterpret_cast<float4*>(Adown + (size_t)wid * N_IN);
    for (int i = threadIdx.x; i < N_IN / 4; i += 256) { up[i] = z; dn[i] = z; }
    __syncthreads();
    int j = threadIdx.x;
    if (j < 9) {
        int dy = j / 3 - 1, dx = j % 3 - 1;
        int yi = 2 * yo + dy, xi = 2 * xo + dx;
        if (yi >= 0 && yi < H_ && xi >= 0 && xi < W_) {
            int i = yi * W_ + xi;
            float p = P[(size_t)wid * 12 + j];
            float csum = 0.f;
            int yc = yi >> 1, xc = xi >> 1;
            for (int yo2 = yc - 1; yo2 <= yc + 1; ++yo2) {
                if (yo2 < 0 || yo2 >= 28) continue;
                int dy2 = yi - 2 * yo2;
                if (dy2 < -1 || dy2 > 1) continue;
                for (int xo2 = xc - 1; xo2 <= xc + 1; ++xo2) {
                    if (xo2 < 0 || xo2 >= 28) continue;
                    int dx2 = xi - 2 * xo2;
                    if (dx2 < -1 || dx2 > 1) continue;
                    int jj = (dy2 + 1) * 3 + (dx2 + 1);
                    csum += P[((size_t)(b * N_OUT + yo2 * 28 + xo2)) * 12 + jj];
                }
            }
            Aups[(size_t)wid * N_IN + i] = p;
            Adown[(size_t)wid * N_IN + i] = p / (1e-10f + csum);
        }
    }
}

extern "C" void kernel_launch(void* const* d_in, const int* in_sizes, int n_in,
                              void* d_out, int out_size, void* d_ws, size_t ws_size,
                              hipStream_t stream)
{
    const float* X_in      = (const float*)d_in[0];
    const float* conv_w    = (const float*)d_in[1];
    const float* conv_b    = (const float*)d_in[2];
    const float* ln_init_s = (const float*)d_in[3];
    const float* ln_init_b = (const float*)d_in[4];
    const float* qw        = (const float*)d_in[5];
    const float* qb        = (const float*)d_in[6];
    const float* kw        = (const float*)d_in[7];
    const float* kb        = (const float*)d_in[8];
    const float* vw        = (const float*)d_in[9];
    const float* vb        = (const float*)d_in[10];
    const float* ln_out_s  = (const float*)d_in[11];
    const float* ln_out_b  = (const float*)d_in[12];
    const float* w1        = (const float*)d_in[13];
    const float* b1        = (const float*)d_in[14];
    const float* w2        = (const float*)d_in[15];
    const float* b2        = (const float*)d_in[16];
    const float* mlp_s     = (const float*)d_in[17];
    const float* mlp_b     = (const float*)d_in[18];
    const float* rel_bias  = (const float*)d_in[19];
    (void)in_sizes; (void)n_in; (void)out_size; (void)ws_size;

    float* out   = (float*)d_out;
    float* Xout  = out;                    // (M_OUT, D) f32 — final output 0 (written last)
    float* Adown = out + XOUT_ELEMS;       // (B, N_OUT, N_IN)
    float* Aups  = Adown + A_ELEMS;

    // dead A-region overlays (all dead before the final write_A):
    float* Abase = Adown;                            // 2*A_ELEMS floats total
    u16* KVu   = (u16*)Abase;                        // M_IN*768 fp16 (77MB): K|V interleaved
    u16* XinH  = (u16*)(Abase + 38535168);           // M_IN*D u16
    u16* h1U   = (u16*)(Abase + 57802752);           // M_OUT*HID u16

    float* ws    = (float*)d_ws;
    float* tmpD  = ws;                               // M_OUT*D f32 (conv out / h2); Q aliases as u16
    float* Pb    = tmpD + XOUT_ELEMS;                // M_OUT*12
    float* biasv = Pb + (size_t)M_OUT * 12;          // 4
    float* kvb   = biasv + 4;                        // 768
    u16* XoutH  = (u16*)(kvb + 768);                 // M_OUT*D
    u16* qwT    = XoutH + XOUT_ELEMS;                // 384*384
    u16* kvT    = qwT + 147456;                      // 768*384 (kw rows then vw rows)
    u16* w1T    = kvT + 294912;                      // 1152*384
    u16* w2T    = w1T + 442368;                      // 384*1152
    u16* cvT    = w2T + 442368;                      // 384*1536
    u16* Qu     = (u16*)tmpD;                        // Q fp16 alias (used between conv and h2)

    // ---- prep: fp16 conversion + weight transposes (merged launches)
    hipLaunchKernelGGL(cvt_h, dim3(2048), dim3(256), 0, stream,
                       X_in, XinH, (size_t)M_IN * D_ / 4);
    hipLaunchKernelGGL(transpose3, dim3(12, 12, 3), dim3(256), 0, stream,
                       qw, kw, vw, qwT, kvT, kvT + 147456);
    hipLaunchKernelGGL(transpose_h, dim3(36, 12), dim3(256), 0, stream, w1, w1T, 384, 1152);
    hipLaunchKernelGGL(transpose_h, dim3(12, 36), dim3(256), 0, stream, w2, w2T, 1152, 384);
    hipLaunchKernelGGL(prep_convw_h, dim3((384 * 1536 + 255) / 256), dim3(256), 0, stream, conv_w, cvT);
    hipLaunchKernelGGL(prep_misc, dim3(3), dim3(256), 0, stream, rel_bias, biasv, kb, vb, kvb);

    // ---- init_proj conv (im2col, 1-pass, BN=64) -> tmpD f32, X_out = LN(tmpD)
    hipLaunchKernelGGL((gemm_split<1, 0, 0, 1, 64>), dim3(6, 98), dim3(256), 0, stream,
                       XinH, (u16*)0, cvT, conv_b, tmpD, (u16*)0, M_OUT, D_, 4 * D_);
    hipLaunchKernelGGL((ln_rows<0, 0>), dim3(M_OUT / 4), dim3(256), 0, stream,
                       tmpD, Xout, XoutH, ln_init_s, ln_init_b);

    // ---- K|V projection (single GEMM, N=768, 1-pass, fp16 OUT, BN=128)
    hipLaunchKernelGGL((gemm_split<0, 0, 2, 1, 128>), dim3(6, 392), dim3(256), 0, stream,
                       XinH, (u16*)0, kvT, kvb, (float*)0, KVu, M_IN, KVSTR, D_);

    for (int it = 0; it < 3; ++it) {
        // Q = Xout @ qw (1-pass, fp16 out into tmpD alias)
        hipLaunchKernelGGL((gemm_split<0, 0, 2, 1, 64>), dim3(6, 98), dim3(256), 0, stream,
                           XoutH, (u16*)0, qwT, qb, (float*)0, Qu, M_OUT, D_, D_);
        hipLaunchKernelGGL(attn_nc, dim3(M_OUT / 4), dim3(256), 0, stream,
                           Qu, KVu, biasv, Pb, ln_out_s, ln_out_b, XoutH);
        // h1 = GELU(Xout @ w1) (1-pass, fp16 out)
        hipLaunchKernelGGL((gemm_split<0, 1, 2, 1, 128>), dim3(9, 98), dim3(256), 0, stream,
                           XoutH, (u16*)0, w1T, b1, (float*)0, h1U, M_OUT, HID_, D_);
        // h2 = h1 @ w2 (1-pass) -> f32 tmpD
        hipLaunchKernelGGL((gemm_split<0, 0, 0, 1, 64>), dim3(6, 98), dim3(256), 0, stream,
                           h1U, (u16*)0, w2T, b2, tmpD, (u16*)0, M_OUT, D_, HID_);
        if (it < 2) {
            hipLaunchKernelGGL((ln_rows<1, 0>), dim3(M_OUT / 4), dim3(256), 0, stream,
                               tmpD, Xout, XoutH, mlp_s, mlp_b);
        } else {
            // final pass: also materialize f32 Xout (output 0)
            hipLaunchKernelGGL((ln_rows<1, 1>), dim3(M_OUT / 4), dim3(256), 0, stream,
                               tmpD, Xout, XoutH, mlp_s, mlp_b);
        }
    }

    // ---- all A-region temporaries dead now; build dense A_ups/A_down from it==2's Pb
    hipLaunchKernelGGL(write_A, dim3(M_OUT), dim3(256), 0, stream, Pb, Aups, Adown);
}

// Round 19
// 466.703 us; speedup vs baseline: 4.2490x; 1.0024x over previous
//
#include <hip/hip_runtime.h>
#include <hip/hip_bf16.h>
#include <math.h>

#define B_    16
#define H_    56
#define W_    56
#define D_    384
#define HID_  1152
#define N_IN  3136
#define N_OUT 784
#define M_OUT (B_ * N_OUT)   // 12544
#define M_IN  (B_ * N_IN)    // 50176
#define KVSTR 768

#define XOUT_ELEMS ((size_t)M_OUT * D_)          // 4,816,896
#define A_ELEMS    ((size_t)B_ * N_OUT * N_IN)   // 39,337,984

typedef unsigned short u16;
using frag_h  = __attribute__((ext_vector_type(8))) _Float16;  // 8 fp16 (4 VGPRs)
using frag_cd = __attribute__((ext_vector_type(4))) float;     // 4 fp32

__device__ __forceinline__ u16 f2h(float f) {
    _Float16 h = (_Float16)f;
    return *reinterpret_cast<u16*>(&h);
}
__device__ __forceinline__ float h2f(u16 u) {
    _Float16 h = *reinterpret_cast<_Float16*>(&u);
    return (float)h;
}

__device__ __forceinline__ float wave_sum(float x) {
#pragma unroll
    for (int off = 32; off; off >>= 1) x += __shfl_xor(x, off, 64);
    return x;
}

#define GLD16(g, l) __builtin_amdgcn_global_load_lds( \
    (const __attribute__((address_space(1))) void*)(g), \
    (__attribute__((address_space(3))) void*)(l), 16, 0, 0)

// ---- f32 -> fp16 single plane, float4 vectorized
__global__ void cvt_h(const float* __restrict__ in, u16* __restrict__ hi, size_t n4) {
    size_t i = (size_t)blockIdx.x * 256 + threadIdx.x;
    size_t stride = (size_t)gridDim.x * 256;
    for (; i < n4; i += stride) {
        float4 v = reinterpret_cast<const float4*>(in)[i];
        ushort4 h;
        h.x = f2h(v.x); h.y = f2h(v.y); h.z = f2h(v.z); h.w = f2h(v.w);
        reinterpret_cast<ushort4*>(hi)[i] = h;
    }
}

// ---- W[K][N] f32 -> Bt[N][K] fp16 (LDS-tiled transpose)
__global__ void transpose_h(const float* __restrict__ Wm, u16* __restrict__ Bt, int K, int N) {
    __shared__ float t[32][33];
    int k0 = blockIdx.y * 32, n0 = blockIdx.x * 32;
    int r = threadIdx.x >> 5, c = threadIdx.x & 31;
#pragma unroll
    for (int i = 0; i < 4; ++i) t[r + 8 * i][c] = Wm[(size_t)(k0 + r + 8 * i) * N + n0 + c];
    __syncthreads();
#pragma unroll
    for (int i = 0; i < 4; ++i)
        Bt[(size_t)(n0 + r + 8 * i) * K + k0 + c] = f2h(t[c][r + 8 * i]);
}

// ---- three 384x384 transposes in one launch (qw, kw, vw)
__global__ void transpose3(const float* __restrict__ qw, const float* __restrict__ kw,
                           const float* __restrict__ vw, u16* __restrict__ qT,
                           u16* __restrict__ kT, u16* __restrict__ vT) {
    __shared__ float t[32][33];
    const float* src = (blockIdx.z == 0) ? qw : (blockIdx.z == 1) ? kw : vw;
    u16* dst = (blockIdx.z == 0) ? qT : (blockIdx.z == 1) ? kT : vT;
    int k0 = blockIdx.y * 32, n0 = blockIdx.x * 32;
    int r = threadIdx.x >> 5, c = threadIdx.x & 31;
#pragma unroll
    for (int i = 0; i < 4; ++i) t[r + 8 * i][c] = src[(size_t)(k0 + r + 8 * i) * 384 + n0 + c];
    __syncthreads();
#pragma unroll
    for (int i = 0; i < 4; ++i)
        dst[(size_t)(n0 + r + 8 * i) * 384 + k0 + c] = f2h(t[c][r + 8 * i]);
}

// ---- conv weight: cvT[n][kk] fp16, kk = p*384 + c ; conv_w OIHW [n][c][p]
__global__ void prep_convw_h(const float* __restrict__ cw, u16* __restrict__ Bt) {
    int idx = blockIdx.x * 256 + threadIdx.x;
    if (idx >= 384 * 1536) return;
    int n = idx / 1536, kk = idx % 1536;
    int p = kk / 384, c = kk % 384;
    Bt[idx] = f2h(cw[n * 1536 + c * 4 + p]);
}

// ---- bias_mean + kb|vb concat in one launch (grid 3 x 256)
__global__ void prep_misc(const float* __restrict__ rb, float* __restrict__ biasv,
                          const float* __restrict__ kb, const float* __restrict__ vb,
                          float* __restrict__ kvb) {
    int i = blockIdx.x * 256 + threadIdx.x;
    if (i == 0) {
        float s = 0.f;
        for (int k = 0; k < 25; ++k) s += rb[k];
        *biasv = s / 25.0f;
    }
    if (i < 384) kvb[i] = kb[i];
    else if (i < 768) kvb[i] = vb[i - 384];
}

// ---- fp16 MFMA GEMM: C = A @ Bt^T + bias. Single-pass AhBh (2^-11 per input —
// all paths measured-safe R10-R16; LN/softmax/residual math stays f32).
// PASSES kept for fallback (2 = +AlBh). OUTMODE: 0 = f32, 2 = single fp16.
// NOTE: Q and h1 GEMMs CANNOT be fused (R17 post-mortem) — the attention
// residual updates X_out between them; h1 must read the post-attn X_out.
// 128xBN tile, BK=64, 4 waves; global_load_lds + XOR-swizzle; XCD remap.
template <int IM2COL, int GELU, int OUTMODE, int PASSES, int BN>
__global__ __launch_bounds__(256,
    ((((PASSES >= 2) ? 32768 : 16384) + BN * 128) <= 40960) ? 4 :
    ((((PASSES >= 2) ? 32768 : 16384) + BN * 128) <= 49152) ? 3 : 2)
void gemm_split(
    const u16* __restrict__ Ah, const u16* __restrict__ Al,
    const u16* __restrict__ Bth,
    const float* __restrict__ bias, float* __restrict__ Cf,
    u16* __restrict__ Chi,
    int M, int N, int K)
{
    constexpr int NF = BN / 32;          // n-frags per wave
    __shared__ u16 sAh[128 * 64];
    __shared__ u16 sAl[(PASSES >= 2) ? 128 * 64 : 8];
    __shared__ u16 sBh[BN * 64];
    const int t = threadIdx.x;
    const int lane = t & 63;
    const int w = t >> 6;
    const int wr = w >> 1, wc = w & 1;
    const int lm = lane & 15, lk = lane >> 4;

    // ---- XCD-aware (y,x) remap
    const int gx = gridDim.x, ny = gridDim.y;
    int d = blockIdx.y * gx + blockIdx.x;
    const int covered = (ny >> 3) * 8 * gx;
    int m_y, n_x;
    if (d < covered) {
        int c = d / (8 * gx), l = d % (8 * gx);
        m_y = c * 8 + (l & 7);
        n_x = l >> 3;
    } else {
        int l = d - covered;
        m_y = (ny & ~7) + l / gx;
        n_x = l % gx;
    }
    const int m0 = m_y * 128;
    const int n0 = n_x * BN;

    const int rt = t >> 3, st = t & 7;                    // staging row-sub, 16B slot
    const int skel = ((st * 16) ^ ((rt & 7) << 4)) >> 1;  // swizzle-inverse src k-elem

    int pb4[4];
    if (IM2COL) {
#pragma unroll
        for (int i = 0; i < 4; ++i) {
            int m = m0 + i * 32 + rt;
            int bb = m / N_OUT, o = m - bb * N_OUT;
            pb4[i] = bb * N_IN + (o / 28) * 112 + (o % 28) * 2;
        }
    }

    frag_cd acc[4][NF];
#pragma unroll
    for (int i = 0; i < 4; ++i)
#pragma unroll
        for (int j = 0; j < NF; ++j) acc[i][j] = (frag_cd){0.f, 0.f, 0.f, 0.f};

    const int swzf = (lm & 7) << 4;

    for (int kt = 0; kt < K; kt += 64) {
#pragma unroll
        for (int i = 0; i < 4; ++i) {
            int r = i * 32 + rt;
            size_t aoff;
            if (IM2COL) {
                int k = kt + skel;
                int p = k / 384, c = k - p * 384;
                aoff = ((size_t)pb4[i] + (p >> 1) * 56 + (p & 1)) * 384 + c;
            } else {
                aoff = (size_t)(m0 + r) * K + kt + skel;
            }
            GLD16(Ah + aoff, &sAh[i * 2048 + t * 8]);
            if (PASSES >= 2) GLD16(Al + aoff, &sAl[i * 2048 + t * 8]);
        }
#pragma unroll
        for (int i = 0; i < BN / 32; ++i) {
            int r = i * 32 + rt;
            size_t boff = (size_t)(n0 + r) * K + kt + skel;
            GLD16(Bth + boff, &sBh[i * 2048 + t * 8]);
        }
        __syncthreads();

#pragma unroll
        for (int h = 0; h < 2; ++h) {
            const int kb = (h * 64 + lk * 16) ^ swzf;
            frag_h ah[4], al[4], bh[NF];
#pragma unroll
            for (int m = 0; m < 4; ++m) {
                int arow = wr * 64 + m * 16 + lm;
                ah[m] = *reinterpret_cast<const frag_h*>(reinterpret_cast<const char*>(sAh) + arow * 128 + kb);
                if (PASSES >= 2)
                    al[m] = *reinterpret_cast<const frag_h*>(reinterpret_cast<const char*>(sAl) + arow * 128 + kb);
            }
#pragma unroll
            for (int n = 0; n < NF; ++n) {
                int brow = wc * (BN / 2) + n * 16 + lm;
                bh[n] = *reinterpret_cast<const frag_h*>(reinterpret_cast<const char*>(sBh) + brow * 128 + kb);
            }
#pragma unroll
            for (int m = 0; m < 4; ++m)
#pragma unroll
                for (int n = 0; n < NF; ++n) {
                    acc[m][n] = __builtin_amdgcn_mfma_f32_16x16x32_f16(ah[m], bh[n], acc[m][n], 0, 0, 0);
                    if (PASSES >= 2)
                        acc[m][n] = __builtin_amdgcn_mfma_f32_16x16x32_f16(al[m], bh[n], acc[m][n], 0, 0, 0);
                }
        }
        __syncthreads();
    }

    // epilogue: C/D layout col=lane&15, row=(lane>>4)*4+reg (m89-verified)
#pragma unroll
    for (int m = 0; m < 4; ++m) {
#pragma unroll
        for (int n = 0; n < NF; ++n) {
            int row0 = m0 + wr * 64 + m * 16 + lk * 4;
            int col  = n0 + wc * (BN / 2) + n * 16 + lm;
            float bv = bias[col];
#pragma unroll
            for (int r = 0; r < 4; ++r) {
                float v = acc[m][n][r] + bv;
                if (GELU) v = 0.5f * v * (1.0f + erff(v * 0.70710678118654752f));
                size_t idx = (size_t)(row0 + r) * N + col;
                if (OUTMODE == 2) Chi[idx] = f2h(v);
                else              Cf[idx] = v;
            }
        }
    }
}

// ---- row LayerNorm over D=384; X kept as single fp16 plane; f32 math.
// ADD: residual add from fp16 X. WF32: also write f32 dst (final pass only).
template <int ADD, int WF32>
__global__ __launch_bounds__(256) void ln_rows(
    const float* __restrict__ src, float* __restrict__ dst,
    u16* __restrict__ dhi, const float* __restrict__ s, const float* __restrict__ bvec)
{
    int wid = blockIdx.x * 4 + (threadIdx.x >> 6);
    int lane = threadIdx.x & 63;
    const float* r = src + (size_t)wid * D_;
    float v[6]; float sum = 0.f;
#pragma unroll
    for (int t = 0; t < 6; ++t) { v[t] = r[lane + 64 * t]; sum += v[t]; }
    sum = wave_sum(sum);
    float mean = sum * (1.0f / D_);
    float vs = 0.f;
#pragma unroll
    for (int t = 0; t < 6; ++t) { float d = v[t] - mean; vs += d * d; }
    vs = wave_sum(vs);
    float rstd = rsqrtf(vs * (1.0f / D_) + 1e-5f);
    float* wo = dst + (size_t)wid * D_;
    u16* wh = dhi + (size_t)wid * D_;
#pragma unroll
    for (int t = 0; t < 6; ++t) {
        int d = lane + 64 * t;
        float o = (v[t] - mean) * rstd * s[d] + bvec[d];
        float nv = ADD ? (h2f(wh[d]) + o) : o;
        if (WF32) wo[d] = nv;
        wh[d] = f2h(nv);
    }
}

// ---- fused: windowed scores + softmax -> P, then new_centers = P@V,
//      X_out += LN(new_centers). Q, KV, X all single fp16; math f32.
__global__ __launch_bounds__(256) void attn_nc(
    const u16* __restrict__ Q, const u16* __restrict__ KV,
    const float* __restrict__ biasp, float* __restrict__ P,
    const float* __restrict__ lns, const float* __restrict__ lnb,
    u16* __restrict__ Xhi)
{
    int wid = blockIdx.x * 4 + (threadIdx.x >> 6);   // (b,o)
    int lane = threadIdx.x & 63;
    int b = wid / N_OUT, o = wid % N_OUT;
    int yo = o / 28, xo = o % 28;
    float q[6];
    const u16* qr = Q + (size_t)wid * D_;
#pragma unroll
    for (int t = 0; t < 6; ++t) q[t] = h2f(qr[lane + 64 * t]);

    float s[9]; bool valid[9];
#pragma unroll
    for (int j = 0; j < 9; ++j) {
        int dy = j / 3 - 1, dx = j % 3 - 1;
        int yi = 2 * yo + dy, xi = 2 * xo + dx;
        bool ok = (yi >= 0) && (yi < H_) && (xi >= 0) && (xi < W_);
        valid[j] = ok;
        float acc = 0.f;
        if (ok) {
            const u16* kr = KV + (size_t)(b * N_IN + yi * W_ + xi) * KVSTR;
#pragma unroll
            for (int t = 0; t < 6; ++t) acc += q[t] * h2f(kr[lane + 64 * t]);
        }
        s[j] = acc;
    }
#pragma unroll
    for (int j = 0; j < 9; ++j) s[j] = wave_sum(s[j]);
    float bias = *biasp;
    float mx = -1e30f;
#pragma unroll
    for (int j = 0; j < 9; ++j) if (valid[j]) mx = fmaxf(mx, s[j] + bias);
    float e[9]; float tot = 0.f;
#pragma unroll
    for (int j = 0; j < 9; ++j) { e[j] = valid[j] ? expf(s[j] + bias - mx) : 0.0f; tot += e[j]; }
    float inv = 1.0f / tot;
#pragma unroll
    for (int j = 0; j < 9; ++j) e[j] *= inv;
    if (lane < 12) P[(size_t)wid * 12 + lane] = (lane < 9) ? e[lane] : 0.0f;

    // ---- P @ V over the window
    float acc[6] = {0, 0, 0, 0, 0, 0};
#pragma unroll
    for (int j = 0; j < 9; ++j) {
        if (valid[j]) {
            int dy = j / 3 - 1, dx = j % 3 - 1;
            int yi = 2 * yo + dy, xi = 2 * xo + dx;
            const u16* vr = KV + (size_t)(b * N_IN + yi * W_ + xi) * KVSTR + 384;
#pragma unroll
            for (int t = 0; t < 6; ++t) acc[t] += e[j] * h2f(vr[lane + 64 * t]);
        }
    }
    float sum = 0.f;
#pragma unroll
    for (int t = 0; t < 6; ++t) sum += acc[t];
    sum = wave_sum(sum);
    float mean = sum * (1.0f / D_);
    float vs = 0.f;
#pragma unroll
    for (int t = 0; t < 6; ++t) { float d = acc[t] - mean; vs += d * d; }
    vs = wave_sum(vs);
    float rstd = rsqrtf(vs * (1.0f / D_) + 1e-5f);
    u16* wh = Xhi + (size_t)wid * D_;
#pragma unroll
    for (int t = 0; t < 6; ++t) {
        int d = lane + 64 * t;
        float nv = h2f(wh[d]) + (acc[t] - mean) * rstd * lns[d] + lnb[d];
        wh[d] = f2h(nv);
    }
}

// ---- dense A_ups/A_down writer: one block per (b,o) row; zero row, fix window.
// Column sums computed inline (<=4 P contributors per input pixel).
__global__ __launch_bounds__(256) void write_A(
    const float* __restrict__ P,
    float* __restrict__ Aups, float* __restrict__ Adown)
{
    int wid = blockIdx.x;                 // (b,o)
    int b = wid / N_OUT, o = wid % N_OUT;
    int yo = o / 28, xo = o % 28;
    float4 z = {0.f, 0.f, 0.f, 0.f};
    float4* up = reinterpret_cast<float4*>(Aups + (size_t)wid * N_IN);
    float4* dn = reinterpret_cast<float4*>(Adown + (size_t)wid * N_IN);
    for (int i = threadIdx.x; i < N_IN / 4; i += 256) { up[i] = z; dn[i] = z; }
    __syncthreads();
    int j = threadIdx.x;
    if (j < 9) {
        int dy = j / 3 - 1, dx = j % 3 - 1;
        int yi = 2 * yo + dy, xi = 2 * xo + dx;
        if (yi >= 0 && yi < H_ && xi >= 0 && xi < W_) {
            int i = yi * W_ + xi;
            float p = P[(size_t)wid * 12 + j];
            float csum = 0.f;
            int yc = yi >> 1, xc = xi >> 1;
            for (int yo2 = yc - 1; yo2 <= yc + 1; ++yo2) {
                if (yo2 < 0 || yo2 >= 28) continue;
                int dy2 = yi - 2 * yo2;
                if (dy2 < -1 || dy2 > 1) continue;
                for (int xo2 = xc - 1; xo2 <= xc + 1; ++xo2) {
                    if (xo2 < 0 || xo2 >= 28) continue;
                    int dx2 = xi - 2 * xo2;
                    if (dx2 < -1 || dx2 > 1) continue;
                    int jj = (dy2 + 1) * 3 + (dx2 + 1);
                    csum += P[((size_t)(b * N_OUT + yo2 * 28 + xo2)) * 12 + jj];
                }
            }
            Aups[(size_t)wid * N_IN + i] = p;
            Adown[(size_t)wid * N_IN + i] = p / (1e-10f + csum);
        }
    }
}

extern "C" void kernel_launch(void* const* d_in, const int* in_sizes, int n_in,
                              void* d_out, int out_size, void* d_ws, size_t ws_size,
                              hipStream_t stream)
{
    const float* X_in      = (const float*)d_in[0];
    const float* conv_w    = (const float*)d_in[1];
    const float* conv_b    = (const float*)d_in[2];
    const float* ln_init_s = (const float*)d_in[3];
    const float* ln_init_b = (const float*)d_in[4];
    const float* qw        = (const float*)d_in[5];
    const float* qb        = (const float*)d_in[6];
    const float* kw        = (const float*)d_in[7];
    const float* kb        = (const float*)d_in[8];
    const float* vw        = (const float*)d_in[9];
    const float* vb        = (const float*)d_in[10];
    const float* ln_out_s  = (const float*)d_in[11];
    const float* ln_out_b  = (const float*)d_in[12];
    const float* w1        = (const float*)d_in[13];
    const float* b1        = (const float*)d_in[14];
    const float* w2        = (const float*)d_in[15];
    const float* b2        = (const float*)d_in[16];
    const float* mlp_s     = (const float*)d_in[17];
    const float* mlp_b     = (const float*)d_in[18];
    const float* rel_bias  = (const float*)d_in[19];
    (void)in_sizes; (void)n_in; (void)out_size; (void)ws_size;

    float* out   = (float*)d_out;
    float* Xout  = out;                    // (M_OUT, D) f32 — final output 0 (written last)
    float* Adown = out + XOUT_ELEMS;       // (B, N_OUT, N_IN)
    float* Aups  = Adown + A_ELEMS;

    // dead A-region overlays (all dead before the final write_A):
    float* Abase = Adown;                            // 2*A_ELEMS floats total
    u16* KVu   = (u16*)Abase;                        // M_IN*768 fp16 (77MB): K|V interleaved
    u16* XinH  = (u16*)(Abase + 38535168);           // M_IN*D u16
    u16* h1U   = (u16*)(Abase + 57802752);           // M_OUT*HID u16

    float* ws    = (float*)d_ws;
    float* tmpD  = ws;                               // M_OUT*D f32 (conv out / h2); Q aliases as u16
    float* Pb    = tmpD + XOUT_ELEMS;                // M_OUT*12
    float* biasv = Pb + (size_t)M_OUT * 12;          // 4
    float* kvb   = biasv + 4;                        // 768
    u16* XoutH  = (u16*)(kvb + 768);                 // M_OUT*D
    u16* qwT    = XoutH + XOUT_ELEMS;                // 384*384
    u16* kvT    = qwT + 147456;                      // 768*384 (kw rows then vw rows)
    u16* w1T    = kvT + 294912;                      // 1152*384
    u16* w2T    = w1T + 442368;                      // 384*1152
    u16* cvT    = w2T + 442368;                      // 384*1536
    u16* Qu     = (u16*)tmpD;                        // Q fp16 alias (used between conv and h2)

    // ---- prep: fp16 conversion + weight transposes (merged launches)
    hipLaunchKernelGGL(cvt_h, dim3(2048), dim3(256), 0, stream,
                       X_in, XinH, (size_t)M_IN * D_ / 4);
    hipLaunchKernelGGL(transpose3, dim3(12, 12, 3), dim3(256), 0, stream,
                       qw, kw, vw, qwT, kvT, kvT + 147456);
    hipLaunchKernelGGL(transpose_h, dim3(36, 12), dim3(256), 0, stream, w1, w1T, 384, 1152);
    hipLaunchKernelGGL(transpose_h, dim3(12, 36), dim3(256), 0, stream, w2, w2T, 1152, 384);
    hipLaunchKernelGGL(prep_convw_h, dim3((384 * 1536 + 255) / 256), dim3(256), 0, stream, conv_w, cvT);
    hipLaunchKernelGGL(prep_misc, dim3(3), dim3(256), 0, stream, rel_bias, biasv, kb, vb, kvb);

    // ---- init_proj conv (im2col, 1-pass, BN=64) -> tmpD f32, X_out = LN(tmpD)
    hipLaunchKernelGGL((gemm_split<1, 0, 0, 1, 64>), dim3(6, 98), dim3(256), 0, stream,
                       XinH, (u16*)0, cvT, conv_b, tmpD, (u16*)0, M_OUT, D_, 4 * D_);
    hipLaunchKernelGGL((ln_rows<0, 0>), dim3(M_OUT / 4), dim3(256), 0, stream,
                       tmpD, Xout, XoutH, ln_init_s, ln_init_b);

    // ---- K|V projection (single GEMM, N=768, 1-pass, fp16 OUT, BN=128)
    hipLaunchKernelGGL((gemm_split<0, 0, 2, 1, 128>), dim3(6, 392), dim3(256), 0, stream,
                       XinH, (u16*)0, kvT, kvb, (float*)0, KVu, M_IN, KVSTR, D_);

    for (int it = 0; it < 3; ++it) {
        // Q = Xout @ qw (1-pass, fp16 out into tmpD alias)
        hipLaunchKernelGGL((gemm_split<0, 0, 2, 1, 64>), dim3(6, 98), dim3(256), 0, stream,
                           XoutH, (u16*)0, qwT, qb, (float*)0, Qu, M_OUT, D_, D_);
        hipLaunchKernelGGL(attn_nc, dim3(M_OUT / 4), dim3(256), 0, stream,
                           Qu, KVu, biasv, Pb, ln_out_s, ln_out_b, XoutH);
        // h1 = GELU(Xout @ w1) (1-pass, fp16 out)
        hipLaunchKernelGGL((gemm_split<0, 1, 2, 1, 128>), dim3(9, 98), dim3(256), 0, stream,
                           XoutH, (u16*)0, w1T, b1, (float*)0, h1U, M_OUT, HID_, D_);
        // h2 = h1 @ w2 (1-pass) -> f32 tmpD
        hipLaunchKernelGGL((gemm_split<0, 0, 0, 1, 64>), dim3(6, 98), dim3(256), 0, stream,
                           h1U, (u16*)0, w2T, b2, tmpD, (u16*)0, M_OUT, D_, HID_);
        if (it < 2) {
            hipLaunchKernelGGL((ln_rows<1, 0>), dim3(M_OUT / 4), dim3(256), 0, stream,
                               tmpD, Xout, XoutH, mlp_s, mlp_b);
        } else {
            // final pass: also materialize f32 Xout (output 0)
            hipLaunchKernelGGL((ln_rows<1, 1>), dim3(M_OUT / 4), dim3(256), 0, stream,
                               tmpD, Xout, XoutH, mlp_s, mlp_b);
        }
    }

    // ---- all A-region temporaries dead now; build dense A_ups/A_down from it==2's Pb
    hipLaunchKernelGGL(write_A, dim3(M_OUT), dim3(256), 0, stream, Pb, Aups, Adown);
}